// Round 10
// baseline (326.191 us; speedup 1.0000x reference)
//
#include <hip/hip_runtime.h>

#define DEV __device__ __forceinline__

typedef unsigned short u16;
typedef unsigned int u32;
typedef __bf16 bf16x8 __attribute__((ext_vector_type(8)));
typedef float f32x4 __attribute__((ext_vector_type(4)));

DEV float elu1(float x) { return x > 0.f ? x + 1.f : __expf(x); }

DEV u16 f2bf(float f) {
    union { float f; unsigned u; } v; v.f = f;
    unsigned r = v.u + 0x7fffu + ((v.u >> 16) & 1u);
    return (u16)(r >> 16);
}

// ===========================================================================
// Conv weight repack (validated R2).
// ===========================================================================
__global__ __launch_bounds__(256) void repack_kernel(
    const float* __restrict__ Wq,
    const float* __restrict__ Wk1, const float* __restrict__ Wk3,
    const float* __restrict__ Wk5, const float* __restrict__ Wk7,
    const float* __restrict__ Wv1, const float* __restrict__ Wv3,
    const float* __restrict__ Wv5, const float* __restrict__ Wv7,
    u16* __restrict__ wpack)
{
    int gid = blockIdx.x * 256 + threadIdx.x;
    int frag = gid >> 6, l = gid & 63;
    const float* W; int K, ocbase = 0, rel;
    if (frag < 1152) {
        W = Wq; K = 3; int slot = frag / 288; rel = frag % 288; ocbase = slot * 64;
    } else {
        int f = frag - 1152; int side = f / 2688; f %= 2688;
        if (f < 32)        { W = side ? Wv1 : Wk1; K = 1; rel = f; }
        else if (f < 320)  { W = side ? Wv3 : Wk3; K = 3; rel = f - 32; }
        else if (f < 1120) { W = side ? Wv5 : Wk5; K = 5; rel = f - 320; }
        else               { W = side ? Wv7 : Wk7; K = 7; rel = f - 1120; }
    }
    int og = rel & 3, cc = (rel >> 2) & 7, tap = rel >> 5;
    int dy = tap / K, dx = tap % K;
    int oc = ocbase + og * 16 + (l & 15);
    int c0 = cc * 32 + (l >> 4) * 8;
    u16 pk[8];
#pragma unroll
    for (int j = 0; j < 8; ++j)
        pk[j] = f2bf(W[((size_t)(oc * 256 + c0 + j) * K + dy) * K + dx]);
    *(int4*)&wpack[(size_t)frag * 512 + l * 8] = *(const int4*)pk;
}

// ===========================================================================
// zero_kv: zero kb/vb heads 2,3 (atomic accumulation targets).
// ===========================================================================
__global__ __launch_bounds__(256) void zero_kv_kernel(float* __restrict__ kb,
                                                      float* __restrict__ vb)
{
    int gid = blockIdx.x * 256 + threadIdx.x;   // 2048*256 = 524288 float4
    int side = gid >> 18, b = (gid >> 15) & 7, u = gid & 32767;
    float* p = (side ? vb : kb) + (size_t)b * 262144 + 131072 + (size_t)u * 4;
    *(float4*)p = make_float4(0.f, 0.f, 0.f, 0.f);
}

// ===========================================================================
// cast_src: fp32 NCHW -> bf16 blocked [b][cc8][pix1024][c32].
// ===========================================================================
__global__ __launch_bounds__(256) void cast_src_kernel(
    const float* __restrict__ x, const float* __restrict__ src,
    u16* __restrict__ xbh, u16* __restrict__ sbh)
{
    __shared__ float lds[32 * 129];
    const int i = blockIdx.x, t = threadIdx.x;   // 1024 blocks
    const int inp = i >> 9, rem = i & 511;
    const int b = rem >> 6, cc = (rem >> 3) & 7, pxb = rem & 7;
    const float* in = (inp ? src : x) + ((size_t)b * 256 + cc * 32) * 1024 + pxb * 128;
    u16* outp = (inp ? sbh : xbh) + (size_t)b * 262144 + (size_t)cc * 32768 + pxb * 128 * 32;
#pragma unroll
    for (int u = 0; u < 4; ++u) {
        int unit = t + u * 256;
        int r = unit >> 5, px4 = unit & 31;
        float4 v = *(const float4*)(in + (size_t)r * 1024 + px4 * 4);
        lds[r * 129 + px4 * 4 + 0] = v.x;
        lds[r * 129 + px4 * 4 + 1] = v.y;
        lds[r * 129 + px4 * 4 + 2] = v.z;
        lds[r * 129 + px4 * 4 + 3] = v.w;
    }
    __syncthreads();
#pragma unroll
    for (int u = 0; u < 2; ++u) {
        int unit = t + u * 256;
        int px = unit >> 2, cg = unit & 3;
        u16 pk[8];
#pragma unroll
        for (int j = 0; j < 8; ++j) pk[j] = f2bf(lds[(cg * 8 + j) * 129 + px]);
        *(int4*)&outp[px * 32 + cg * 8] = *(const int4*)pk;
    }
}

// ===========================================================================
// cast_qk: qb/kb fp32 [b][c][l] -> bf16 [b*4+h][l][64].
// ===========================================================================
__global__ __launch_bounds__(256) void cast_qk_kernel(
    const float* __restrict__ qb, const float* __restrict__ kb,
    u16* __restrict__ qbt, u16* __restrict__ kbt)
{
    __shared__ float lds[64 * 65];
    const int i = blockIdx.x, t = threadIdx.x;   // 1024 blocks
    const int inp = i >> 9, rem = i & 511;
    const int b = rem >> 6, h = (rem >> 4) & 3, pxb = rem & 15;
    const float* in = (inp ? kb : qb) + ((size_t)b * 256 + h * 64) * 1024 + pxb * 64;
    u16* outp = (inp ? kbt : qbt) + (((size_t)(b * 4 + h)) * 1024 + pxb * 64) * 64;
#pragma unroll
    for (int u = 0; u < 4; ++u) {
        int unit = t + u * 256;
        int r = unit >> 4, px4 = unit & 15;
        float4 v = *(const float4*)(in + (size_t)r * 1024 + px4 * 4);
        lds[r * 65 + px4 * 4 + 0] = v.x;
        lds[r * 65 + px4 * 4 + 1] = v.y;
        lds[r * 65 + px4 * 4 + 2] = v.z;
        lds[r * 65 + px4 * 4 + 3] = v.w;
    }
    __syncthreads();
#pragma unroll
    for (int u = 0; u < 2; ++u) {
        int unit = t + u * 256;
        int px = unit >> 3, cg = unit & 7;
        u16 pk[8];
#pragma unroll
        for (int j = 0; j < 8; ++j) pk[j] = f2bf(lds[(cg * 8 + j) * 65 + px]);
        *(int4*)&outp[px * 64 + cg * 8] = *(const int4*)pk;
    }
}

// ===========================================================================
// FF/W repack (after conv; w1p/w2p live in dead wpack region).
// ===========================================================================
__global__ __launch_bounds__(256) void repack_ff_kernel(
    const float* __restrict__ W1, const float* __restrict__ W2,
    u16* __restrict__ w1p, u16* __restrict__ w2p)
{
    int gid = blockIdx.x * 256 + threadIdx.x;   // 192*256 = 49152
    int f = gid >> 6, l = gid & 63;
    u16 pk[8];
    if (f < 512) {
        int ks = f >> 5, nf = f & 31;
#pragma unroll
        for (int j = 0; j < 8; ++j)
            pk[j] = f2bf(W1[(size_t)(ks * 32 + (l >> 4) * 8 + j) * 512 + nf * 16 + (l & 15)]);
        *(int4*)&w1p[(size_t)f * 512 + l * 8] = *(const int4*)pk;
    } else {
        int f2 = f - 512;
        int ks = f2 >> 4, nf = f2 & 15;
#pragma unroll
        for (int j = 0; j < 8; ++j)
            pk[j] = f2bf(W2[(size_t)(ks * 32 + (l >> 4) * 8 + j) * 256 + nf * 16 + (l & 15)]);
        *(int4*)&w2p[(size_t)f2 * 512 + l * 8] = *(const int4*)pk;
    }
}

// ===========================================================================
// MFMA implicit-GEMM conv: 512 threads (8 waves), 64 oc x 512 px (16 rows).
// R10: A-frag tap+1 register prefetch (explicit software pipeline) and
// atomic epilogue for c-split (K5/K7) jobs (reduce_kernel eliminated).
// ===========================================================================
template<int K>
DEV void conv_mfma_body(const u16* __restrict__ srcb,
                        const u16* __restrict__ wsec,
                        float* __restrict__ dst,
                        u16* Bt, int y0, int cch0, int ncc, int t,
                        bool atomicOut)
{
    constexpr int P = K / 2;
    constexpr int NT = K * K;
    const int w = t >> 6, l = t & 63;
    const int chi = l >> 4, ln = l & 15;
    const int rowbase = chi * 22 + w * 2 + 3 - P;
    const int colbase = ln + 3 - P;
    f32x4 acc[4][4];
#pragma unroll
    for (int m = 0; m < 4; ++m)
#pragma unroll
        for (int n = 0; n < 4; ++n) acc[m][n] = (f32x4){0.f, 0.f, 0.f, 0.f};

    for (int cc = 0; cc < ncc; ++cc) {
        const int ccg = cch0 + cc;
        __syncthreads();
#pragma unroll
        for (int u = 0; u < 7; ++u) {
            int unit = t + (u << 9);
            if (unit < 2816) {
                int xv = unit & 31, r = unit >> 5;
                int yy = r % 22, ch = r / 22;
                int ygl = y0 - 3 + yy;
                int4 pk;
                if ((unsigned)ygl < 32u)
                    pk = *(const int4*)&srcb[(size_t)ccg * 32768 + (ygl * 32 + xv) * 32 + ch * 8];
                else
                    pk = (int4){0, 0, 0, 0};
                *(int4*)&Bt[((ch * 22 + yy) * 40 + xv + 3) * 8] = pk;
            } else if (unit < 3520) {
                int hu = unit - 2816;
                int hx = hu & 7; int xi = hx < 3 ? hx : hx + 32;
                int r = hu >> 3; int yy = r % 22, ch = r / 22;
                int4 z = {0, 0, 0, 0};
                *(int4*)&Bt[((ch * 22 + yy) * 40 + xi) * 8] = z;
            }
        }
        __syncthreads();
        // ---- tap loop with A-frag prefetch pipeline ----
        const u16* wp0 = wsec + ((size_t)(0 * 8 + ccg) * 4) * 512 + l * 8;
        bf16x8 a0 = *(const bf16x8*)(wp0);
        bf16x8 a1 = *(const bf16x8*)(wp0 + 512);
        bf16x8 a2 = *(const bf16x8*)(wp0 + 1024);
        bf16x8 a3 = *(const bf16x8*)(wp0 + 1536);
#pragma unroll
        for (int tap = 0; tap < NT; ++tap) {
            bf16x8 n0 = a0, n1 = a1, n2 = a2, n3 = a3;
            if (tap + 1 < NT) {
                const u16* wp = wsec + ((size_t)((tap + 1) * 8 + ccg) * 4) * 512 + l * 8;
                n0 = *(const bf16x8*)(wp);
                n1 = *(const bf16x8*)(wp + 512);
                n2 = *(const bf16x8*)(wp + 1024);
                n3 = *(const bf16x8*)(wp + 1536);
            }
            const int dy = tap / K, dx = tap % K;
            bf16x8 bf[4];
#pragma unroll
            for (int n = 0; n < 4; ++n) {
                int row = rowbase + dy + (n >> 1);
                int col = colbase + dx + (n & 1) * 16;
                bf[n] = *(const bf16x8*)&Bt[(row * 40 + col) * 8];
            }
#pragma unroll
            for (int n = 0; n < 4; ++n) {
                acc[0][n] = __builtin_amdgcn_mfma_f32_16x16x32_bf16(a0, bf[n], acc[0][n], 0, 0, 0);
                acc[1][n] = __builtin_amdgcn_mfma_f32_16x16x32_bf16(a1, bf[n], acc[1][n], 0, 0, 0);
                acc[2][n] = __builtin_amdgcn_mfma_f32_16x16x32_bf16(a2, bf[n], acc[2][n], 0, 0, 0);
                acc[3][n] = __builtin_amdgcn_mfma_f32_16x16x32_bf16(a3, bf[n], acc[3][n], 0, 0, 0);
            }
            a0 = n0; a1 = n1; a2 = n2; a3 = n3;
        }
    }
#pragma unroll
    for (int m = 0; m < 4; ++m)
#pragma unroll
        for (int n = 0; n < 4; ++n) {
            int y = y0 + w * 2 + (n >> 1);
            int px = y * 32 + (n & 1) * 16 + ln;
            int ocb = m * 16 + chi * 4;
            if (!atomicOut) {
#pragma unroll
                for (int r = 0; r < 4; ++r)
                    dst[(size_t)(ocb + r) * 1024 + px] = acc[m][n][r];
            } else {
#pragma unroll
                for (int r = 0; r < 4; ++r)
                    atomicAdd(&dst[(size_t)(ocb + r) * 1024 + px], acc[m][n][r]);
            }
        }
}

// Job decode (R9 XCD grouping): bx = m*256 + b*32 + g, grid 512. XCD = g%8.
//  g<4: q slot g. else gs=g-4, side=gs/14, gg=gs%14:
//   gg=0: K1; gg=1: K3; gg in [2,6): K5 cpart=gg-2 (atomic);
//   gg in [6,14): K7 cpart=gg-6 (atomic).
__global__ __launch_bounds__(512) void conv_mfma_kernel(
    const u16* __restrict__ xbh, const u16* __restrict__ sbh,
    const u16* __restrict__ wpack,
    float* __restrict__ qb, float* __restrict__ kb, float* __restrict__ vb)
{
    __shared__ u16 Bt[4 * 22 * 40 * 8];
    const int bx = blockIdx.x, t = threadIdx.x;
    const int g = bx & 31, b = (bx >> 5) & 7, m = bx >> 8;
    if (g < 4) {
        conv_mfma_body<3>(xbh + (size_t)b * 262144,
                          wpack + (size_t)(g * 288) * 512,
                          qb + ((size_t)b * 256 + g * 64) * 1024,
                          Bt, m * 16, 0, 8, t, false);
        return;
    }
    const int gs = g - 4;
    const int side = gs / 14, gg = gs % 14;
    const u16* sp = sbh + (size_t)b * 262144;
    float* fin = side ? vb : kb;
    const size_t wkb = 1152 + (size_t)side * 2688;
    if (gg == 0) {
        conv_mfma_body<1>(sp, wpack + (wkb + 0) * 512,
                          fin + ((size_t)b * 256) * 1024, Bt, m * 16, 0, 8, t, false);
    } else if (gg == 1) {
        conv_mfma_body<3>(sp, wpack + (wkb + 32) * 512,
                          fin + ((size_t)b * 256 + 64) * 1024, Bt, m * 16, 0, 8, t, false);
    } else if (gg < 6) {
        int cpart = gg - 2;
        conv_mfma_body<5>(sp, wpack + (wkb + 320) * 512,
                          fin + ((size_t)b * 256 + 128) * 1024,
                          Bt, m * 16, cpart * 2, 2, t, true);
    } else {
        int cpart = gg - 6;
        conv_mfma_body<7>(sp, wpack + (wkb + 1120) * 512,
                          fin + ((size_t)b * 256 + 192) * 1024,
                          Bt, m * 16, cpart, 1, t, true);
    }
}

// ===========================================================================
// Fused QK^T + softmax -> vis (validated R4/R6).
// ===========================================================================
__global__ __launch_bounds__(512) void qk_sm_kernel(const u16* __restrict__ qbt,
                                                    const u16* __restrict__ kbt,
                                                    float* __restrict__ vis)
{
    __shared__ u16 kf[32 * 512];
    __shared__ u16 qf[4 * 512];
    __shared__ float redM[32 * 8];
    __shared__ float redS[32 * 8];
    const int t = threadIdx.x;
    const int bx = blockIdx.x;          // 8b*4h*32lt = 1024
    const int b = bx >> 7, h = (bx >> 5) & 3, l0 = (bx & 31) * 32;
    const u16* qtp = qbt + ((size_t)(b * 4 + h)) * 1024 * 64;
    const u16* ktp = kbt + ((size_t)(b * 4 + h)) * 1024 * 64;

    if (t < 256) {
        int r = t & 31, dblk = t >> 5;
        int4 pk = *(const int4*)&qtp[(size_t)(l0 + r) * 64 + dblk * 8];
        *(int4*)&qf[(((r >> 4) * 2 + (dblk >> 2)) * 64 + (dblk & 3) * 16 + (r & 15)) * 8] = pk;
    }
    __syncthreads();

    const int w = t >> 6, l = t & 63, ln = l & 15, lg = l >> 4;
    bf16x8 a[2][2];
#pragma unroll
    for (int fr = 0; fr < 2; ++fr)
#pragma unroll
        for (int ks = 0; ks < 2; ++ks)
            a[fr][ks] = *(const bf16x8*)&qf[((fr * 2 + ks) * 64 + l) * 8];

    f32x4 acc[2][4][2];
#pragma unroll
    for (int fr = 0; fr < 2; ++fr)
#pragma unroll
        for (int cc = 0; cc < 4; ++cc)
#pragma unroll
            for (int f = 0; f < 2; ++f) acc[fr][cc][f] = (f32x4){0.f, 0.f, 0.f, 0.f};

#pragma unroll
    for (int cc = 0; cc < 4; ++cc) {
        __syncthreads();
#pragma unroll
        for (int it = 0; it < 4; ++it) {
            int unit = it * 512 + t;
            int sl = unit & 255, dblk = unit >> 8;
            int4 pk = *(const int4*)&ktp[(size_t)(cc * 256 + sl) * 64 + dblk * 8];
            *(int4*)&kf[(((sl >> 4) * 2 + (dblk >> 2)) * 64 + (dblk & 3) * 16 + (sl & 15)) * 8] = pk;
        }
        __syncthreads();
#pragma unroll
        for (int f = 0; f < 2; ++f) {
            int fg = (w * 2 + f) * 2;
            bf16x8 b0 = *(const bf16x8*)&kf[((fg + 0) * 64 + l) * 8];
            bf16x8 b1 = *(const bf16x8*)&kf[((fg + 1) * 64 + l) * 8];
#pragma unroll
            for (int fr = 0; fr < 2; ++fr) {
                acc[fr][cc][f] = __builtin_amdgcn_mfma_f32_16x16x32_bf16(a[fr][0], b0, acc[fr][cc][f], 0, 0, 0);
                acc[fr][cc][f] = __builtin_amdgcn_mfma_f32_16x16x32_bf16(a[fr][1], b1, acc[fr][cc][f], 0, 0, 0);
            }
        }
    }

#pragma unroll
    for (int fr = 0; fr < 2; ++fr)
#pragma unroll
        for (int cc = 0; cc < 4; ++cc)
#pragma unroll
            for (int f = 0; f < 2; ++f)
#pragma unroll
                for (int e = 0; e < 4; ++e) acc[fr][cc][f][e] *= 0.125f;

    float rmax[2][4];
#pragma unroll
    for (int fr = 0; fr < 2; ++fr)
#pragma unroll
        for (int reg = 0; reg < 4; ++reg) {
            float m = -1e30f;
#pragma unroll
            for (int cc = 0; cc < 4; ++cc)
#pragma unroll
                for (int f = 0; f < 2; ++f) m = fmaxf(m, acc[fr][cc][f][reg]);
#pragma unroll
            for (int off = 1; off < 16; off <<= 1) m = fmaxf(m, __shfl_xor(m, off));
            if (ln == 0) redM[(fr * 16 + lg * 4 + reg) * 8 + w] = m;
            rmax[fr][reg] = m;
        }
    __syncthreads();
#pragma unroll
    for (int fr = 0; fr < 2; ++fr)
#pragma unroll
        for (int reg = 0; reg < 4; ++reg) {
            int r = fr * 16 + lg * 4 + reg;
            float m = redM[r * 8];
#pragma unroll
            for (int ww = 1; ww < 8; ++ww) m = fmaxf(m, redM[r * 8 + ww]);
            rmax[fr][reg] = m;
        }
#pragma unroll
    for (int fr = 0; fr < 2; ++fr)
#pragma unroll
        for (int reg = 0; reg < 4; ++reg) {
            float s = 0.f;
            float m = rmax[fr][reg];
#pragma unroll
            for (int cc = 0; cc < 4; ++cc)
#pragma unroll
                for (int f = 0; f < 2; ++f) {
                    float e = __expf(acc[fr][cc][f][reg] - m);
                    acc[fr][cc][f][reg] = e;
                    s += e;
                }
#pragma unroll
            for (int off = 1; off < 16; off <<= 1) s += __shfl_xor(s, off);
            if (ln == 0) redS[(fr * 16 + lg * 4 + reg) * 8 + w] = s;
        }
    __syncthreads();
    float* visp = vis + (((size_t)(b * 4 + h)) << 20);
#pragma unroll
    for (int fr = 0; fr < 2; ++fr)
#pragma unroll
        for (int reg = 0; reg < 4; ++reg) {
            int r = fr * 16 + lg * 4 + reg;
            float s = redS[r * 8] + redS[r * 8 + 1] + redS[r * 8 + 2] + redS[r * 8 + 3]
                    + redS[r * 8 + 4] + redS[r * 8 + 5] + redS[r * 8 + 6] + redS[r * 8 + 7];
            float inv = 1.f / s;
            float* vr = visp + (size_t)(l0 + r) * 1024 + w * 32 + ln;
#pragma unroll
            for (int cc = 0; cc < 4; ++cc)
#pragma unroll
                for (int f = 0; f < 2; ++f)
                    vr[cc * 256 + f * 16] = acc[fr][cc][f][reg] * inv;
        }
}

// ---------------------------------------------------------------------------
// Linear attention (validated R2).
// ---------------------------------------------------------------------------
__global__ __launch_bounds__(256) void kv_kernel(const float* __restrict__ k,
                                                 const float* __restrict__ v,
                                                 float* __restrict__ KVp,
                                                 float* __restrict__ Ksump)
{
    __shared__ float4 Kt4[64*17];
    __shared__ float4 Vt4[64*16];
    float* Kt = (float*)Kt4;
    float* Vt = (float*)Vt4;
    const int t = threadIdx.x;
    const int bx = blockIdx.x;
    const int b = bx >> 4, h = (bx >> 2) & 3, ch = bx & 3;
    const float* kb = k + ((size_t)b*256 + h*64)*1024 + ch*256;
    const float* vb = v + ((size_t)b*256 + h*64)*1024 + ch*256;
    const int d = t >> 2, v0 = (t & 3) * 16;
    float4 acc[4];
#pragma unroll
    for (int j = 0; j < 4; ++j) acc[j] = make_float4(0.f, 0.f, 0.f, 0.f);
    float ks = 0.f;
    for (int st = 0; st < 4; ++st) {
        __syncthreads();
        {
            int dd = t >> 2, r0 = (t & 3) * 16;
#pragma unroll
            for (int mm = 0; mm < 4; ++mm) {
                float4 kv = *(const float4*)(kb + dd*1024 + st*64 + r0 + mm*4);
                Kt[(r0+mm*4+0)*68 + dd] = elu1(kv.x);
                Kt[(r0+mm*4+1)*68 + dd] = elu1(kv.y);
                Kt[(r0+mm*4+2)*68 + dd] = elu1(kv.z);
                Kt[(r0+mm*4+3)*68 + dd] = elu1(kv.w);
                float4 vv = *(const float4*)(vb + dd*1024 + st*64 + r0 + mm*4);
                Vt[(r0+mm*4+0)*64 + dd] = vv.x;
                Vt[(r0+mm*4+1)*64 + dd] = vv.y;
                Vt[(r0+mm*4+2)*64 + dd] = vv.z;
                Vt[(r0+mm*4+3)*64 + dd] = vv.w;
            }
        }
        __syncthreads();
#pragma unroll 8
        for (int s = 0; s < 64; ++s) {
            float kf = Kt[s*68 + d];
            const float4* vp = (const float4*)(Vt + s*64 + v0);
#pragma unroll
            for (int j = 0; j < 4; ++j) {
                float4 vv = vp[j];
                acc[j].x += kf*vv.x; acc[j].y += kf*vv.y;
                acc[j].z += kf*vv.z; acc[j].w += kf*vv.w;
            }
        }
        if (t < 64) {
#pragma unroll 8
            for (int s = 0; s < 64; ++s) ks += Kt[s*68 + t];
        }
    }
    float* op = KVp + ((size_t)((ch*32 + b*4 + h)*64 + d))*64 + v0;
#pragma unroll
    for (int j = 0; j < 4; ++j) ((float4*)op)[j] = acc[j];
    if (t < 64) Ksump[(size_t)(ch*32 + b*4 + h)*64 + t] = ks;
}

__global__ __launch_bounds__(256) void msg_kernel(const float* __restrict__ q,
                                                  const float* __restrict__ KVp,
                                                  const float* __restrict__ Ksump,
                                                  float* __restrict__ msg)
{
    __shared__ float4 kvl4[4*1028];
    __shared__ float ksl[4*65];
    float* kvl = (float*)kvl4;
    const int t = threadIdx.x;
    const int bx = blockIdx.x;
    const int b = bx >> 4;
    const int l0 = (bx & 15) * 64;
    for (int m = 0; m < 64; ++m) {
        int idx = t + 256*m;
        int hh = idx >> 12, dd = (idx >> 6) & 63, vv = idx & 63;
        float s = 0.f;
#pragma unroll
        for (int ch = 0; ch < 4; ++ch)
            s += KVp[(size_t)((ch*32 + b*4))*4096 + idx];
        kvl[hh*4112 + dd*64 + vv] = s;
    }
    {
        float s = 0.f;
#pragma unroll
        for (int ch = 0; ch < 4; ++ch)
            s += Ksump[(size_t)(ch*32 + b*4)*64 + t];
        ksl[(t >> 6)*65 + (t & 63)] = s;
    }
    __syncthreads();
    const int h = t & 3, l = l0 + (t >> 2);
    const float* qb = q + ((size_t)b*256 + h*64)*1024 + l;
    float qf[64];
#pragma unroll
    for (int dd = 0; dd < 64; ++dd) qf[dd] = elu1(qb[dd*1024]);
    float zd = 1e-6f;
#pragma unroll
    for (int dd = 0; dd < 64; ++dd) zd += qf[dd] * ksl[h*65 + dd];
    const float Z = 1.f / zd;
    float* op = msg + ((size_t)(b*1024 + l))*256 + h*64;
    for (int c0 = 0; c0 < 64; c0 += 16) {
        float4 a[4];
#pragma unroll
        for (int j = 0; j < 4; ++j) a[j] = make_float4(0.f, 0.f, 0.f, 0.f);
#pragma unroll
        for (int dd = 0; dd < 64; ++dd) {
            float qv = qf[dd];
            const float4* kp = (const float4*)(kvl + h*4112 + dd*64 + c0);
#pragma unroll
            for (int j = 0; j < 4; ++j) {
                float4 kk = kp[j];
                a[j].x += qv*kk.x; a[j].y += qv*kk.y;
                a[j].z += qv*kk.z; a[j].w += qv*kk.w;
            }
        }
#pragma unroll
        for (int j = 0; j < 4; ++j) {
            a[j].x *= Z; a[j].y *= Z; a[j].z *= Z; a[j].w *= Z;
            ((float4*)(op + c0))[j] = a[j];
        }
    }
}

__global__ __launch_bounds__(256) void merge_ln1_kernel(const float* __restrict__ msg,
                                                        const float* __restrict__ Wm,
                                                        const float* __restrict__ g1,
                                                        const float* __restrict__ b1,
                                                        float* __restrict__ msgm)
{
    __shared__ float4 mL4[16*65];
    __shared__ float mv[32];
    float* mL = (float*)mL4;
    const int t = threadIdx.x;
    const size_t base = (size_t)blockIdx.x * 16;
    {
        int r = t >> 4, cb = t & 15;
#pragma unroll
        for (int j = 0; j < 16; ++j)
            mL[r*260 + cb + 16*j] = msg[(base + r)*256 + cb + 16*j];
    }
    __syncthreads();
    float acc[16];
#pragma unroll
    for (int r = 0; r < 16; ++r) acc[r] = 0.f;
    for (int i = 0; i < 256; i += 4) {
        float w0 = Wm[(size_t)(i+0)*256 + t];
        float w1 = Wm[(size_t)(i+1)*256 + t];
        float w2 = Wm[(size_t)(i+2)*256 + t];
        float w3 = Wm[(size_t)(i+3)*256 + t];
#pragma unroll
        for (int r = 0; r < 16; ++r) {
            float4 m4 = mL4[r*65 + (i >> 2)];
            acc[r] += m4.x*w0 + m4.y*w1 + m4.z*w2 + m4.w*w3;
        }
    }
    __syncthreads();
#pragma unroll
    for (int r = 0; r < 16; ++r) mL[r*260 + t] = acc[r];
    __syncthreads();
    {
        int wid = t >> 6, lane = t & 63;
#pragma unroll
        for (int rr = 0; rr < 4; ++rr) {
            int r = wid*4 + rr;
            float s1 = 0.f, s2 = 0.f;
#pragma unroll
            for (int m = 0; m < 4; ++m) {
                float vv = mL[r*260 + lane + 64*m];
                s1 += vv; s2 += vv*vv;
            }
#pragma unroll
            for (int off = 1; off < 64; off <<= 1) {
                s1 += __shfl_xor(s1, off);
                s2 += __shfl_xor(s2, off);
            }
            if (lane == 0) {
                float mean = s1 * (1.f/256.f);
                float var  = s2 * (1.f/256.f) - mean*mean;
                mv[r*2]   = mean;
                mv[r*2+1] = rsqrtf(var + 1e-5f);
            }
        }
    }
    __syncthreads();
    const float gg = g1[t], bb = b1[t];
#pragma unroll
    for (int r = 0; r < 16; ++r) {
        float val = (mL[r*260 + t] - mv[r*2]) * mv[r*2+1] * gg + bb;
        msgm[(base + r)*256 + t] = val;
    }
}

// ===========================================================================
// FF via MFMA (validated R4).
// ===========================================================================
__global__ __launch_bounds__(256) void ff_mfma_kernel(
    const float* __restrict__ x, const float* __restrict__ msgm,
    const u16* __restrict__ w1p, const u16* __restrict__ w2p,
    const float* __restrict__ g2, const float* __restrict__ b2,
    float* __restrict__ out)
{
    __shared__ u16 tile[32 * 520];
    __shared__ float redS[32 * 4];
    __shared__ float redQ[32 * 4];
    float* tf = (float*)tile;
    const int t = threadIdx.x;
    const int base = blockIdx.x * 32;       // 256 blocks
    const int b = base >> 10, l0 = base & 1023;
    const int w = t >> 6, l = t & 63, ln = l & 15, lg = l >> 4;

    {
        int rr = t & 31, cg = t >> 5;
        for (int cci = 0; cci < 32; ++cci) {
            int c = cci * 8 + cg;
            float v = x[((size_t)b * 256 + c) * 1024 + l0 + rr];
            tile[rr * 520 + c] = f2bf(v);
        }
        int r = t >> 3, cb = (t & 7) * 32;
#pragma unroll
        for (int i = 0; i < 8; ++i) {
            float4 v = *(const float4*)&msgm[((size_t)(base + r)) * 256 + cb + i * 4];
            u32 p0 = (u32)f2bf(v.x) | ((u32)f2bf(v.y) << 16);
            u32 p1 = (u32)f2bf(v.z) | ((u32)f2bf(v.w) << 16);
            *(u32*)&tile[r * 520 + 256 + cb + i * 4] = p0;
            *(u32*)&tile[r * 520 + 256 + cb + i * 4 + 2] = p1;
        }
    }
    __syncthreads();

    f32x4 acc[2][8];
#pragma unroll
    for (int fr = 0; fr < 2; ++fr)
#pragma unroll
        for (int fc = 0; fc < 8; ++fc) acc[fr][fc] = (f32x4){0.f, 0.f, 0.f, 0.f};
    for (int ks = 0; ks < 16; ++ks) {
        bf16x8 a0 = *(const bf16x8*)&tile[(ln) * 520 + ks * 32 + lg * 8];
        bf16x8 a1 = *(const bf16x8*)&tile[(16 + ln) * 520 + ks * 32 + lg * 8];
#pragma unroll
        for (int fc = 0; fc < 8; ++fc) {
            bf16x8 bb = *(const bf16x8*)&w1p[((size_t)(ks * 32 + w * 8 + fc) * 64 + l) * 8];
            acc[0][fc] = __builtin_amdgcn_mfma_f32_16x16x32_bf16(a0, bb, acc[0][fc], 0, 0, 0);
            acc[1][fc] = __builtin_amdgcn_mfma_f32_16x16x32_bf16(a1, bb, acc[1][fc], 0, 0, 0);
        }
    }
    __syncthreads();
#pragma unroll
    for (int fr = 0; fr < 2; ++fr)
#pragma unroll
        for (int fc = 0; fc < 8; ++fc)
#pragma unroll
            for (int reg = 0; reg < 4; ++reg) {
                int r = fr * 16 + lg * 4 + reg;
                int c = w * 128 + fc * 16 + ln;
                tile[r * 520 + c] = f2bf(fmaxf(acc[fr][fc][reg], 0.f));
            }
    __syncthreads();

    f32x4 acc2[2][4];
#pragma unroll
    for (int fr = 0; fr < 2; ++fr)
#pragma unroll
        for (int fc = 0; fc < 4; ++fc) acc2[fr][fc] = (f32x4){0.f, 0.f, 0.f, 0.f};
    for (int ks = 0; ks < 16; ++ks) {
        bf16x8 a0 = *(const bf16x8*)&tile[(ln) * 520 + ks * 32 + lg * 8];
        bf16x8 a1 = *(const bf16x8*)&tile[(16 + ln) * 520 + ks * 32 + lg * 8];
#pragma unroll
        for (int fc = 0; fc < 4; ++fc) {
            bf16x8 bb = *(const bf16x8*)&w2p[((size_t)(ks * 16 + w * 4 + fc) * 64 + l) * 8];
            acc2[0][fc] = __builtin_amdgcn_mfma_f32_16x16x32_bf16(a0, bb, acc2[0][fc], 0, 0, 0);
            acc2[1][fc] = __builtin_amdgcn_mfma_f32_16x16x32_bf16(a1, bb, acc2[1][fc], 0, 0, 0);
        }
    }
#pragma unroll
    for (int fr = 0; fr < 2; ++fr)
#pragma unroll
        for (int reg = 0; reg < 4; ++reg) {
            float s = 0.f, qsum = 0.f;
#pragma unroll
            for (int fc = 0; fc < 4; ++fc) {
                float v = acc2[fr][fc][reg];
                s += v; qsum += v * v;
            }
#pragma unroll
            for (int off = 1; off < 16; off <<= 1) {
                s += __shfl_xor(s, off);
                qsum += __shfl_xor(qsum, off);
            }
            if (ln == 0) {
                int r = fr * 16 + lg * 4 + reg;
                redS[r * 4 + w] = s;
                redQ[r * 4 + w] = qsum;
            }
        }
    __syncthreads();
    float mean[2][4], rstd[2][4];
#pragma unroll
    for (int fr = 0; fr < 2; ++fr)
#pragma unroll
        for (int reg = 0; reg < 4; ++reg) {
            int r = fr * 16 + lg * 4 + reg;
            float s = redS[r * 4] + redS[r * 4 + 1] + redS[r * 4 + 2] + redS[r * 4 + 3];
            float qs = redQ[r * 4] + redQ[r * 4 + 1] + redQ[r * 4 + 2] + redQ[r * 4 + 3];
            float m = s * (1.f / 256.f);
            mean[fr][reg] = m;
            rstd[fr][reg] = rsqrtf(qs * (1.f / 256.f) - m * m + 1e-5f);
        }
#pragma unroll
    for (int fc = 0; fc < 4; ++fc) {
        int c = w * 64 + fc * 16 + ln;
        float gg = g2[c], bb = b2[c];
#pragma unroll
        for (int fr = 0; fr < 2; ++fr)
#pragma unroll
            for (int reg = 0; reg < 4; ++reg) {
                int r = fr * 16 + lg * 4 + reg;
                tf[r * 260 + c] = (acc2[fr][fc][reg] - mean[fr][reg]) * rstd[fr][reg] * gg + bb;
            }
    }
    __syncthreads();
    {
        const float* xp = x + ((size_t)b * 256 + t) * 1024 + l0;
        float* op = out + ((size_t)b * 256 + t) * 1024 + l0;
#pragma unroll
        for (int i = 0; i < 8; ++i) {
            float4 xv = *(const float4*)(xp + i * 4);
            float4 o;
            o.x = xv.x + tf[(i * 4 + 0) * 260 + t];
            o.y = xv.y + tf[(i * 4 + 1) * 260 + t];
            o.z = xv.z + tf[(i * 4 + 2) * 260 + t];
            o.w = xv.w + tf[(i * 4 + 3) * 260 + t];
            *(float4*)(op + i * 4) = o;
        }
    }
}

// ---------------------------------------------------------------------------
extern "C" void kernel_launch(void* const* d_in, const int* in_sizes, int n_in,
                              void* d_out, int out_size, void* d_ws, size_t ws_size,
                              hipStream_t stream)
{
    const float* x    = (const float*)d_in[0];
    const float* src  = (const float*)d_in[1];
    const float* Wq   = (const float*)d_in[2];
    const float* Wk1  = (const float*)d_in[3];
    const float* Wk3  = (const float*)d_in[4];
    const float* Wk5  = (const float*)d_in[5];
    const float* Wk7  = (const float*)d_in[6];
    const float* Wv1  = (const float*)d_in[7];
    const float* Wv3  = (const float*)d_in[8];
    const float* Wv5  = (const float*)d_in[9];
    const float* Wv7  = (const float*)d_in[10];
    const float* Wm   = (const float*)d_in[11];
    const float* g1   = (const float*)d_in[12];
    const float* b1   = (const float*)d_in[13];
    const float* g2   = (const float*)d_in[14];
    const float* b2   = (const float*)d_in[15];
    const float* W1   = (const float*)d_in[16];
    const float* W2   = (const float*)d_in[17];

    float* out = (float*)d_out;
    float* vis = out + 2097152;          // [b,h,l,s]

    // ws extent+lifetime map (float offsets; audited R6; p5/p7 ELIMINATED in
    // R10 — K5/K7 conv jobs atomicAdd directly into kb/vb heads 2,3):
    //  qb    [0,        2097152)  conv..msg_kernel
    //  kb    [2097152,  4194304)  zero/conv..kv/cast_qk
    //  vb    [4194304,  6291456)  zero/conv..kv
    //  wpack [6291456,  7962624)  repack..conv
    //    then w1p [6291456, 6422528) repack_ff..ff
    //         w2p [6422528, 6488064) repack_ff..ff
    //         qbt [6488064, 7536640) cast_qk..qk_sm
    //         kbt [7536640, 8585216) cast_qk..qk_sm (overlaps dead xbh)
    //  xbh   [7962624,  9011200)  cast_src..conv
    //  sbh   [9011200, 10059776)  cast_src..conv
    //    then msg [7962624, 10059776) msg_kernel..merge
    //  msgm  [10059776, 12156928)  merge..ff
    //  KVp   [12156928, 12681216), Ksump [12681216, 12689408)
    float* ws    = (float*)d_ws;
    float* qb    = ws;
    float* kb    = ws + 2097152;
    float* vb    = ws + 4194304;
    u16*   wpack = (u16*)(ws + 6291456);
    u16*   w1p   = (u16*)(ws + 6291456);
    u16*   w2p   = (u16*)(ws + 6422528);
    u16*   qbt   = (u16*)(ws + 6488064);
    u16*   kbt   = (u16*)(ws + 7536640);
    u16*   xbh   = (u16*)(ws + 7962624);
    u16*   sbh   = (u16*)(ws + 9011200);
    float* msg   = ws + 7962624;
    float* msgm  = ws + 10059776;
    float* KVp   = ws + 12156928;
    float* Ksump = ws + 12681216;

    repack_kernel   <<<1632, 256, 0, stream>>>(Wq, Wk1, Wk3, Wk5, Wk7,
                                               Wv1, Wv3, Wv5, Wv7, wpack);
    zero_kv_kernel  <<<2048, 256, 0, stream>>>(kb, vb);
    cast_src_kernel <<<1024, 256, 0, stream>>>(x, src, xbh, sbh);
    conv_mfma_kernel<<<512,  512, 0, stream>>>(xbh, sbh, wpack, qb, kb, vb);
    repack_ff_kernel<<<192,  256, 0, stream>>>(W1, W2, w1p, w2p);
    cast_qk_kernel  <<<1024, 256, 0, stream>>>(qb, kb, qbt, kbt);
    qk_sm_kernel    <<<1024, 512, 0, stream>>>(qbt, kbt, vis);
    kv_kernel       <<<128,  256, 0, stream>>>(kb, vb, KVp, Ksump);
    msg_kernel      <<<128,  256, 0, stream>>>(qb, KVp, Ksump, msg);
    merge_ln1_kernel<<<512,  256, 0, stream>>>(msg, Wm, g1, b1, msgm);
    ff_mfma_kernel  <<<256,  256, 0, stream>>>(x, msgm, w1p, w2p, g2, b2, out);
}

// Round 11
// 291.695 us; speedup vs baseline: 1.1183x; 1.1183x over previous
//
#include <hip/hip_runtime.h>

#define DEV __device__ __forceinline__

typedef unsigned short u16;
typedef unsigned int u32;
typedef __bf16 bf16x8 __attribute__((ext_vector_type(8)));
typedef float f32x4 __attribute__((ext_vector_type(4)));

DEV float elu1(float x) { return x > 0.f ? x + 1.f : __expf(x); }

DEV u16 f2bf(float f) {
    union { float f; unsigned u; } v; v.f = f;
    unsigned r = v.u + 0x7fffu + ((v.u >> 16) & 1u);
    return (u16)(r >> 16);
}

// ===========================================================================
// Conv weight repack (validated R2).
// ===========================================================================
__global__ __launch_bounds__(256) void repack_kernel(
    const float* __restrict__ Wq,
    const float* __restrict__ Wk1, const float* __restrict__ Wk3,
    const float* __restrict__ Wk5, const float* __restrict__ Wk7,
    const float* __restrict__ Wv1, const float* __restrict__ Wv3,
    const float* __restrict__ Wv5, const float* __restrict__ Wv7,
    u16* __restrict__ wpack)
{
    int gid = blockIdx.x * 256 + threadIdx.x;
    int frag = gid >> 6, l = gid & 63;
    const float* W; int K, ocbase = 0, rel;
    if (frag < 1152) {
        W = Wq; K = 3; int slot = frag / 288; rel = frag % 288; ocbase = slot * 64;
    } else {
        int f = frag - 1152; int side = f / 2688; f %= 2688;
        if (f < 32)        { W = side ? Wv1 : Wk1; K = 1; rel = f; }
        else if (f < 320)  { W = side ? Wv3 : Wk3; K = 3; rel = f - 32; }
        else if (f < 1120) { W = side ? Wv5 : Wk5; K = 5; rel = f - 320; }
        else               { W = side ? Wv7 : Wk7; K = 7; rel = f - 1120; }
    }
    int og = rel & 3, cc = (rel >> 2) & 7, tap = rel >> 5;
    int dy = tap / K, dx = tap % K;
    int oc = ocbase + og * 16 + (l & 15);
    int c0 = cc * 32 + (l >> 4) * 8;
    u16 pk[8];
#pragma unroll
    for (int j = 0; j < 8; ++j)
        pk[j] = f2bf(W[((size_t)(oc * 256 + c0 + j) * K + dy) * K + dx]);
    *(int4*)&wpack[(size_t)frag * 512 + l * 8] = *(const int4*)pk;
}

// ===========================================================================
// cast_src: fp32 NCHW -> bf16 blocked [b][cc8][pix1024][c32].
// ===========================================================================
__global__ __launch_bounds__(256) void cast_src_kernel(
    const float* __restrict__ x, const float* __restrict__ src,
    u16* __restrict__ xbh, u16* __restrict__ sbh)
{
    __shared__ float lds[32 * 129];
    const int i = blockIdx.x, t = threadIdx.x;   // 1024 blocks
    const int inp = i >> 9, rem = i & 511;
    const int b = rem >> 6, cc = (rem >> 3) & 7, pxb = rem & 7;
    const float* in = (inp ? src : x) + ((size_t)b * 256 + cc * 32) * 1024 + pxb * 128;
    u16* outp = (inp ? sbh : xbh) + (size_t)b * 262144 + (size_t)cc * 32768 + pxb * 128 * 32;
#pragma unroll
    for (int u = 0; u < 4; ++u) {
        int unit = t + u * 256;
        int r = unit >> 5, px4 = unit & 31;
        float4 v = *(const float4*)(in + (size_t)r * 1024 + px4 * 4);
        lds[r * 129 + px4 * 4 + 0] = v.x;
        lds[r * 129 + px4 * 4 + 1] = v.y;
        lds[r * 129 + px4 * 4 + 2] = v.z;
        lds[r * 129 + px4 * 4 + 3] = v.w;
    }
    __syncthreads();
#pragma unroll
    for (int u = 0; u < 2; ++u) {
        int unit = t + u * 256;
        int px = unit >> 2, cg = unit & 3;
        u16 pk[8];
#pragma unroll
        for (int j = 0; j < 8; ++j) pk[j] = f2bf(lds[(cg * 8 + j) * 129 + px]);
        *(int4*)&outp[px * 32 + cg * 8] = *(const int4*)pk;
    }
}

// ===========================================================================
// cast_qk: qb/kb fp32 [b][c][l] -> bf16 [b*4+h][l][64].
// ===========================================================================
__global__ __launch_bounds__(256) void cast_qk_kernel(
    const float* __restrict__ qb, const float* __restrict__ kb,
    u16* __restrict__ qbt, u16* __restrict__ kbt)
{
    __shared__ float lds[64 * 65];
    const int i = blockIdx.x, t = threadIdx.x;   // 1024 blocks
    const int inp = i >> 9, rem = i & 511;
    const int b = rem >> 6, h = (rem >> 4) & 3, pxb = rem & 15;
    const float* in = (inp ? kb : qb) + ((size_t)b * 256 + h * 64) * 1024 + pxb * 64;
    u16* outp = (inp ? kbt : qbt) + (((size_t)(b * 4 + h)) * 1024 + pxb * 64) * 64;
#pragma unroll
    for (int u = 0; u < 4; ++u) {
        int unit = t + u * 256;
        int r = unit >> 4, px4 = unit & 15;
        float4 v = *(const float4*)(in + (size_t)r * 1024 + px4 * 4);
        lds[r * 65 + px4 * 4 + 0] = v.x;
        lds[r * 65 + px4 * 4 + 1] = v.y;
        lds[r * 65 + px4 * 4 + 2] = v.z;
        lds[r * 65 + px4 * 4 + 3] = v.w;
    }
    __syncthreads();
#pragma unroll
    for (int u = 0; u < 2; ++u) {
        int unit = t + u * 256;
        int px = unit >> 3, cg = unit & 7;
        u16 pk[8];
#pragma unroll
        for (int j = 0; j < 8; ++j) pk[j] = f2bf(lds[(cg * 8 + j) * 65 + px]);
        *(int4*)&outp[px * 64 + cg * 8] = *(const int4*)pk;
    }
}

// ===========================================================================
// FF/Wm repack: W1 (512 frags), W2 (256 frags), Wm (128 frags: 8ks x 16nf).
// ===========================================================================
__global__ __launch_bounds__(256) void repack_ff_kernel(
    const float* __restrict__ W1, const float* __restrict__ W2,
    const float* __restrict__ Wm,
    u16* __restrict__ w1p, u16* __restrict__ w2p, u16* __restrict__ wmp)
{
    int gid = blockIdx.x * 256 + threadIdx.x;   // 224*256 = 57344 (896 frags)
    int f = gid >> 6, l = gid & 63;
    if (f >= 896) return;
    u16 pk[8];
    if (f < 512) {
        int ks = f >> 5, nf = f & 31;
#pragma unroll
        for (int j = 0; j < 8; ++j)
            pk[j] = f2bf(W1[(size_t)(ks * 32 + (l >> 4) * 8 + j) * 512 + nf * 16 + (l & 15)]);
        *(int4*)&w1p[(size_t)f * 512 + l * 8] = *(const int4*)pk;
    } else if (f < 768) {
        int f2 = f - 512;
        int ks = f2 >> 4, nf = f2 & 15;
#pragma unroll
        for (int j = 0; j < 8; ++j)
            pk[j] = f2bf(W2[(size_t)(ks * 32 + (l >> 4) * 8 + j) * 256 + nf * 16 + (l & 15)]);
        *(int4*)&w2p[(size_t)f2 * 512 + l * 8] = *(const int4*)pk;
    } else {
        int f3 = f - 768;
        int ks = f3 >> 4, nf = f3 & 15;
#pragma unroll
        for (int j = 0; j < 8; ++j)
            pk[j] = f2bf(Wm[(size_t)(ks * 32 + (l >> 4) * 8 + j) * 256 + nf * 16 + (l & 15)]);
        *(int4*)&wmp[(size_t)f3 * 512 + l * 8] = *(const int4*)pk;
    }
}

// ===========================================================================
// MFMA implicit-GEMM conv (exact R9 body: validated 88.7us, VGPR 108).
// ===========================================================================
template<int K>
DEV void conv_mfma_body(const u16* __restrict__ srcb,
                        const u16* __restrict__ wsec,
                        float* __restrict__ dst,
                        u16* Bt, int y0, int cch0, int ncc, int t)
{
    constexpr int P = K / 2;
    const int w = t >> 6, l = t & 63;
    const int chi = l >> 4, ln = l & 15;
    const int rowbase = chi * 22 + w * 2 + 3 - P;
    const int colbase = ln + 3 - P;
    f32x4 acc[4][4];
#pragma unroll
    for (int m = 0; m < 4; ++m)
#pragma unroll
        for (int n = 0; n < 4; ++n) acc[m][n] = (f32x4){0.f, 0.f, 0.f, 0.f};

    for (int cc = 0; cc < ncc; ++cc) {
        const int ccg = cch0 + cc;
        __syncthreads();
#pragma unroll
        for (int u = 0; u < 7; ++u) {
            int unit = t + (u << 9);
            if (unit < 2816) {
                int xv = unit & 31, r = unit >> 5;
                int yy = r % 22, ch = r / 22;
                int ygl = y0 - 3 + yy;
                int4 pk;
                if ((unsigned)ygl < 32u)
                    pk = *(const int4*)&srcb[(size_t)ccg * 32768 + (ygl * 32 + xv) * 32 + ch * 8];
                else
                    pk = (int4){0, 0, 0, 0};
                *(int4*)&Bt[((ch * 22 + yy) * 40 + xv + 3) * 8] = pk;
            } else if (unit < 3520) {
                int hu = unit - 2816;
                int hx = hu & 7; int xi = hx < 3 ? hx : hx + 32;
                int r = hu >> 3; int yy = r % 22, ch = r / 22;
                int4 z = {0, 0, 0, 0};
                *(int4*)&Bt[((ch * 22 + yy) * 40 + xi) * 8] = z;
            }
        }
        __syncthreads();
#pragma unroll
        for (int dy = 0; dy < K; ++dy) {
#pragma unroll
            for (int dx = 0; dx < K; ++dx) {
                const int tap = dy * K + dx;
                const u16* wp = wsec + ((size_t)(tap * 8 + ccg) * 4) * 512 + l * 8;
                bf16x8 a0 = *(const bf16x8*)(wp);
                bf16x8 a1 = *(const bf16x8*)(wp + 512);
                bf16x8 a2 = *(const bf16x8*)(wp + 1024);
                bf16x8 a3 = *(const bf16x8*)(wp + 1536);
                bf16x8 bf[4];
#pragma unroll
                for (int n = 0; n < 4; ++n) {
                    int row = rowbase + dy + (n >> 1);
                    int col = colbase + dx + (n & 1) * 16;
                    bf[n] = *(const bf16x8*)&Bt[(row * 40 + col) * 8];
                }
#pragma unroll
                for (int n = 0; n < 4; ++n) {
                    acc[0][n] = __builtin_amdgcn_mfma_f32_16x16x32_bf16(a0, bf[n], acc[0][n], 0, 0, 0);
                    acc[1][n] = __builtin_amdgcn_mfma_f32_16x16x32_bf16(a1, bf[n], acc[1][n], 0, 0, 0);
                    acc[2][n] = __builtin_amdgcn_mfma_f32_16x16x32_bf16(a2, bf[n], acc[2][n], 0, 0, 0);
                    acc[3][n] = __builtin_amdgcn_mfma_f32_16x16x32_bf16(a3, bf[n], acc[3][n], 0, 0, 0);
                }
            }
        }
    }
#pragma unroll
    for (int m = 0; m < 4; ++m)
#pragma unroll
        for (int n = 0; n < 4; ++n) {
            int y = y0 + w * 2 + (n >> 1);
            int px = y * 32 + (n & 1) * 16 + ln;
            int ocb = m * 16 + chi * 4;
#pragma unroll
            for (int r = 0; r < 4; ++r)
                dst[(size_t)(ocb + r) * 1024 + px] = acc[m][n][r];
        }
}

// Job decode (R9 XCD grouping): bx = m*256 + b*32 + g, grid 512. XCD = g%8.
__global__ __launch_bounds__(512) void conv_mfma_kernel(
    const u16* __restrict__ xbh, const u16* __restrict__ sbh,
    const u16* __restrict__ wpack,
    float* __restrict__ qb, float* __restrict__ kb, float* __restrict__ vb,
    float* __restrict__ p5, float* __restrict__ p7)
{
    __shared__ u16 Bt[4 * 22 * 40 * 8];
    const int bx = blockIdx.x, t = threadIdx.x;
    const int g = bx & 31, b = (bx >> 5) & 7, m = bx >> 8;
    if (g < 4) {
        conv_mfma_body<3>(xbh + (size_t)b * 262144,
                          wpack + (size_t)(g * 288) * 512,
                          qb + ((size_t)b * 256 + g * 64) * 1024,
                          Bt, m * 16, 0, 8, t);
        return;
    }
    const int gs = g - 4;
    const int side = gs / 14, gg = gs % 14;
    const u16* sp = sbh + (size_t)b * 262144;
    float* fin = side ? vb : kb;
    const size_t wkb = 1152 + (size_t)side * 2688;
    if (gg == 0) {
        conv_mfma_body<1>(sp, wpack + (wkb + 0) * 512,
                          fin + ((size_t)b * 256) * 1024, Bt, m * 16, 0, 8, t);
    } else if (gg == 1) {
        conv_mfma_body<3>(sp, wpack + (wkb + 32) * 512,
                          fin + ((size_t)b * 256 + 64) * 1024, Bt, m * 16, 0, 8, t);
    } else if (gg < 6) {
        int cpart = gg - 2;
        conv_mfma_body<5>(sp, wpack + (wkb + 320) * 512,
                          p5 + (((size_t)side * 4 + cpart) * 8 + b) * 65536,
                          Bt, m * 16, cpart * 2, 2, t);
    } else {
        int cpart = gg - 6;
        conv_mfma_body<7>(sp, wpack + (wkb + 1120) * 512,
                          p7 + (((size_t)side * 8 + cpart) * 8 + b) * 65536,
                          Bt, m * 16, cpart, 1, t);
    }
}

__global__ __launch_bounds__(256) void reduce_kernel(
    const float* __restrict__ p5, const float* __restrict__ p7,
    float* __restrict__ kb, float* __restrict__ vb)
{
    int gid = blockIdx.x * 256 + threadIdx.x;   // 2048 blocks -> 524288 units
    int px4 = gid & 255;
    int rr = gid >> 8;
    int oc = rr & 63, b = (rr >> 6) & 7, head = (rr >> 9) & 1, side = rr >> 10;
    float* outb = side ? vb : kb;
    float4 s = make_float4(0.f, 0.f, 0.f, 0.f);
    if (head == 0) {
#pragma unroll
        for (int p = 0; p < 4; ++p) {
            float4 u = *((const float4*)(p5 + (((size_t)side * 4 + p) * 8 + b) * 65536 + (size_t)oc * 1024) + px4);
            s.x += u.x; s.y += u.y; s.z += u.z; s.w += u.w;
        }
        *((float4*)(outb + ((size_t)b * 256 + 128 + oc) * 1024) + px4) = s;
    } else {
#pragma unroll
        for (int p = 0; p < 8; ++p) {
            float4 u = *((const float4*)(p7 + (((size_t)side * 8 + p) * 8 + b) * 65536 + (size_t)oc * 1024) + px4);
            s.x += u.x; s.y += u.y; s.z += u.z; s.w += u.w;
        }
        *((float4*)(outb + ((size_t)b * 256 + 192 + oc) * 1024) + px4) = s;
    }
}

// ===========================================================================
// Fused QK^T + softmax -> vis (validated R4/R6).
// ===========================================================================
__global__ __launch_bounds__(512) void qk_sm_kernel(const u16* __restrict__ qbt,
                                                    const u16* __restrict__ kbt,
                                                    float* __restrict__ vis)
{
    __shared__ u16 kf[32 * 512];
    __shared__ u16 qf[4 * 512];
    __shared__ float redM[32 * 8];
    __shared__ float redS[32 * 8];
    const int t = threadIdx.x;
    const int bx = blockIdx.x;          // 8b*4h*32lt = 1024
    const int b = bx >> 7, h = (bx >> 5) & 3, l0 = (bx & 31) * 32;
    const u16* qtp = qbt + ((size_t)(b * 4 + h)) * 1024 * 64;
    const u16* ktp = kbt + ((size_t)(b * 4 + h)) * 1024 * 64;

    if (t < 256) {
        int r = t & 31, dblk = t >> 5;
        int4 pk = *(const int4*)&qtp[(size_t)(l0 + r) * 64 + dblk * 8];
        *(int4*)&qf[(((r >> 4) * 2 + (dblk >> 2)) * 64 + (dblk & 3) * 16 + (r & 15)) * 8] = pk;
    }
    __syncthreads();

    const int w = t >> 6, l = t & 63, ln = l & 15, lg = l >> 4;
    bf16x8 a[2][2];
#pragma unroll
    for (int fr = 0; fr < 2; ++fr)
#pragma unroll
        for (int ks = 0; ks < 2; ++ks)
            a[fr][ks] = *(const bf16x8*)&qf[((fr * 2 + ks) * 64 + l) * 8];

    f32x4 acc[2][4][2];
#pragma unroll
    for (int fr = 0; fr < 2; ++fr)
#pragma unroll
        for (int cc = 0; cc < 4; ++cc)
#pragma unroll
            for (int f = 0; f < 2; ++f) acc[fr][cc][f] = (f32x4){0.f, 0.f, 0.f, 0.f};

#pragma unroll
    for (int cc = 0; cc < 4; ++cc) {
        __syncthreads();
#pragma unroll
        for (int it = 0; it < 4; ++it) {
            int unit = it * 512 + t;
            int sl = unit & 255, dblk = unit >> 8;
            int4 pk = *(const int4*)&ktp[(size_t)(cc * 256 + sl) * 64 + dblk * 8];
            *(int4*)&kf[(((sl >> 4) * 2 + (dblk >> 2)) * 64 + (dblk & 3) * 16 + (sl & 15)) * 8] = pk;
        }
        __syncthreads();
#pragma unroll
        for (int f = 0; f < 2; ++f) {
            int fg = (w * 2 + f) * 2;
            bf16x8 b0 = *(const bf16x8*)&kf[((fg + 0) * 64 + l) * 8];
            bf16x8 b1 = *(const bf16x8*)&kf[((fg + 1) * 64 + l) * 8];
#pragma unroll
            for (int fr = 0; fr < 2; ++fr) {
                acc[fr][cc][f] = __builtin_amdgcn_mfma_f32_16x16x32_bf16(a[fr][0], b0, acc[fr][cc][f], 0, 0, 0);
                acc[fr][cc][f] = __builtin_amdgcn_mfma_f32_16x16x32_bf16(a[fr][1], b1, acc[fr][cc][f], 0, 0, 0);
            }
        }
    }

#pragma unroll
    for (int fr = 0; fr < 2; ++fr)
#pragma unroll
        for (int cc = 0; cc < 4; ++cc)
#pragma unroll
            for (int f = 0; f < 2; ++f)
#pragma unroll
                for (int e = 0; e < 4; ++e) acc[fr][cc][f][e] *= 0.125f;

    float rmax[2][4];
#pragma unroll
    for (int fr = 0; fr < 2; ++fr)
#pragma unroll
        for (int reg = 0; reg < 4; ++reg) {
            float m = -1e30f;
#pragma unroll
            for (int cc = 0; cc < 4; ++cc)
#pragma unroll
                for (int f = 0; f < 2; ++f) m = fmaxf(m, acc[fr][cc][f][reg]);
#pragma unroll
            for (int off = 1; off < 16; off <<= 1) m = fmaxf(m, __shfl_xor(m, off));
            if (ln == 0) redM[(fr * 16 + lg * 4 + reg) * 8 + w] = m;
            rmax[fr][reg] = m;
        }
    __syncthreads();
#pragma unroll
    for (int fr = 0; fr < 2; ++fr)
#pragma unroll
        for (int reg = 0; reg < 4; ++reg) {
            int r = fr * 16 + lg * 4 + reg;
            float m = redM[r * 8];
#pragma unroll
            for (int ww = 1; ww < 8; ++ww) m = fmaxf(m, redM[r * 8 + ww]);
            rmax[fr][reg] = m;
        }
#pragma unroll
    for (int fr = 0; fr < 2; ++fr)
#pragma unroll
        for (int reg = 0; reg < 4; ++reg) {
            float s = 0.f;
            float m = rmax[fr][reg];
#pragma unroll
            for (int cc = 0; cc < 4; ++cc)
#pragma unroll
                for (int f = 0; f < 2; ++f) {
                    float e = __expf(acc[fr][cc][f][reg] - m);
                    acc[fr][cc][f][reg] = e;
                    s += e;
                }
#pragma unroll
            for (int off = 1; off < 16; off <<= 1) s += __shfl_xor(s, off);
            if (ln == 0) redS[(fr * 16 + lg * 4 + reg) * 8 + w] = s;
        }
    __syncthreads();
    float* visp = vis + (((size_t)(b * 4 + h)) << 20);
#pragma unroll
    for (int fr = 0; fr < 2; ++fr)
#pragma unroll
        for (int reg = 0; reg < 4; ++reg) {
            int r = fr * 16 + lg * 4 + reg;
            float s = redS[r * 8] + redS[r * 8 + 1] + redS[r * 8 + 2] + redS[r * 8 + 3]
                    + redS[r * 8 + 4] + redS[r * 8 + 5] + redS[r * 8 + 6] + redS[r * 8 + 7];
            float inv = 1.f / s;
            float* vr = visp + (size_t)(l0 + r) * 1024 + w * 32 + ln;
#pragma unroll
            for (int cc = 0; cc < 4; ++cc)
#pragma unroll
                for (int f = 0; f < 2; ++f)
                    vr[cc * 256 + f * 16] = acc[fr][cc][f][reg] * inv;
        }
}

// ---------------------------------------------------------------------------
// Linear attention (validated R2).
// ---------------------------------------------------------------------------
__global__ __launch_bounds__(256) void kv_kernel(const float* __restrict__ k,
                                                 const float* __restrict__ v,
                                                 float* __restrict__ KVp,
                                                 float* __restrict__ Ksump)
{
    __shared__ float4 Kt4[64*17];
    __shared__ float4 Vt4[64*16];
    float* Kt = (float*)Kt4;
    float* Vt = (float*)Vt4;
    const int t = threadIdx.x;
    const int bx = blockIdx.x;
    const int b = bx >> 4, h = (bx >> 2) & 3, ch = bx & 3;
    const float* kb = k + ((size_t)b*256 + h*64)*1024 + ch*256;
    const float* vb = v + ((size_t)b*256 + h*64)*1024 + ch*256;
    const int d = t >> 2, v0 = (t & 3) * 16;
    float4 acc[4];
#pragma unroll
    for (int j = 0; j < 4; ++j) acc[j] = make_float4(0.f, 0.f, 0.f, 0.f);
    float ks = 0.f;
    for (int st = 0; st < 4; ++st) {
        __syncthreads();
        {
            int dd = t >> 2, r0 = (t & 3) * 16;
#pragma unroll
            for (int mm = 0; mm < 4; ++mm) {
                float4 kv = *(const float4*)(kb + dd*1024 + st*64 + r0 + mm*4);
                Kt[(r0+mm*4+0)*68 + dd] = elu1(kv.x);
                Kt[(r0+mm*4+1)*68 + dd] = elu1(kv.y);
                Kt[(r0+mm*4+2)*68 + dd] = elu1(kv.z);
                Kt[(r0+mm*4+3)*68 + dd] = elu1(kv.w);
                float4 vv = *(const float4*)(vb + dd*1024 + st*64 + r0 + mm*4);
                Vt[(r0+mm*4+0)*64 + dd] = vv.x;
                Vt[(r0+mm*4+1)*64 + dd] = vv.y;
                Vt[(r0+mm*4+2)*64 + dd] = vv.z;
                Vt[(r0+mm*4+3)*64 + dd] = vv.w;
            }
        }
        __syncthreads();
#pragma unroll 8
        for (int s = 0; s < 64; ++s) {
            float kf = Kt[s*68 + d];
            const float4* vp = (const float4*)(Vt + s*64 + v0);
#pragma unroll
            for (int j = 0; j < 4; ++j) {
                float4 vv = vp[j];
                acc[j].x += kf*vv.x; acc[j].y += kf*vv.y;
                acc[j].z += kf*vv.z; acc[j].w += kf*vv.w;
            }
        }
        if (t < 64) {
#pragma unroll 8
            for (int s = 0; s < 64; ++s) ks += Kt[s*68 + t];
        }
    }
    float* op = KVp + ((size_t)((ch*32 + b*4 + h)*64 + d))*64 + v0;
#pragma unroll
    for (int j = 0; j < 4; ++j) ((float4*)op)[j] = acc[j];
    if (t < 64) Ksump[(size_t)(ch*32 + b*4 + h)*64 + t] = ks;
}

__global__ __launch_bounds__(256) void msg_kernel(const float* __restrict__ q,
                                                  const float* __restrict__ KVp,
                                                  const float* __restrict__ Ksump,
                                                  float* __restrict__ msg)
{
    __shared__ float4 kvl4[4*1028];
    __shared__ float ksl[4*65];
    float* kvl = (float*)kvl4;
    const int t = threadIdx.x;
    const int bx = blockIdx.x;
    const int b = bx >> 4;
    const int l0 = (bx & 15) * 64;
    for (int m = 0; m < 64; ++m) {
        int idx = t + 256*m;
        int hh = idx >> 12, dd = (idx >> 6) & 63, vv = idx & 63;
        float s = 0.f;
#pragma unroll
        for (int ch = 0; ch < 4; ++ch)
            s += KVp[(size_t)((ch*32 + b*4))*4096 + idx];
        kvl[hh*4112 + dd*64 + vv] = s;
    }
    {
        float s = 0.f;
#pragma unroll
        for (int ch = 0; ch < 4; ++ch)
            s += Ksump[(size_t)(ch*32 + b*4)*64 + t];
        ksl[(t >> 6)*65 + (t & 63)] = s;
    }
    __syncthreads();
    const int h = t & 3, l = l0 + (t >> 2);
    const float* qb = q + ((size_t)b*256 + h*64)*1024 + l;
    float qf[64];
#pragma unroll
    for (int dd = 0; dd < 64; ++dd) qf[dd] = elu1(qb[dd*1024]);
    float zd = 1e-6f;
#pragma unroll
    for (int dd = 0; dd < 64; ++dd) zd += qf[dd] * ksl[h*65 + dd];
    const float Z = 1.f / zd;
    float* op = msg + ((size_t)(b*1024 + l))*256 + h*64;
    for (int c0 = 0; c0 < 64; c0 += 16) {
        float4 a[4];
#pragma unroll
        for (int j = 0; j < 4; ++j) a[j] = make_float4(0.f, 0.f, 0.f, 0.f);
#pragma unroll
        for (int dd = 0; dd < 64; ++dd) {
            float qv = qf[dd];
            const float4* kp = (const float4*)(kvl + h*4112 + dd*64 + c0);
#pragma unroll
            for (int j = 0; j < 4; ++j) {
                float4 kk = kp[j];
                a[j].x += qv*kk.x; a[j].y += qv*kk.y;
                a[j].z += qv*kk.z; a[j].w += qv*kk.w;
            }
        }
#pragma unroll
        for (int j = 0; j < 4; ++j) {
            a[j].x *= Z; a[j].y *= Z; a[j].z *= Z; a[j].w *= Z;
            ((float4*)(op + c0))[j] = a[j];
        }
    }
}

// ===========================================================================
// merge via MFMA: msgm = LN1(msg @ Wm). Same structure as ff GEMM2 (validated
// R4): 32-row tiles, 256 threads, wave w -> cols w*64..+64, 8 k-steps.
// ===========================================================================
__global__ __launch_bounds__(256) void merge_mfma_kernel(
    const float* __restrict__ msg, const u16* __restrict__ wmp,
    const float* __restrict__ g1, const float* __restrict__ b1,
    float* __restrict__ msgm)
{
    __shared__ u16 tile[32 * 520];
    __shared__ float redS[32 * 4];
    __shared__ float redQ[32 * 4];
    const int t = threadIdx.x;
    const int base = blockIdx.x * 32;       // 256 blocks
    const int w = t >> 6, l = t & 63, ln = l & 15, lg = l >> 4;

    // stage msg tile bf16 [32][256] (stride 520)
    {
        int r = t >> 3, cb = (t & 7) * 32;
#pragma unroll
        for (int i = 0; i < 8; ++i) {
            float4 v = *(const float4*)&msg[((size_t)(base + r)) * 256 + cb + i * 4];
            u32 p0 = (u32)f2bf(v.x) | ((u32)f2bf(v.y) << 16);
            u32 p1 = (u32)f2bf(v.z) | ((u32)f2bf(v.w) << 16);
            *(u32*)&tile[r * 520 + cb + i * 4] = p0;
            *(u32*)&tile[r * 520 + cb + i * 4 + 2] = p1;
        }
    }
    __syncthreads();

    f32x4 acc2[2][4];
#pragma unroll
    for (int fr = 0; fr < 2; ++fr)
#pragma unroll
        for (int fc = 0; fc < 4; ++fc) acc2[fr][fc] = (f32x4){0.f, 0.f, 0.f, 0.f};
    for (int ks = 0; ks < 8; ++ks) {
        bf16x8 a0 = *(const bf16x8*)&tile[(ln) * 520 + ks * 32 + lg * 8];
        bf16x8 a1 = *(const bf16x8*)&tile[(16 + ln) * 520 + ks * 32 + lg * 8];
#pragma unroll
        for (int fc = 0; fc < 4; ++fc) {
            bf16x8 bb = *(const bf16x8*)&wmp[((size_t)(ks * 16 + w * 4 + fc) * 64 + l) * 8];
            acc2[0][fc] = __builtin_amdgcn_mfma_f32_16x16x32_bf16(a0, bb, acc2[0][fc], 0, 0, 0);
            acc2[1][fc] = __builtin_amdgcn_mfma_f32_16x16x32_bf16(a1, bb, acc2[1][fc], 0, 0, 0);
        }
    }
    // LN1 stats (row sums over 256 cols; 4 waves x 64 cols each)
#pragma unroll
    for (int fr = 0; fr < 2; ++fr)
#pragma unroll
        for (int reg = 0; reg < 4; ++reg) {
            float s = 0.f, qsum = 0.f;
#pragma unroll
            for (int fc = 0; fc < 4; ++fc) {
                float v = acc2[fr][fc][reg];
                s += v; qsum += v * v;
            }
#pragma unroll
            for (int off = 1; off < 16; off <<= 1) {
                s += __shfl_xor(s, off);
                qsum += __shfl_xor(qsum, off);
            }
            if (ln == 0) {
                int r = fr * 16 + lg * 4 + reg;
                redS[r * 4 + w] = s;
                redQ[r * 4 + w] = qsum;
            }
        }
    __syncthreads();
#pragma unroll
    for (int fc = 0; fc < 4; ++fc) {
        int c = w * 64 + fc * 16 + ln;
        float gg = g1[c], bb = b1[c];
#pragma unroll
        for (int fr = 0; fr < 2; ++fr)
#pragma unroll
            for (int reg = 0; reg < 4; ++reg) {
                int r = fr * 16 + lg * 4 + reg;
                float s = redS[r * 4] + redS[r * 4 + 1] + redS[r * 4 + 2] + redS[r * 4 + 3];
                float qs = redQ[r * 4] + redQ[r * 4 + 1] + redQ[r * 4 + 2] + redQ[r * 4 + 3];
                float mean = s * (1.f / 256.f);
                float rstd = rsqrtf(qs * (1.f / 256.f) - mean * mean + 1e-5f);
                msgm[((size_t)(base + r)) * 256 + c] =
                    (acc2[fr][fc][reg] - mean) * rstd * gg + bb;
            }
    }
}

// ===========================================================================
// FF via MFMA (validated R4).
// ===========================================================================
__global__ __launch_bounds__(256) void ff_mfma_kernel(
    const float* __restrict__ x, const float* __restrict__ msgm,
    const u16* __restrict__ w1p, const u16* __restrict__ w2p,
    const float* __restrict__ g2, const float* __restrict__ b2,
    float* __restrict__ out)
{
    __shared__ u16 tile[32 * 520];
    __shared__ float redS[32 * 4];
    __shared__ float redQ[32 * 4];
    float* tf = (float*)tile;
    const int t = threadIdx.x;
    const int base = blockIdx.x * 32;       // 256 blocks
    const int b = base >> 10, l0 = base & 1023;
    const int w = t >> 6, l = t & 63, ln = l & 15, lg = l >> 4;

    {
        int rr = t & 31, cg = t >> 5;
        for (int cci = 0; cci < 32; ++cci) {
            int c = cci * 8 + cg;
            float v = x[((size_t)b * 256 + c) * 1024 + l0 + rr];
            tile[rr * 520 + c] = f2bf(v);
        }
        int r = t >> 3, cb = (t & 7) * 32;
#pragma unroll
        for (int i = 0; i < 8; ++i) {
            float4 v = *(const float4*)&msgm[((size_t)(base + r)) * 256 + cb + i * 4];
            u32 p0 = (u32)f2bf(v.x) | ((u32)f2bf(v.y) << 16);
            u32 p1 = (u32)f2bf(v.z) | ((u32)f2bf(v.w) << 16);
            *(u32*)&tile[r * 520 + 256 + cb + i * 4] = p0;
            *(u32*)&tile[r * 520 + 256 + cb + i * 4 + 2] = p1;
        }
    }
    __syncthreads();

    f32x4 acc[2][8];
#pragma unroll
    for (int fr = 0; fr < 2; ++fr)
#pragma unroll
        for (int fc = 0; fc < 8; ++fc) acc[fr][fc] = (f32x4){0.f, 0.f, 0.f, 0.f};
    for (int ks = 0; ks < 16; ++ks) {
        bf16x8 a0 = *(const bf16x8*)&tile[(ln) * 520 + ks * 32 + lg * 8];
        bf16x8 a1 = *(const bf16x8*)&tile[(16 + ln) * 520 + ks * 32 + lg * 8];
#pragma unroll
        for (int fc = 0; fc < 8; ++fc) {
            bf16x8 bb = *(const bf16x8*)&w1p[((size_t)(ks * 32 + w * 8 + fc) * 64 + l) * 8];
            acc[0][fc] = __builtin_amdgcn_mfma_f32_16x16x32_bf16(a0, bb, acc[0][fc], 0, 0, 0);
            acc[1][fc] = __builtin_amdgcn_mfma_f32_16x16x32_bf16(a1, bb, acc[1][fc], 0, 0, 0);
        }
    }
    __syncthreads();
#pragma unroll
    for (int fr = 0; fr < 2; ++fr)
#pragma unroll
        for (int fc = 0; fc < 8; ++fc)
#pragma unroll
            for (int reg = 0; reg < 4; ++reg) {
                int r = fr * 16 + lg * 4 + reg;
                int c = w * 128 + fc * 16 + ln;
                tile[r * 520 + c] = f2bf(fmaxf(acc[fr][fc][reg], 0.f));
            }
    __syncthreads();

    f32x4 acc2[2][4];
#pragma unroll
    for (int fr = 0; fr < 2; ++fr)
#pragma unroll
        for (int fc = 0; fc < 4; ++fc) acc2[fr][fc] = (f32x4){0.f, 0.f, 0.f, 0.f};
    for (int ks = 0; ks < 16; ++ks) {
        bf16x8 a0 = *(const bf16x8*)&tile[(ln) * 520 + ks * 32 + lg * 8];
        bf16x8 a1 = *(const bf16x8*)&tile[(16 + ln) * 520 + ks * 32 + lg * 8];
#pragma unroll
        for (int fc = 0; fc < 4; ++fc) {
            bf16x8 bb = *(const bf16x8*)&w2p[((size_t)(ks * 16 + w * 4 + fc) * 64 + l) * 8];
            acc2[0][fc] = __builtin_amdgcn_mfma_f32_16x16x32_bf16(a0, bb, acc2[0][fc], 0, 0, 0);
            acc2[1][fc] = __builtin_amdgcn_mfma_f32_16x16x32_bf16(a1, bb, acc2[1][fc], 0, 0, 0);
        }
    }
#pragma unroll
    for (int fr = 0; fr < 2; ++fr)
#pragma unroll
        for (int reg = 0; reg < 4; ++reg) {
            float s = 0.f, qsum = 0.f;
#pragma unroll
            for (int fc = 0; fc < 4; ++fc) {
                float v = acc2[fr][fc][reg];
                s += v; qsum += v * v;
            }
#pragma unroll
            for (int off = 1; off < 16; off <<= 1) {
                s += __shfl_xor(s, off);
                qsum += __shfl_xor(qsum, off);
            }
            if (ln == 0) {
                int r = fr * 16 + lg * 4 + reg;
                redS[r * 4 + w] = s;
                redQ[r * 4 + w] = qsum;
            }
        }
    __syncthreads();
    float mean[2][4], rstd[2][4];
#pragma unroll
    for (int fr = 0; fr < 2; ++fr)
#pragma unroll
        for (int reg = 0; reg < 4; ++reg) {
            int r = fr * 16 + lg * 4 + reg;
            float s = redS[r * 4] + redS[r * 4 + 1] + redS[r * 4 + 2] + redS[r * 4 + 3];
            float qs = redQ[r * 4] + redQ[r * 4 + 1] + redQ[r * 4 + 2] + redQ[r * 4 + 3];
            float m = s * (1.f / 256.f);
            mean[fr][reg] = m;
            rstd[fr][reg] = rsqrtf(qs * (1.f / 256.f) - m * m + 1e-5f);
        }
#pragma unroll
    for (int fc = 0; fc < 4; ++fc) {
        int c = w * 64 + fc * 16 + ln;
        float gg = g2[c], bb = b2[c];
#pragma unroll
        for (int fr = 0; fr < 2; ++fr)
#pragma unroll
            for (int reg = 0; reg < 4; ++reg) {
                int r = fr * 16 + lg * 4 + reg;
                tf[r * 260 + c] = (acc2[fr][fc][reg] - mean[fr][reg]) * rstd[fr][reg] * gg + bb;
            }
    }
    __syncthreads();
    {
        const float* xp = x + ((size_t)b * 256 + t) * 1024 + l0;
        float* op = out + ((size_t)b * 256 + t) * 1024 + l0;
#pragma unroll
        for (int i = 0; i < 8; ++i) {
            float4 xv = *(const float4*)(xp + i * 4);
            float4 o;
            o.x = xv.x + tf[(i * 4 + 0) * 260 + t];
            o.y = xv.y + tf[(i * 4 + 1) * 260 + t];
            o.z = xv.z + tf[(i * 4 + 2) * 260 + t];
            o.w = xv.w + tf[(i * 4 + 3) * 260 + t];
            *(float4*)(op + i * 4) = o;
        }
    }
}

// ---------------------------------------------------------------------------
extern "C" void kernel_launch(void* const* d_in, const int* in_sizes, int n_in,
                              void* d_out, int out_size, void* d_ws, size_t ws_size,
                              hipStream_t stream)
{
    const float* x    = (const float*)d_in[0];
    const float* src  = (const float*)d_in[1];
    const float* Wq   = (const float*)d_in[2];
    const float* Wk1  = (const float*)d_in[3];
    const float* Wk3  = (const float*)d_in[4];
    const float* Wk5  = (const float*)d_in[5];
    const float* Wk7  = (const float*)d_in[6];
    const float* Wv1  = (const float*)d_in[7];
    const float* Wv3  = (const float*)d_in[8];
    const float* Wv5  = (const float*)d_in[9];
    const float* Wv7  = (const float*)d_in[10];
    const float* Wm   = (const float*)d_in[11];
    const float* g1   = (const float*)d_in[12];
    const float* b1   = (const float*)d_in[13];
    const float* g2   = (const float*)d_in[14];
    const float* b2   = (const float*)d_in[15];
    const float* W1   = (const float*)d_in[16];
    const float* W2   = (const float*)d_in[17];

    float* out = (float*)d_out;
    float* vis = out + 2097152;          // [b,h,l,s]

    // Conv partials in vis region (dead until qk_sm overwrites all of it).
    float* p5 = vis;                     // [2][4][8][64][1024]
    float* p7 = vis + 4194304;           // [2][8][8][64][1024]

    // ws extent+lifetime map (float offsets; re-audited R11):
    //  qb    [0,        2097152)  conv..msg_kernel
    //  kb    [2097152,  4194304)  conv..kv/cast_qk
    //  vb    [4194304,  6291456)  conv..kv
    //  wpack [6291456,  7962624)  repack..conv
    //    then w1p [6291456, 6422528) repack_ff..ff
    //         w2p [6422528, 6488064) repack_ff..ff
    //         wmp [6488064, 6520832) repack_ff..merge
    //         qbt [6520832, 7569408) cast_qk..qk_sm
    //         kbt [7569408, 8617984) cast_qk..qk_sm (overlaps dead xbh only)
    //  xbh   [7962624,  9011200)  cast_src..conv
    //  sbh   [9011200, 10059776)  cast_src..conv
    //    then msg [7962624, 10059776) msg_kernel..merge (after qk_sm: kbt dead)
    //  msgm  [10059776, 12156928)  merge..ff
    //  KVp   [12156928, 12681216), Ksump [12681216, 12689408)
    float* ws    = (float*)d_ws;
    float* qb    = ws;
    float* kb    = ws + 2097152;
    float* vb    = ws + 4194304;
    u16*   wpack = (u16*)(ws + 6291456);
    u16*   w1p   = (u16*)(ws + 6291456);
    u16*   w2p   = (u16*)(ws + 6422528);
    u16*   wmp   = (u16*)(ws + 6488064);
    u16*   qbt   = (u16*)(ws + 6520832);
    u16*   kbt   = (u16*)(ws + 7569408);
    u16*   xbh   = (u16*)(ws + 7962624);
    u16*   sbh   = (u16*)(ws + 9011200);
    float* msg   = ws + 7962624;
    float* msgm  = ws + 10059776;
    float* KVp   = ws + 12156928;
    float* Ksump = ws + 12681216;

    repack_kernel   <<<1632, 256, 0, stream>>>(Wq, Wk1, Wk3, Wk5, Wk7,
                                               Wv1, Wv3, Wv5, Wv7, wpack);
    cast_src_kernel <<<1024, 256, 0, stream>>>(x, src, xbh, sbh);
    conv_mfma_kernel<<<512,  512, 0, stream>>>(xbh, sbh, wpack, qb, kb, vb, p5, p7);
    reduce_kernel   <<<2048, 256, 0, stream>>>(p5, p7, kb, vb);
    repack_ff_kernel<<<224,  256, 0, stream>>>(W1, W2, Wm, w1p, w2p, wmp);
    cast_qk_kernel  <<<1024, 256, 0, stream>>>(qb, kb, qbt, kbt);
    qk_sm_kernel    <<<1024, 512, 0, stream>>>(qbt, kbt, vis);
    kv_kernel       <<<128,  256, 0, stream>>>(kb, vb, KVp, Ksump);
    msg_kernel      <<<128,  256, 0, stream>>>(qb, KVp, Ksump, msg);
    merge_mfma_kernel<<<256, 256, 0, stream>>>(msg, wmp, g1, b1, msgm);
    ff_mfma_kernel  <<<256,  256, 0, stream>>>(x, msgm, w1p, w2p, g2, b2, out);
}

// Round 12
// 274.114 us; speedup vs baseline: 1.1900x; 1.0641x over previous
//
#include <hip/hip_runtime.h>

#define DEV __device__ __forceinline__

typedef unsigned short u16;
typedef unsigned int u32;
typedef __bf16 bf16x8 __attribute__((ext_vector_type(8)));
typedef float f32x4 __attribute__((ext_vector_type(4)));

DEV float elu1(float x) { return x > 0.f ? x + 1.f : __expf(x); }

DEV u16 f2bf(float f) {
    union { float f; unsigned u; } v; v.f = f;
    unsigned r = v.u + 0x7fffu + ((v.u >> 16) & 1u);
    return (u16)(r >> 16);
}

// ===========================================================================
// Conv weight repack (validated R2).
// ===========================================================================
__global__ __launch_bounds__(256) void repack_kernel(
    const float* __restrict__ Wq,
    const float* __restrict__ Wk1, const float* __restrict__ Wk3,
    const float* __restrict__ Wk5, const float* __restrict__ Wk7,
    const float* __restrict__ Wv1, const float* __restrict__ Wv3,
    const float* __restrict__ Wv5, const float* __restrict__ Wv7,
    u16* __restrict__ wpack)
{
    int gid = blockIdx.x * 256 + threadIdx.x;
    int frag = gid >> 6, l = gid & 63;
    const float* W; int K, ocbase = 0, rel;
    if (frag < 1152) {
        W = Wq; K = 3; int slot = frag / 288; rel = frag % 288; ocbase = slot * 64;
    } else {
        int f = frag - 1152; int side = f / 2688; f %= 2688;
        if (f < 32)        { W = side ? Wv1 : Wk1; K = 1; rel = f; }
        else if (f < 320)  { W = side ? Wv3 : Wk3; K = 3; rel = f - 32; }
        else if (f < 1120) { W = side ? Wv5 : Wk5; K = 5; rel = f - 320; }
        else               { W = side ? Wv7 : Wk7; K = 7; rel = f - 1120; }
    }
    int og = rel & 3, cc = (rel >> 2) & 7, tap = rel >> 5;
    int dy = tap / K, dx = tap % K;
    int oc = ocbase + og * 16 + (l & 15);
    int c0 = cc * 32 + (l >> 4) * 8;
    u16 pk[8];
#pragma unroll
    for (int j = 0; j < 8; ++j)
        pk[j] = f2bf(W[((size_t)(oc * 256 + c0 + j) * K + dy) * K + dx]);
    *(int4*)&wpack[(size_t)frag * 512 + l * 8] = *(const int4*)pk;
}

// ===========================================================================
// cast_src: fp32 NCHW -> bf16 blocked [b][cc8][pix1024][c32].
// ===========================================================================
__global__ __launch_bounds__(256) void cast_src_kernel(
    const float* __restrict__ x, const float* __restrict__ src,
    u16* __restrict__ xbh, u16* __restrict__ sbh)
{
    __shared__ float lds[32 * 129];
    const int i = blockIdx.x, t = threadIdx.x;   // 1024 blocks
    const int inp = i >> 9, rem = i & 511;
    const int b = rem >> 6, cc = (rem >> 3) & 7, pxb = rem & 7;
    const float* in = (inp ? src : x) + ((size_t)b * 256 + cc * 32) * 1024 + pxb * 128;
    u16* outp = (inp ? sbh : xbh) + (size_t)b * 262144 + (size_t)cc * 32768 + pxb * 128 * 32;
#pragma unroll
    for (int u = 0; u < 4; ++u) {
        int unit = t + u * 256;
        int r = unit >> 5, px4 = unit & 31;
        float4 v = *(const float4*)(in + (size_t)r * 1024 + px4 * 4);
        lds[r * 129 + px4 * 4 + 0] = v.x;
        lds[r * 129 + px4 * 4 + 1] = v.y;
        lds[r * 129 + px4 * 4 + 2] = v.z;
        lds[r * 129 + px4 * 4 + 3] = v.w;
    }
    __syncthreads();
#pragma unroll
    for (int u = 0; u < 2; ++u) {
        int unit = t + u * 256;
        int px = unit >> 2, cg = unit & 3;
        u16 pk[8];
#pragma unroll
        for (int j = 0; j < 8; ++j) pk[j] = f2bf(lds[(cg * 8 + j) * 129 + px]);
        *(int4*)&outp[px * 32 + cg * 8] = *(const int4*)pk;
    }
}

// ===========================================================================
// cast_qk: qb/kb fp32 [b][c][l] -> bf16 [b*4+h][l][64].
// ===========================================================================
__global__ __launch_bounds__(256) void cast_qk_kernel(
    const float* __restrict__ qb, const float* __restrict__ kb,
    u16* __restrict__ qbt, u16* __restrict__ kbt)
{
    __shared__ float lds[64 * 65];
    const int i = blockIdx.x, t = threadIdx.x;   // 1024 blocks
    const int inp = i >> 9, rem = i & 511;
    const int b = rem >> 6, h = (rem >> 4) & 3, pxb = rem & 15;
    const float* in = (inp ? kb : qb) + ((size_t)b * 256 + h * 64) * 1024 + pxb * 64;
    u16* outp = (inp ? kbt : qbt) + (((size_t)(b * 4 + h)) * 1024 + pxb * 64) * 64;
#pragma unroll
    for (int u = 0; u < 4; ++u) {
        int unit = t + u * 256;
        int r = unit >> 4, px4 = unit & 15;
        float4 v = *(const float4*)(in + (size_t)r * 1024 + px4 * 4);
        lds[r * 65 + px4 * 4 + 0] = v.x;
        lds[r * 65 + px4 * 4 + 1] = v.y;
        lds[r * 65 + px4 * 4 + 2] = v.z;
        lds[r * 65 + px4 * 4 + 3] = v.w;
    }
    __syncthreads();
#pragma unroll
    for (int u = 0; u < 2; ++u) {
        int unit = t + u * 256;
        int px = unit >> 3, cg = unit & 7;
        u16 pk[8];
#pragma unroll
        for (int j = 0; j < 8; ++j) pk[j] = f2bf(lds[(cg * 8 + j) * 65 + px]);
        *(int4*)&outp[px * 64 + cg * 8] = *(const int4*)pk;
    }
}

// ===========================================================================
// FF/Wm repack: W1 (512 frags), W2 (256 frags), Wm (128 frags).
// ===========================================================================
__global__ __launch_bounds__(256) void repack_ff_kernel(
    const float* __restrict__ W1, const float* __restrict__ W2,
    const float* __restrict__ Wm,
    u16* __restrict__ w1p, u16* __restrict__ w2p, u16* __restrict__ wmp)
{
    int gid = blockIdx.x * 256 + threadIdx.x;   // 224*256 (896 frags)
    int f = gid >> 6, l = gid & 63;
    if (f >= 896) return;
    u16 pk[8];
    if (f < 512) {
        int ks = f >> 5, nf = f & 31;
#pragma unroll
        for (int j = 0; j < 8; ++j)
            pk[j] = f2bf(W1[(size_t)(ks * 32 + (l >> 4) * 8 + j) * 512 + nf * 16 + (l & 15)]);
        *(int4*)&w1p[(size_t)f * 512 + l * 8] = *(const int4*)pk;
    } else if (f < 768) {
        int f2 = f - 512;
        int ks = f2 >> 4, nf = f2 & 15;
#pragma unroll
        for (int j = 0; j < 8; ++j)
            pk[j] = f2bf(W2[(size_t)(ks * 32 + (l >> 4) * 8 + j) * 256 + nf * 16 + (l & 15)]);
        *(int4*)&w2p[(size_t)f2 * 512 + l * 8] = *(const int4*)pk;
    } else {
        int f3 = f - 768;
        int ks = f3 >> 4, nf = f3 & 15;
#pragma unroll
        for (int j = 0; j < 8; ++j)
            pk[j] = f2bf(Wm[(size_t)(ks * 32 + (l >> 4) * 8 + j) * 256 + nf * 16 + (l & 15)]);
        *(int4*)&wmp[(size_t)f3 * 512 + l * 8] = *(const int4*)pk;
    }
}

// ===========================================================================
// MFMA implicit-GEMM conv (exact R9 body: validated 88.7us, VGPR 108).
// ===========================================================================
template<int K>
DEV void conv_mfma_body(const u16* __restrict__ srcb,
                        const u16* __restrict__ wsec,
                        float* __restrict__ dst,
                        u16* Bt, int y0, int cch0, int ncc, int t)
{
    constexpr int P = K / 2;
    const int w = t >> 6, l = t & 63;
    const int chi = l >> 4, ln = l & 15;
    const int rowbase = chi * 22 + w * 2 + 3 - P;
    const int colbase = ln + 3 - P;
    f32x4 acc[4][4];
#pragma unroll
    for (int m = 0; m < 4; ++m)
#pragma unroll
        for (int n = 0; n < 4; ++n) acc[m][n] = (f32x4){0.f, 0.f, 0.f, 0.f};

    for (int cc = 0; cc < ncc; ++cc) {
        const int ccg = cch0 + cc;
        __syncthreads();
#pragma unroll
        for (int u = 0; u < 7; ++u) {
            int unit = t + (u << 9);
            if (unit < 2816) {
                int xv = unit & 31, r = unit >> 5;
                int yy = r % 22, ch = r / 22;
                int ygl = y0 - 3 + yy;
                int4 pk;
                if ((unsigned)ygl < 32u)
                    pk = *(const int4*)&srcb[(size_t)ccg * 32768 + (ygl * 32 + xv) * 32 + ch * 8];
                else
                    pk = (int4){0, 0, 0, 0};
                *(int4*)&Bt[((ch * 22 + yy) * 40 + xv + 3) * 8] = pk;
            } else if (unit < 3520) {
                int hu = unit - 2816;
                int hx = hu & 7; int xi = hx < 3 ? hx : hx + 32;
                int r = hu >> 3; int yy = r % 22, ch = r / 22;
                int4 z = {0, 0, 0, 0};
                *(int4*)&Bt[((ch * 22 + yy) * 40 + xi) * 8] = z;
            }
        }
        __syncthreads();
#pragma unroll
        for (int dy = 0; dy < K; ++dy) {
#pragma unroll
            for (int dx = 0; dx < K; ++dx) {
                const int tap = dy * K + dx;
                const u16* wp = wsec + ((size_t)(tap * 8 + ccg) * 4) * 512 + l * 8;
                bf16x8 a0 = *(const bf16x8*)(wp);
                bf16x8 a1 = *(const bf16x8*)(wp + 512);
                bf16x8 a2 = *(const bf16x8*)(wp + 1024);
                bf16x8 a3 = *(const bf16x8*)(wp + 1536);
                bf16x8 bf[4];
#pragma unroll
                for (int n = 0; n < 4; ++n) {
                    int row = rowbase + dy + (n >> 1);
                    int col = colbase + dx + (n & 1) * 16;
                    bf[n] = *(const bf16x8*)&Bt[(row * 40 + col) * 8];
                }
#pragma unroll
                for (int n = 0; n < 4; ++n) {
                    acc[0][n] = __builtin_amdgcn_mfma_f32_16x16x32_bf16(a0, bf[n], acc[0][n], 0, 0, 0);
                    acc[1][n] = __builtin_amdgcn_mfma_f32_16x16x32_bf16(a1, bf[n], acc[1][n], 0, 0, 0);
                    acc[2][n] = __builtin_amdgcn_mfma_f32_16x16x32_bf16(a2, bf[n], acc[2][n], 0, 0, 0);
                    acc[3][n] = __builtin_amdgcn_mfma_f32_16x16x32_bf16(a3, bf[n], acc[3][n], 0, 0, 0);
                }
            }
        }
    }
#pragma unroll
    for (int m = 0; m < 4; ++m)
#pragma unroll
        for (int n = 0; n < 4; ++n) {
            int y = y0 + w * 2 + (n >> 1);
            int px = y * 32 + (n & 1) * 16 + ln;
            int ocb = m * 16 + chi * 4;
#pragma unroll
            for (int r = 0; r < 4; ++r)
                dst[(size_t)(ocb + r) * 1024 + px] = acc[m][n][r];
        }
}

__global__ __launch_bounds__(512) void conv_mfma_kernel(
    const u16* __restrict__ xbh, const u16* __restrict__ sbh,
    const u16* __restrict__ wpack,
    float* __restrict__ qb, float* __restrict__ kb, float* __restrict__ vb,
    float* __restrict__ p5, float* __restrict__ p7)
{
    __shared__ u16 Bt[4 * 22 * 40 * 8];
    const int bx = blockIdx.x, t = threadIdx.x;
    const int g = bx & 31, b = (bx >> 5) & 7, m = bx >> 8;
    if (g < 4) {
        conv_mfma_body<3>(xbh + (size_t)b * 262144,
                          wpack + (size_t)(g * 288) * 512,
                          qb + ((size_t)b * 256 + g * 64) * 1024,
                          Bt, m * 16, 0, 8, t);
        return;
    }
    const int gs = g - 4;
    const int side = gs / 14, gg = gs % 14;
    const u16* sp = sbh + (size_t)b * 262144;
    float* fin = side ? vb : kb;
    const size_t wkb = 1152 + (size_t)side * 2688;
    if (gg == 0) {
        conv_mfma_body<1>(sp, wpack + (wkb + 0) * 512,
                          fin + ((size_t)b * 256) * 1024, Bt, m * 16, 0, 8, t);
    } else if (gg == 1) {
        conv_mfma_body<3>(sp, wpack + (wkb + 32) * 512,
                          fin + ((size_t)b * 256 + 64) * 1024, Bt, m * 16, 0, 8, t);
    } else if (gg < 6) {
        int cpart = gg - 2;
        conv_mfma_body<5>(sp, wpack + (wkb + 320) * 512,
                          p5 + (((size_t)side * 4 + cpart) * 8 + b) * 65536,
                          Bt, m * 16, cpart * 2, 2, t);
    } else {
        int cpart = gg - 6;
        conv_mfma_body<7>(sp, wpack + (wkb + 1120) * 512,
                          p7 + (((size_t)side * 8 + cpart) * 8 + b) * 65536,
                          Bt, m * 16, cpart, 1, t);
    }
}

__global__ __launch_bounds__(256) void reduce_kernel(
    const float* __restrict__ p5, const float* __restrict__ p7,
    float* __restrict__ kb, float* __restrict__ vb)
{
    int gid = blockIdx.x * 256 + threadIdx.x;
    int px4 = gid & 255;
    int rr = gid >> 8;
    int oc = rr & 63, b = (rr >> 6) & 7, head = (rr >> 9) & 1, side = rr >> 10;
    float* outb = side ? vb : kb;
    float4 s = make_float4(0.f, 0.f, 0.f, 0.f);
    if (head == 0) {
#pragma unroll
        for (int p = 0; p < 4; ++p) {
            float4 u = *((const float4*)(p5 + (((size_t)side * 4 + p) * 8 + b) * 65536 + (size_t)oc * 1024) + px4);
            s.x += u.x; s.y += u.y; s.z += u.z; s.w += u.w;
        }
        *((float4*)(outb + ((size_t)b * 256 + 128 + oc) * 1024) + px4) = s;
    } else {
#pragma unroll
        for (int p = 0; p < 8; ++p) {
            float4 u = *((const float4*)(p7 + (((size_t)side * 8 + p) * 8 + b) * 65536 + (size_t)oc * 1024) + px4);
            s.x += u.x; s.y += u.y; s.z += u.z; s.w += u.w;
        }
        *((float4*)(outb + ((size_t)b * 256 + 192 + oc) * 1024) + px4) = s;
    }
}

// ===========================================================================
// Fused QK^T + softmax -> vis. R12: vectorized float4 epilogue via LDS
// transpose (aliases the dead kf/qf staging buffers).
// ===========================================================================
__global__ __launch_bounds__(512) void qk_sm_kernel(const u16* __restrict__ qbt,
                                                    const u16* __restrict__ kbt,
                                                    float* __restrict__ vis)
{
    __shared__ u16 shbuf[36 * 512];     // kf (32KB) + qf (4KB); reused as outT
    __shared__ float redM[32 * 8];
    __shared__ float redS[32 * 8];
    u16* kf = shbuf;
    u16* qf = shbuf + 32 * 512;
    const int t = threadIdx.x;
    const int bx = blockIdx.x;          // 8b*4h*32lt = 1024
    const int b = bx >> 7, h = (bx >> 5) & 3, l0 = (bx & 31) * 32;
    const u16* qtp = qbt + ((size_t)(b * 4 + h)) * 1024 * 64;
    const u16* ktp = kbt + ((size_t)(b * 4 + h)) * 1024 * 64;

    if (t < 256) {
        int r = t & 31, dblk = t >> 5;
        int4 pk = *(const int4*)&qtp[(size_t)(l0 + r) * 64 + dblk * 8];
        *(int4*)&qf[(((r >> 4) * 2 + (dblk >> 2)) * 64 + (dblk & 3) * 16 + (r & 15)) * 8] = pk;
    }
    __syncthreads();

    const int w = t >> 6, l = t & 63, ln = l & 15, lg = l >> 4;
    bf16x8 a[2][2];
#pragma unroll
    for (int fr = 0; fr < 2; ++fr)
#pragma unroll
        for (int ks = 0; ks < 2; ++ks)
            a[fr][ks] = *(const bf16x8*)&qf[((fr * 2 + ks) * 64 + l) * 8];

    f32x4 acc[2][4][2];
#pragma unroll
    for (int fr = 0; fr < 2; ++fr)
#pragma unroll
        for (int cc = 0; cc < 4; ++cc)
#pragma unroll
            for (int f = 0; f < 2; ++f) acc[fr][cc][f] = (f32x4){0.f, 0.f, 0.f, 0.f};

#pragma unroll
    for (int cc = 0; cc < 4; ++cc) {
        __syncthreads();
#pragma unroll
        for (int it = 0; it < 4; ++it) {
            int unit = it * 512 + t;
            int sl = unit & 255, dblk = unit >> 8;
            int4 pk = *(const int4*)&ktp[(size_t)(cc * 256 + sl) * 64 + dblk * 8];
            *(int4*)&kf[(((sl >> 4) * 2 + (dblk >> 2)) * 64 + (dblk & 3) * 16 + (sl & 15)) * 8] = pk;
        }
        __syncthreads();
#pragma unroll
        for (int f = 0; f < 2; ++f) {
            int fg = (w * 2 + f) * 2;
            bf16x8 b0 = *(const bf16x8*)&kf[((fg + 0) * 64 + l) * 8];
            bf16x8 b1 = *(const bf16x8*)&kf[((fg + 1) * 64 + l) * 8];
#pragma unroll
            for (int fr = 0; fr < 2; ++fr) {
                acc[fr][cc][f] = __builtin_amdgcn_mfma_f32_16x16x32_bf16(a[fr][0], b0, acc[fr][cc][f], 0, 0, 0);
                acc[fr][cc][f] = __builtin_amdgcn_mfma_f32_16x16x32_bf16(a[fr][1], b1, acc[fr][cc][f], 0, 0, 0);
            }
        }
    }

#pragma unroll
    for (int fr = 0; fr < 2; ++fr)
#pragma unroll
        for (int cc = 0; cc < 4; ++cc)
#pragma unroll
            for (int f = 0; f < 2; ++f)
#pragma unroll
                for (int e = 0; e < 4; ++e) acc[fr][cc][f][e] *= 0.125f;

    float rmax[2][4];
#pragma unroll
    for (int fr = 0; fr < 2; ++fr)
#pragma unroll
        for (int reg = 0; reg < 4; ++reg) {
            float m = -1e30f;
#pragma unroll
            for (int cc = 0; cc < 4; ++cc)
#pragma unroll
                for (int f = 0; f < 2; ++f) m = fmaxf(m, acc[fr][cc][f][reg]);
#pragma unroll
            for (int off = 1; off < 16; off <<= 1) m = fmaxf(m, __shfl_xor(m, off));
            if (ln == 0) redM[(fr * 16 + lg * 4 + reg) * 8 + w] = m;
            rmax[fr][reg] = m;
        }
    __syncthreads();
#pragma unroll
    for (int fr = 0; fr < 2; ++fr)
#pragma unroll
        for (int reg = 0; reg < 4; ++reg) {
            int r = fr * 16 + lg * 4 + reg;
            float m = redM[r * 8];
#pragma unroll
            for (int ww = 1; ww < 8; ++ww) m = fmaxf(m, redM[r * 8 + ww]);
            rmax[fr][reg] = m;
        }
#pragma unroll
    for (int fr = 0; fr < 2; ++fr)
#pragma unroll
        for (int reg = 0; reg < 4; ++reg) {
            float s = 0.f;
            float m = rmax[fr][reg];
#pragma unroll
            for (int cc = 0; cc < 4; ++cc)
#pragma unroll
                for (int f = 0; f < 2; ++f) {
                    float e = __expf(acc[fr][cc][f][reg] - m);
                    acc[fr][cc][f][reg] = e;
                    s += e;
                }
#pragma unroll
            for (int off = 1; off < 16; off <<= 1) s += __shfl_xor(s, off);
            if (ln == 0) redS[(fr * 16 + lg * 4 + reg) * 8 + w] = s;
        }
    __syncthreads();
    float invv[2][4];
#pragma unroll
    for (int fr = 0; fr < 2; ++fr)
#pragma unroll
        for (int reg = 0; reg < 4; ++reg) {
            int r = fr * 16 + lg * 4 + reg;
            float s = redS[r * 8] + redS[r * 8 + 1] + redS[r * 8 + 2] + redS[r * 8 + 3]
                    + redS[r * 8 + 4] + redS[r * 8 + 5] + redS[r * 8 + 6] + redS[r * 8 + 7];
            invv[fr][reg] = 1.f / s;
        }
    // vectorized epilogue: per 256-col chunk, LDS transpose then float4 store
    float* outT = (float*)shbuf;        // [32][260] f32 = 33.3 KB <= 36 KB
    float* visp = vis + (((size_t)(b * 4 + h)) << 20);
#pragma unroll
    for (int cc = 0; cc < 4; ++cc) {
        __syncthreads();
#pragma unroll
        for (int fr = 0; fr < 2; ++fr)
#pragma unroll
            for (int reg = 0; reg < 4; ++reg) {
                int r = fr * 16 + lg * 4 + reg;
#pragma unroll
                for (int f = 0; f < 2; ++f)
                    outT[r * 260 + w * 32 + f * 16 + ln] = acc[fr][cc][f][reg] * invv[fr][reg];
            }
        __syncthreads();
#pragma unroll
        for (int u = 0; u < 4; ++u) {
            int unit = u * 512 + t;     // 2048 float4 units
            int r = unit >> 6, c4 = unit & 63;
            float4 v = *(const float4*)&outT[r * 260 + c4 * 4];
            *(float4*)&visp[(size_t)(l0 + r) * 1024 + cc * 256 + c4 * 4] = v;
        }
    }
}

// ---------------------------------------------------------------------------
// Linear attention (validated R2).
// ---------------------------------------------------------------------------
__global__ __launch_bounds__(256) void kv_kernel(const float* __restrict__ k,
                                                 const float* __restrict__ v,
                                                 float* __restrict__ KVp,
                                                 float* __restrict__ Ksump)
{
    __shared__ float4 Kt4[64*17];
    __shared__ float4 Vt4[64*16];
    float* Kt = (float*)Kt4;
    float* Vt = (float*)Vt4;
    const int t = threadIdx.x;
    const int bx = blockIdx.x;
    const int b = bx >> 4, h = (bx >> 2) & 3, ch = bx & 3;
    const float* kb = k + ((size_t)b*256 + h*64)*1024 + ch*256;
    const float* vb = v + ((size_t)b*256 + h*64)*1024 + ch*256;
    const int d = t >> 2, v0 = (t & 3) * 16;
    float4 acc[4];
#pragma unroll
    for (int j = 0; j < 4; ++j) acc[j] = make_float4(0.f, 0.f, 0.f, 0.f);
    float ks = 0.f;
    for (int st = 0; st < 4; ++st) {
        __syncthreads();
        {
            int dd = t >> 2, r0 = (t & 3) * 16;
#pragma unroll
            for (int mm = 0; mm < 4; ++mm) {
                float4 kv = *(const float4*)(kb + dd*1024 + st*64 + r0 + mm*4);
                Kt[(r0+mm*4+0)*68 + dd] = elu1(kv.x);
                Kt[(r0+mm*4+1)*68 + dd] = elu1(kv.y);
                Kt[(r0+mm*4+2)*68 + dd] = elu1(kv.z);
                Kt[(r0+mm*4+3)*68 + dd] = elu1(kv.w);
                float4 vv = *(const float4*)(vb + dd*1024 + st*64 + r0 + mm*4);
                Vt[(r0+mm*4+0)*64 + dd] = vv.x;
                Vt[(r0+mm*4+1)*64 + dd] = vv.y;
                Vt[(r0+mm*4+2)*64 + dd] = vv.z;
                Vt[(r0+mm*4+3)*64 + dd] = vv.w;
            }
        }
        __syncthreads();
#pragma unroll 8
        for (int s = 0; s < 64; ++s) {
            float kf = Kt[s*68 + d];
            const float4* vp = (const float4*)(Vt + s*64 + v0);
#pragma unroll
            for (int j = 0; j < 4; ++j) {
                float4 vv = vp[j];
                acc[j].x += kf*vv.x; acc[j].y += kf*vv.y;
                acc[j].z += kf*vv.z; acc[j].w += kf*vv.w;
            }
        }
        if (t < 64) {
#pragma unroll 8
            for (int s = 0; s < 64; ++s) ks += Kt[s*68 + t];
        }
    }
    float* op = KVp + ((size_t)((ch*32 + b*4 + h)*64 + d))*64 + v0;
#pragma unroll
    for (int j = 0; j < 4; ++j) ((float4*)op)[j] = acc[j];
    if (t < 64) Ksump[(size_t)(ch*32 + b*4 + h)*64 + t] = ks;
}

__global__ __launch_bounds__(256) void msg_kernel(const float* __restrict__ q,
                                                  const float* __restrict__ KVp,
                                                  const float* __restrict__ Ksump,
                                                  float* __restrict__ msg)
{
    __shared__ float4 kvl4[4*1028];
    __shared__ float ksl[4*65];
    float* kvl = (float*)kvl4;
    const int t = threadIdx.x;
    const int bx = blockIdx.x;
    const int b = bx >> 4;
    const int l0 = (bx & 15) * 64;
    for (int m = 0; m < 64; ++m) {
        int idx = t + 256*m;
        int hh = idx >> 12, dd = (idx >> 6) & 63, vv = idx & 63;
        float s = 0.f;
#pragma unroll
        for (int ch = 0; ch < 4; ++ch)
            s += KVp[(size_t)((ch*32 + b*4))*4096 + idx];
        kvl[hh*4112 + dd*64 + vv] = s;
    }
    {
        float s = 0.f;
#pragma unroll
        for (int ch = 0; ch < 4; ++ch)
            s += Ksump[(size_t)(ch*32 + b*4)*64 + t];
        ksl[(t >> 6)*65 + (t & 63)] = s;
    }
    __syncthreads();
    const int h = t & 3, l = l0 + (t >> 2);
    const float* qb = q + ((size_t)b*256 + h*64)*1024 + l;
    float qf[64];
#pragma unroll
    for (int dd = 0; dd < 64; ++dd) qf[dd] = elu1(qb[dd*1024]);
    float zd = 1e-6f;
#pragma unroll
    for (int dd = 0; dd < 64; ++dd) zd += qf[dd] * ksl[h*65 + dd];
    const float Z = 1.f / zd;
    float* op = msg + ((size_t)(b*1024 + l))*256 + h*64;
    for (int c0 = 0; c0 < 64; c0 += 16) {
        float4 a[4];
#pragma unroll
        for (int j = 0; j < 4; ++j) a[j] = make_float4(0.f, 0.f, 0.f, 0.f);
#pragma unroll
        for (int dd = 0; dd < 64; ++dd) {
            float qv = qf[dd];
            const float4* kp = (const float4*)(kvl + h*4112 + dd*64 + c0);
#pragma unroll
            for (int j = 0; j < 4; ++j) {
                float4 kk = kp[j];
                a[j].x += qv*kk.x; a[j].y += qv*kk.y;
                a[j].z += qv*kk.z; a[j].w += qv*kk.w;
            }
        }
#pragma unroll
        for (int j = 0; j < 4; ++j) {
            a[j].x *= Z; a[j].y *= Z; a[j].z *= Z; a[j].w *= Z;
            ((float4*)(op + c0))[j] = a[j];
        }
    }
}

// ===========================================================================
// Fused merge(Wm,LN1) + FF(W1,relu,W2,LN2) + residual. 16-row tiles, 512
// blocks (2+/CU). Merge phase = validated merge_mfma math; FF = validated
// ff_mfma math with fr-dimension removed.
// ===========================================================================
__global__ __launch_bounds__(256) void ff_fused_kernel(
    const float* __restrict__ x, const float* __restrict__ msg,
    const u16* __restrict__ wmp,
    const u16* __restrict__ w1p, const u16* __restrict__ w2p,
    const float* __restrict__ g1, const float* __restrict__ b1,
    const float* __restrict__ g2, const float* __restrict__ b2,
    float* __restrict__ out)
{
    __shared__ u16 tile[16 * 520];      // concat [16][520]; reused as f32 [16][260]
    __shared__ u16 mtile[16 * 264];     // msg bf16
    __shared__ float redS[16 * 4];
    __shared__ float redQ[16 * 4];
    float* tf = (float*)tile;
    const int t = threadIdx.x;
    const int base = blockIdx.x * 16;   // 512 blocks
    const int b = base >> 10, l0 = base & 1023;
    const int w = t >> 6, l = t & 63, ln = l & 15, lg = l >> 4;

    // ---- stage x (cols 0..255) and msg bf16 ----
    {
        int rr = t & 15, cg = t >> 4;
        for (int cci = 0; cci < 16; ++cci) {
            int c = cci * 16 + cg;
            tile[rr * 520 + c] = f2bf(x[((size_t)b * 256 + c) * 1024 + l0 + rr]);
        }
        int r = t >> 4, cb = (t & 15) * 16;
#pragma unroll
        for (int i = 0; i < 4; ++i) {
            float4 v = *(const float4*)&msg[((size_t)(base + r)) * 256 + cb + i * 4];
            u32 p0 = (u32)f2bf(v.x) | ((u32)f2bf(v.y) << 16);
            u32 p1 = (u32)f2bf(v.z) | ((u32)f2bf(v.w) << 16);
            *(u32*)&mtile[r * 264 + cb + i * 4] = p0;
            *(u32*)&mtile[r * 264 + cb + i * 4 + 2] = p1;
        }
    }
    __syncthreads();

    // ---- merge GEMM: wave w -> cols w*64..+64 ----
    f32x4 accm[4];
#pragma unroll
    for (int fc = 0; fc < 4; ++fc) accm[fc] = (f32x4){0.f, 0.f, 0.f, 0.f};
    for (int ks = 0; ks < 8; ++ks) {
        bf16x8 a0 = *(const bf16x8*)&mtile[ln * 264 + ks * 32 + lg * 8];
#pragma unroll
        for (int fc = 0; fc < 4; ++fc) {
            bf16x8 bb = *(const bf16x8*)&wmp[((size_t)(ks * 16 + w * 4 + fc) * 64 + l) * 8];
            accm[fc] = __builtin_amdgcn_mfma_f32_16x16x32_bf16(a0, bb, accm[fc], 0, 0, 0);
        }
    }
    // LN1 stats
#pragma unroll
    for (int reg = 0; reg < 4; ++reg) {
        float s = 0.f, qsum = 0.f;
#pragma unroll
        for (int fc = 0; fc < 4; ++fc) {
            float v = accm[fc][reg];
            s += v; qsum += v * v;
        }
#pragma unroll
        for (int off = 1; off < 16; off <<= 1) {
            s += __shfl_xor(s, off);
            qsum += __shfl_xor(qsum, off);
        }
        if (ln == 0) {
            int r = lg * 4 + reg;
            redS[r * 4 + w] = s;
            redQ[r * 4 + w] = qsum;
        }
    }
    __syncthreads();
#pragma unroll
    for (int fc = 0; fc < 4; ++fc) {
        int c = w * 64 + fc * 16 + ln;
        float gg = g1[c], bb = b1[c];
#pragma unroll
        for (int reg = 0; reg < 4; ++reg) {
            int r = lg * 4 + reg;
            float s = redS[r * 4] + redS[r * 4 + 1] + redS[r * 4 + 2] + redS[r * 4 + 3];
            float qs = redQ[r * 4] + redQ[r * 4 + 1] + redQ[r * 4 + 2] + redQ[r * 4 + 3];
            float mean = s * (1.f / 256.f);
            float rstd = rsqrtf(qs * (1.f / 256.f) - mean * mean + 1e-5f);
            tile[r * 520 + 256 + c] = f2bf((accm[fc][reg] - mean) * rstd * gg + bb);
        }
    }
    __syncthreads();

    // ---- GEMM1: hidden[16][512], wave w -> cols w*128..+128 ----
    f32x4 acc1[8];
#pragma unroll
    for (int fc = 0; fc < 8; ++fc) acc1[fc] = (f32x4){0.f, 0.f, 0.f, 0.f};
    for (int ks = 0; ks < 16; ++ks) {
        bf16x8 a0 = *(const bf16x8*)&tile[ln * 520 + ks * 32 + lg * 8];
#pragma unroll
        for (int fc = 0; fc < 8; ++fc) {
            bf16x8 bb = *(const bf16x8*)&w1p[((size_t)(ks * 32 + w * 8 + fc) * 64 + l) * 8];
            acc1[fc] = __builtin_amdgcn_mfma_f32_16x16x32_bf16(a0, bb, acc1[fc], 0, 0, 0);
        }
    }
    __syncthreads();
#pragma unroll
    for (int fc = 0; fc < 8; ++fc)
#pragma unroll
        for (int reg = 0; reg < 4; ++reg) {
            int r = lg * 4 + reg;
            int c = w * 128 + fc * 16 + ln;
            tile[r * 520 + c] = f2bf(fmaxf(acc1[fc][reg], 0.f));
        }
    __syncthreads();

    // ---- GEMM2: out[16][256], wave w -> cols w*64..+64 ----
    f32x4 acc2[4];
#pragma unroll
    for (int fc = 0; fc < 4; ++fc) acc2[fc] = (f32x4){0.f, 0.f, 0.f, 0.f};
    for (int ks = 0; ks < 16; ++ks) {
        bf16x8 a0 = *(const bf16x8*)&tile[ln * 520 + ks * 32 + lg * 8];
#pragma unroll
        for (int fc = 0; fc < 4; ++fc) {
            bf16x8 bb = *(const bf16x8*)&w2p[((size_t)(ks * 16 + w * 4 + fc) * 64 + l) * 8];
            acc2[fc] = __builtin_amdgcn_mfma_f32_16x16x32_bf16(a0, bb, acc2[fc], 0, 0, 0);
        }
    }
    // LN2 stats
#pragma unroll
    for (int reg = 0; reg < 4; ++reg) {
        float s = 0.f, qsum = 0.f;
#pragma unroll
        for (int fc = 0; fc < 4; ++fc) {
            float v = acc2[fc][reg];
            s += v; qsum += v * v;
        }
#pragma unroll
        for (int off = 1; off < 16; off <<= 1) {
            s += __shfl_xor(s, off);
            qsum += __shfl_xor(qsum, off);
        }
        if (ln == 0) {
            int r = lg * 4 + reg;
            redS[r * 4 + w] = s;
            redQ[r * 4 + w] = qsum;
        }
    }
    __syncthreads();
    float mean[4], rstd[4];
#pragma unroll
    for (int reg = 0; reg < 4; ++reg) {
        int r = lg * 4 + reg;
        float s = redS[r * 4] + redS[r * 4 + 1] + redS[r * 4 + 2] + redS[r * 4 + 3];
        float qs = redQ[r * 4] + redQ[r * 4 + 1] + redQ[r * 4 + 2] + redQ[r * 4 + 3];
        float m = s * (1.f / 256.f);
        mean[reg] = m;
        rstd[reg] = rsqrtf(qs * (1.f / 256.f) - m * m + 1e-5f);
    }
    __syncthreads();                    // tile (A source) dead; reuse as tf
#pragma unroll
    for (int fc = 0; fc < 4; ++fc) {
        int c = w * 64 + fc * 16 + ln;
        float gg = g2[c], bb = b2[c];
#pragma unroll
        for (int reg = 0; reg < 4; ++reg) {
            int r = lg * 4 + reg;
            tf[r * 260 + c] = (acc2[fc][reg] - mean[reg]) * rstd[reg] * gg + bb;
        }
    }
    __syncthreads();
    // ---- residual + write: thread t = channel ----
    {
        const float* xp = x + ((size_t)b * 256 + t) * 1024 + l0;
        float* op = out + ((size_t)b * 256 + t) * 1024 + l0;
#pragma unroll
        for (int i = 0; i < 4; ++i) {
            float4 xv = *(const float4*)(xp + i * 4);
            float4 o;
            o.x = xv.x + tf[(i * 4 + 0) * 260 + t];
            o.y = xv.y + tf[(i * 4 + 1) * 260 + t];
            o.z = xv.z + tf[(i * 4 + 2) * 260 + t];
            o.w = xv.w + tf[(i * 4 + 3) * 260 + t];
            *(float4*)(op + i * 4) = o;
        }
    }
}

// ---------------------------------------------------------------------------
extern "C" void kernel_launch(void* const* d_in, const int* in_sizes, int n_in,
                              void* d_out, int out_size, void* d_ws, size_t ws_size,
                              hipStream_t stream)
{
    const float* x    = (const float*)d_in[0];
    const float* src  = (const float*)d_in[1];
    const float* Wq   = (const float*)d_in[2];
    const float* Wk1  = (const float*)d_in[3];
    const float* Wk3  = (const float*)d_in[4];
    const float* Wk5  = (const float*)d_in[5];
    const float* Wk7  = (const float*)d_in[6];
    const float* Wv1  = (const float*)d_in[7];
    const float* Wv3  = (const float*)d_in[8];
    const float* Wv5  = (const float*)d_in[9];
    const float* Wv7  = (const float*)d_in[10];
    const float* Wm   = (const float*)d_in[11];
    const float* g1   = (const float*)d_in[12];
    const float* b1   = (const float*)d_in[13];
    const float* g2   = (const float*)d_in[14];
    const float* b2   = (const float*)d_in[15];
    const float* W1   = (const float*)d_in[16];
    const float* W2   = (const float*)d_in[17];

    float* out = (float*)d_out;
    float* vis = out + 2097152;          // [b,h,l,s]

    // Conv partials in vis region (dead until qk_sm overwrites all of it).
    float* p5 = vis;                     // [2][4][8][64][1024]
    float* p7 = vis + 4194304;           // [2][8][8][64][1024]

    // ws extent+lifetime map (float offsets; re-audited R12 — msgm removed):
    //  qb    [0,        2097152)  conv..msg_kernel
    //  kb    [2097152,  4194304)  conv..kv/cast_qk
    //  vb    [4194304,  6291456)  conv..kv
    //  wpack [6291456,  7962624)  repack..conv
    //    then w1p [6291456, 6422528) repack_ff..ff_fused
    //         w2p [6422528, 6488064) repack_ff..ff_fused
    //         wmp [6488064, 6520832) repack_ff..ff_fused
    //         qbt [6520832, 7569408) cast_qk..qk_sm
    //         kbt [7569408, 8617984) cast_qk..qk_sm (overlaps dead xbh only)
    //  xbh   [7962624,  9011200)  cast_src..conv
    //  sbh   [9011200, 10059776)  cast_src..conv
    //    then msg [7962624, 10059776) msg_kernel..ff_fused (after qk_sm)
    //  KVp   [12156928, 12681216), Ksump [12681216, 12689408)
    float* ws    = (float*)d_ws;
    float* qb    = ws;
    float* kb    = ws + 2097152;
    float* vb    = ws + 4194304;
    u16*   wpack = (u16*)(ws + 6291456);
    u16*   w1p   = (u16*)(ws + 6291456);
    u16*   w2p   = (u16*)(ws + 6422528);
    u16*   wmp   = (u16*)(ws + 6488064);
    u16*   qbt   = (u16*)(ws + 6520832);
    u16*   kbt   = (u16*)(ws + 7569408);
    u16*   xbh   = (u16*)(ws + 7962624);
    u16*   sbh   = (u16*)(ws + 9011200);
    float* msg   = ws + 7962624;
    float* KVp   = ws + 12156928;
    float* Ksump = ws + 12681216;

    repack_kernel   <<<1632, 256, 0, stream>>>(Wq, Wk1, Wk3, Wk5, Wk7,
                                               Wv1, Wv3, Wv5, Wv7, wpack);
    cast_src_kernel <<<1024, 256, 0, stream>>>(x, src, xbh, sbh);
    conv_mfma_kernel<<<512,  512, 0, stream>>>(xbh, sbh, wpack, qb, kb, vb, p5, p7);
    reduce_kernel   <<<2048, 256, 0, stream>>>(p5, p7, kb, vb);
    repack_ff_kernel<<<224,  256, 0, stream>>>(W1, W2, Wm, w1p, w2p, wmp);
    cast_qk_kernel  <<<1024, 256, 0, stream>>>(qb, kb, qbt, kbt);
    qk_sm_kernel    <<<1024, 512, 0, stream>>>(qbt, kbt, vis);
    kv_kernel       <<<128,  256, 0, stream>>>(kb, vb, KVp, Ksump);
    msg_kernel      <<<128,  256, 0, stream>>>(qb, KVp, Ksump, msg);
    ff_fused_kernel <<<512,  256, 0, stream>>>(x, msg, wmp, w1p, w2p,
                                               g1, b1, g2, b2, out);
}

// Round 13
// 269.105 us; speedup vs baseline: 1.2121x; 1.0186x over previous
//
#include <hip/hip_runtime.h>

#define DEV __device__ __forceinline__

typedef unsigned short u16;
typedef unsigned int u32;
typedef __bf16 bf16x8 __attribute__((ext_vector_type(8)));
typedef float f32x4 __attribute__((ext_vector_type(4)));

DEV float elu1(float x) { return x > 0.f ? x + 1.f : __expf(x); }

DEV u16 f2bf(float f) {
    union { float f; unsigned u; } v; v.f = f;
    unsigned r = v.u + 0x7fffu + ((v.u >> 16) & 1u);
    return (u16)(r >> 16);
}

DEV float bf2f(u16 h) {
    union { u32 u; float f; } v; v.u = ((u32)h) << 16; return v.f;
}

// ===========================================================================
// prep1 = conv-weight repack (validated R2)  ||  cast_src (validated R5).
// ===========================================================================
__global__ __launch_bounds__(256) void prep1_kernel(
    const float* __restrict__ Wq,
    const float* __restrict__ Wk1, const float* __restrict__ Wk3,
    const float* __restrict__ Wk5, const float* __restrict__ Wk7,
    const float* __restrict__ Wv1, const float* __restrict__ Wv3,
    const float* __restrict__ Wv5, const float* __restrict__ Wv7,
    u16* __restrict__ wpack,
    const float* __restrict__ x, const float* __restrict__ src,
    u16* __restrict__ xbh, u16* __restrict__ sbh)
{
    __shared__ float lds[32 * 129];
    const int t = threadIdx.x;
    if (blockIdx.x < 1632) {
        int gid = blockIdx.x * 256 + t;
        int frag = gid >> 6, l = gid & 63;
        const float* W; int K, ocbase = 0, rel;
        if (frag < 1152) {
            W = Wq; K = 3; int slot = frag / 288; rel = frag % 288; ocbase = slot * 64;
        } else {
            int f = frag - 1152; int side = f / 2688; f %= 2688;
            if (f < 32)        { W = side ? Wv1 : Wk1; K = 1; rel = f; }
            else if (f < 320)  { W = side ? Wv3 : Wk3; K = 3; rel = f - 32; }
            else if (f < 1120) { W = side ? Wv5 : Wk5; K = 5; rel = f - 320; }
            else               { W = side ? Wv7 : Wk7; K = 7; rel = f - 1120; }
        }
        int og = rel & 3, cc = (rel >> 2) & 7, tap = rel >> 5;
        int dy = tap / K, dx = tap % K;
        int oc = ocbase + og * 16 + (l & 15);
        int c0 = cc * 32 + (l >> 4) * 8;
        u16 pk[8];
#pragma unroll
        for (int j = 0; j < 8; ++j)
            pk[j] = f2bf(W[((size_t)(oc * 256 + c0 + j) * K + dy) * K + dx]);
        *(int4*)&wpack[(size_t)frag * 512 + l * 8] = *(const int4*)pk;
        return;
    }
    const int i = blockIdx.x - 1632;    // 1024 cast_src blocks
    const int inp = i >> 9, rem = i & 511;
    const int b = rem >> 6, cc = (rem >> 3) & 7, pxb = rem & 7;
    const float* in = (inp ? src : x) + ((size_t)b * 256 + cc * 32) * 1024 + pxb * 128;
    u16* outp = (inp ? sbh : xbh) + (size_t)b * 262144 + (size_t)cc * 32768 + pxb * 128 * 32;
#pragma unroll
    for (int u = 0; u < 4; ++u) {
        int unit = t + u * 256;
        int r = unit >> 5, px4 = unit & 31;
        float4 v = *(const float4*)(in + (size_t)r * 1024 + px4 * 4);
        lds[r * 129 + px4 * 4 + 0] = v.x;
        lds[r * 129 + px4 * 4 + 1] = v.y;
        lds[r * 129 + px4 * 4 + 2] = v.z;
        lds[r * 129 + px4 * 4 + 3] = v.w;
    }
    __syncthreads();
#pragma unroll
    for (int u = 0; u < 2; ++u) {
        int unit = t + u * 256;
        int px = unit >> 2, cg = unit & 3;
        u16 pk[8];
#pragma unroll
        for (int j = 0; j < 8; ++j) pk[j] = f2bf(lds[(cg * 8 + j) * 129 + px]);
        *(int4*)&outp[px * 32 + cg * 8] = *(const int4*)pk;
    }
}

// ===========================================================================
// MFMA implicit-GEMM conv (exact R9 body: validated 88.7us, VGPR 108).
// ===========================================================================
template<int K>
DEV void conv_mfma_body(const u16* __restrict__ srcb,
                        const u16* __restrict__ wsec,
                        float* __restrict__ dst,
                        u16* Bt, int y0, int cch0, int ncc, int t)
{
    constexpr int P = K / 2;
    const int w = t >> 6, l = t & 63;
    const int chi = l >> 4, ln = l & 15;
    const int rowbase = chi * 22 + w * 2 + 3 - P;
    const int colbase = ln + 3 - P;
    f32x4 acc[4][4];
#pragma unroll
    for (int m = 0; m < 4; ++m)
#pragma unroll
        for (int n = 0; n < 4; ++n) acc[m][n] = (f32x4){0.f, 0.f, 0.f, 0.f};

    for (int cc = 0; cc < ncc; ++cc) {
        const int ccg = cch0 + cc;
        __syncthreads();
#pragma unroll
        for (int u = 0; u < 7; ++u) {
            int unit = t + (u << 9);
            if (unit < 2816) {
                int xv = unit & 31, r = unit >> 5;
                int yy = r % 22, ch = r / 22;
                int ygl = y0 - 3 + yy;
                int4 pk;
                if ((unsigned)ygl < 32u)
                    pk = *(const int4*)&srcb[(size_t)ccg * 32768 + (ygl * 32 + xv) * 32 + ch * 8];
                else
                    pk = (int4){0, 0, 0, 0};
                *(int4*)&Bt[((ch * 22 + yy) * 40 + xv + 3) * 8] = pk;
            } else if (unit < 3520) {
                int hu = unit - 2816;
                int hx = hu & 7; int xi = hx < 3 ? hx : hx + 32;
                int r = hu >> 3; int yy = r % 22, ch = r / 22;
                int4 z = {0, 0, 0, 0};
                *(int4*)&Bt[((ch * 22 + yy) * 40 + xi) * 8] = z;
            }
        }
        __syncthreads();
#pragma unroll
        for (int dy = 0; dy < K; ++dy) {
#pragma unroll
            for (int dx = 0; dx < K; ++dx) {
                const int tap = dy * K + dx;
                const u16* wp = wsec + ((size_t)(tap * 8 + ccg) * 4) * 512 + l * 8;
                bf16x8 a0 = *(const bf16x8*)(wp);
                bf16x8 a1 = *(const bf16x8*)(wp + 512);
                bf16x8 a2 = *(const bf16x8*)(wp + 1024);
                bf16x8 a3 = *(const bf16x8*)(wp + 1536);
                bf16x8 bf[4];
#pragma unroll
                for (int n = 0; n < 4; ++n) {
                    int row = rowbase + dy + (n >> 1);
                    int col = colbase + dx + (n & 1) * 16;
                    bf[n] = *(const bf16x8*)&Bt[(row * 40 + col) * 8];
                }
#pragma unroll
                for (int n = 0; n < 4; ++n) {
                    acc[0][n] = __builtin_amdgcn_mfma_f32_16x16x32_bf16(a0, bf[n], acc[0][n], 0, 0, 0);
                    acc[1][n] = __builtin_amdgcn_mfma_f32_16x16x32_bf16(a1, bf[n], acc[1][n], 0, 0, 0);
                    acc[2][n] = __builtin_amdgcn_mfma_f32_16x16x32_bf16(a2, bf[n], acc[2][n], 0, 0, 0);
                    acc[3][n] = __builtin_amdgcn_mfma_f32_16x16x32_bf16(a3, bf[n], acc[3][n], 0, 0, 0);
                }
            }
        }
    }
#pragma unroll
    for (int m = 0; m < 4; ++m)
#pragma unroll
        for (int n = 0; n < 4; ++n) {
            int y = y0 + w * 2 + (n >> 1);
            int px = y * 32 + (n & 1) * 16 + ln;
            int ocb = m * 16 + chi * 4;
#pragma unroll
            for (int r = 0; r < 4; ++r)
                dst[(size_t)(ocb + r) * 1024 + px] = acc[m][n][r];
        }
}

__global__ __launch_bounds__(512) void conv_mfma_kernel(
    const u16* __restrict__ xbh, const u16* __restrict__ sbh,
    const u16* __restrict__ wpack,
    float* __restrict__ qb, float* __restrict__ kb, float* __restrict__ vb,
    float* __restrict__ p5, float* __restrict__ p7)
{
    __shared__ u16 Bt[4 * 22 * 40 * 8];
    const int bx = blockIdx.x, t = threadIdx.x;
    const int g = bx & 31, b = (bx >> 5) & 7, m = bx >> 8;
    if (g < 4) {
        conv_mfma_body<3>(xbh + (size_t)b * 262144,
                          wpack + (size_t)(g * 288) * 512,
                          qb + ((size_t)b * 256 + g * 64) * 1024,
                          Bt, m * 16, 0, 8, t);
        return;
    }
    const int gs = g - 4;
    const int side = gs / 14, gg = gs % 14;
    const u16* sp = sbh + (size_t)b * 262144;
    float* fin = side ? vb : kb;
    const size_t wkb = 1152 + (size_t)side * 2688;
    if (gg == 0) {
        conv_mfma_body<1>(sp, wpack + (wkb + 0) * 512,
                          fin + ((size_t)b * 256) * 1024, Bt, m * 16, 0, 8, t);
    } else if (gg == 1) {
        conv_mfma_body<3>(sp, wpack + (wkb + 32) * 512,
                          fin + ((size_t)b * 256 + 64) * 1024, Bt, m * 16, 0, 8, t);
    } else if (gg < 6) {
        int cpart = gg - 2;
        conv_mfma_body<5>(sp, wpack + (wkb + 320) * 512,
                          p5 + (((size_t)side * 4 + cpart) * 8 + b) * 65536,
                          Bt, m * 16, cpart * 2, 2, t);
    } else {
        int cpart = gg - 6;
        conv_mfma_body<7>(sp, wpack + (wkb + 1120) * 512,
                          p7 + (((size_t)side * 8 + cpart) * 8 + b) * 65536,
                          Bt, m * 16, cpart, 1, t);
    }
}

// ===========================================================================
// prep2 = reduce (validated R6) || FF/Wm repack (validated R11/R12).
// ===========================================================================
__global__ __launch_bounds__(256) void prep2_kernel(
    const float* __restrict__ p5, const float* __restrict__ p7,
    float* __restrict__ kb, float* __restrict__ vb,
    const float* __restrict__ W1, const float* __restrict__ W2,
    const float* __restrict__ Wm,
    u16* __restrict__ w1p, u16* __restrict__ w2p, u16* __restrict__ wmp)
{
    const int t = threadIdx.x;
    if (blockIdx.x < 2048) {
        int gid = blockIdx.x * 256 + t;
        int px4 = gid & 255;
        int rr = gid >> 8;
        int oc = rr & 63, b = (rr >> 6) & 7, head = (rr >> 9) & 1, side = rr >> 10;
        float* outb = side ? vb : kb;
        float4 s = make_float4(0.f, 0.f, 0.f, 0.f);
        if (head == 0) {
#pragma unroll
            for (int p = 0; p < 4; ++p) {
                float4 u = *((const float4*)(p5 + (((size_t)side * 4 + p) * 8 + b) * 65536 + (size_t)oc * 1024) + px4);
                s.x += u.x; s.y += u.y; s.z += u.z; s.w += u.w;
            }
            *((float4*)(outb + ((size_t)b * 256 + 128 + oc) * 1024) + px4) = s;
        } else {
#pragma unroll
            for (int p = 0; p < 8; ++p) {
                float4 u = *((const float4*)(p7 + (((size_t)side * 8 + p) * 8 + b) * 65536 + (size_t)oc * 1024) + px4);
                s.x += u.x; s.y += u.y; s.z += u.z; s.w += u.w;
            }
            *((float4*)(outb + ((size_t)b * 256 + 192 + oc) * 1024) + px4) = s;
        }
        return;
    }
    int gid = (blockIdx.x - 2048) * 256 + t;    // 224 blocks, 896 frags
    int f = gid >> 6, l = gid & 63;
    if (f >= 896) return;
    u16 pk[8];
    if (f < 512) {
        int ks = f >> 5, nf = f & 31;
#pragma unroll
        for (int j = 0; j < 8; ++j)
            pk[j] = f2bf(W1[(size_t)(ks * 32 + (l >> 4) * 8 + j) * 512 + nf * 16 + (l & 15)]);
        *(int4*)&w1p[(size_t)f * 512 + l * 8] = *(const int4*)pk;
    } else if (f < 768) {
        int f2 = f - 512;
        int ks = f2 >> 4, nf = f2 & 15;
#pragma unroll
        for (int j = 0; j < 8; ++j)
            pk[j] = f2bf(W2[(size_t)(ks * 32 + (l >> 4) * 8 + j) * 256 + nf * 16 + (l & 15)]);
        *(int4*)&w2p[(size_t)f2 * 512 + l * 8] = *(const int4*)pk;
    } else {
        int f3 = f - 768;
        int ks = f3 >> 4, nf = f3 & 15;
#pragma unroll
        for (int j = 0; j < 8; ++j)
            pk[j] = f2bf(Wm[(size_t)(ks * 32 + (l >> 4) * 8 + j) * 256 + nf * 16 + (l & 15)]);
        *(int4*)&wmp[(size_t)f3 * 512 + l * 8] = *(const int4*)pk;
    }
}

// ===========================================================================
// prep3 = cast_qk (validated R6) || kv (validated R2). Both depend only on
// reduce output; co-dispatched.
// ===========================================================================
__global__ __launch_bounds__(256) void prep3_kernel(
    const float* __restrict__ qb, const float* __restrict__ kb,
    const float* __restrict__ vb,
    u16* __restrict__ qbt, u16* __restrict__ kbt,
    float* __restrict__ KVp, float* __restrict__ Ksump)
{
    __shared__ float4 smem4[2112];      // kv: Kt(64*17) + Vt(64*16); cast: 16.6KB
    const int t = threadIdx.x;
    if (blockIdx.x < 1024) {
        float* lds = (float*)smem4;     // [64][65]
        const int i = blockIdx.x;
        const int inp = i >> 9, rem = i & 511;
        const int b = rem >> 6, h = (rem >> 4) & 3, pxb = rem & 15;
        const float* in = (inp ? kb : qb) + ((size_t)b * 256 + h * 64) * 1024 + pxb * 64;
        u16* outp = (inp ? kbt : qbt) + (((size_t)(b * 4 + h)) * 1024 + pxb * 64) * 64;
#pragma unroll
        for (int u = 0; u < 4; ++u) {
            int unit = t + u * 256;
            int r = unit >> 4, px4 = unit & 15;
            float4 v = *(const float4*)(in + (size_t)r * 1024 + px4 * 4);
            lds[r * 65 + px4 * 4 + 0] = v.x;
            lds[r * 65 + px4 * 4 + 1] = v.y;
            lds[r * 65 + px4 * 4 + 2] = v.z;
            lds[r * 65 + px4 * 4 + 3] = v.w;
        }
        __syncthreads();
#pragma unroll
        for (int u = 0; u < 2; ++u) {
            int unit = t + u * 256;
            int px = unit >> 3, cg = unit & 7;
            u16 pk[8];
#pragma unroll
            for (int j = 0; j < 8; ++j) pk[j] = f2bf(lds[(cg * 8 + j) * 65 + px]);
            *(int4*)&outp[px * 64 + cg * 8] = *(const int4*)pk;
        }
        return;
    }
    // ---- kv path ----
    float4* Kt4 = smem4;                // [64*17]
    float4* Vt4 = smem4 + 64 * 17;      // [64*16]
    float* Kt = (float*)Kt4;
    float* Vt = (float*)Vt4;
    const int bx = blockIdx.x - 1024;   // 128 blocks
    const int b = bx >> 4, h = (bx >> 2) & 3, ch = bx & 3;
    const float* kp = kb + ((size_t)b * 256 + h * 64) * 1024 + ch * 256;
    const float* vp = vb + ((size_t)b * 256 + h * 64) * 1024 + ch * 256;
    const int d = t >> 2, v0 = (t & 3) * 16;
    float4 acc[4];
#pragma unroll
    for (int j = 0; j < 4; ++j) acc[j] = make_float4(0.f, 0.f, 0.f, 0.f);
    float ks = 0.f;
    for (int st = 0; st < 4; ++st) {
        __syncthreads();
        {
            int dd = t >> 2, r0 = (t & 3) * 16;
#pragma unroll
            for (int mm = 0; mm < 4; ++mm) {
                float4 kv = *(const float4*)(kp + dd * 1024 + st * 64 + r0 + mm * 4);
                Kt[(r0 + mm * 4 + 0) * 68 + dd] = elu1(kv.x);
                Kt[(r0 + mm * 4 + 1) * 68 + dd] = elu1(kv.y);
                Kt[(r0 + mm * 4 + 2) * 68 + dd] = elu1(kv.z);
                Kt[(r0 + mm * 4 + 3) * 68 + dd] = elu1(kv.w);
                float4 vv = *(const float4*)(vp + dd * 1024 + st * 64 + r0 + mm * 4);
                Vt[(r0 + mm * 4 + 0) * 64 + dd] = vv.x;
                Vt[(r0 + mm * 4 + 1) * 64 + dd] = vv.y;
                Vt[(r0 + mm * 4 + 2) * 64 + dd] = vv.z;
                Vt[(r0 + mm * 4 + 3) * 64 + dd] = vv.w;
            }
        }
        __syncthreads();
#pragma unroll 8
        for (int s = 0; s < 64; ++s) {
            float kf = Kt[s * 68 + d];
            const float4* vvp = (const float4*)(Vt + s * 64 + v0);
#pragma unroll
            for (int j = 0; j < 4; ++j) {
                float4 vv = vvp[j];
                acc[j].x += kf * vv.x; acc[j].y += kf * vv.y;
                acc[j].z += kf * vv.z; acc[j].w += kf * vv.w;
            }
        }
        if (t < 64) {
#pragma unroll 8
            for (int s = 0; s < 64; ++s) ks += Kt[s * 68 + t];
        }
    }
    float* op = KVp + ((size_t)((ch * 32 + b * 4 + h) * 64 + d)) * 64 + v0;
#pragma unroll
    for (int j = 0; j < 4; ++j) ((float4*)op)[j] = acc[j];
    if (t < 64) Ksump[(size_t)(ch * 32 + b * 4 + h) * 64 + t] = ks;
}

// ===========================================================================
// qk_sm (validated R12) || msg (R13 rewrite: bf16 Q rows from qbt, float4
// KVp staging, 512 threads). 1024 qk blocks + 64 msg blocks.
// ===========================================================================
__global__ __launch_bounds__(512) void qk_sm_msg_kernel(
    const u16* __restrict__ qbt, const u16* __restrict__ kbt,
    float* __restrict__ vis,
    const float* __restrict__ KVp, const float* __restrict__ Ksump,
    float* __restrict__ msg)
{
    __shared__ float4 smem4[4178];      // 66,848 B union
    const int t = threadIdx.x;
    if (blockIdx.x < 1024) {
        u16* kf = (u16*)smem4;
        u16* qf = (u16*)smem4 + 32 * 512;
        float* redM = (float*)((char*)smem4 + 36864);
        float* redS = redM + 256;
        const int bx = blockIdx.x;
        const int b = bx >> 7, h = (bx >> 5) & 3, l0 = (bx & 31) * 32;
        const u16* qtp = qbt + ((size_t)(b * 4 + h)) * 1024 * 64;
        const u16* ktp = kbt + ((size_t)(b * 4 + h)) * 1024 * 64;

        if (t < 256) {
            int r = t & 31, dblk = t >> 5;
            int4 pk = *(const int4*)&qtp[(size_t)(l0 + r) * 64 + dblk * 8];
            *(int4*)&qf[(((r >> 4) * 2 + (dblk >> 2)) * 64 + (dblk & 3) * 16 + (r & 15)) * 8] = pk;
        }
        __syncthreads();

        const int w = t >> 6, l = t & 63, ln = l & 15, lg = l >> 4;
        bf16x8 a[2][2];
#pragma unroll
        for (int fr = 0; fr < 2; ++fr)
#pragma unroll
            for (int ks = 0; ks < 2; ++ks)
                a[fr][ks] = *(const bf16x8*)&qf[((fr * 2 + ks) * 64 + l) * 8];

        f32x4 acc[2][4][2];
#pragma unroll
        for (int fr = 0; fr < 2; ++fr)
#pragma unroll
            for (int cc = 0; cc < 4; ++cc)
#pragma unroll
                for (int f = 0; f < 2; ++f) acc[fr][cc][f] = (f32x4){0.f, 0.f, 0.f, 0.f};

#pragma unroll
        for (int cc = 0; cc < 4; ++cc) {
            __syncthreads();
#pragma unroll
            for (int it = 0; it < 4; ++it) {
                int unit = it * 512 + t;
                int sl = unit & 255, dblk = unit >> 8;
                int4 pk = *(const int4*)&ktp[(size_t)(cc * 256 + sl) * 64 + dblk * 8];
                *(int4*)&kf[(((sl >> 4) * 2 + (dblk >> 2)) * 64 + (dblk & 3) * 16 + (sl & 15)) * 8] = pk;
            }
            __syncthreads();
#pragma unroll
            for (int f = 0; f < 2; ++f) {
                int fg = (w * 2 + f) * 2;
                bf16x8 b0 = *(const bf16x8*)&kf[((fg + 0) * 64 + l) * 8];
                bf16x8 b1 = *(const bf16x8*)&kf[((fg + 1) * 64 + l) * 8];
#pragma unroll
                for (int fr = 0; fr < 2; ++fr) {
                    acc[fr][cc][f] = __builtin_amdgcn_mfma_f32_16x16x32_bf16(a[fr][0], b0, acc[fr][cc][f], 0, 0, 0);
                    acc[fr][cc][f] = __builtin_amdgcn_mfma_f32_16x16x32_bf16(a[fr][1], b1, acc[fr][cc][f], 0, 0, 0);
                }
            }
        }

#pragma unroll
        for (int fr = 0; fr < 2; ++fr)
#pragma unroll
            for (int cc = 0; cc < 4; ++cc)
#pragma unroll
                for (int f = 0; f < 2; ++f)
#pragma unroll
                    for (int e = 0; e < 4; ++e) acc[fr][cc][f][e] *= 0.125f;

        float rmax[2][4];
#pragma unroll
        for (int fr = 0; fr < 2; ++fr)
#pragma unroll
            for (int reg = 0; reg < 4; ++reg) {
                float m = -1e30f;
#pragma unroll
                for (int cc = 0; cc < 4; ++cc)
#pragma unroll
                    for (int f = 0; f < 2; ++f) m = fmaxf(m, acc[fr][cc][f][reg]);
#pragma unroll
                for (int off = 1; off < 16; off <<= 1) m = fmaxf(m, __shfl_xor(m, off));
                if (ln == 0) redM[(fr * 16 + lg * 4 + reg) * 8 + w] = m;
                rmax[fr][reg] = m;
            }
        __syncthreads();
#pragma unroll
        for (int fr = 0; fr < 2; ++fr)
#pragma unroll
            for (int reg = 0; reg < 4; ++reg) {
                int r = fr * 16 + lg * 4 + reg;
                float m = redM[r * 8];
#pragma unroll
                for (int ww = 1; ww < 8; ++ww) m = fmaxf(m, redM[r * 8 + ww]);
                rmax[fr][reg] = m;
            }
#pragma unroll
        for (int fr = 0; fr < 2; ++fr)
#pragma unroll
            for (int reg = 0; reg < 4; ++reg) {
                float s = 0.f;
                float m = rmax[fr][reg];
#pragma unroll
                for (int cc = 0; cc < 4; ++cc)
#pragma unroll
                    for (int f = 0; f < 2; ++f) {
                        float e = __expf(acc[fr][cc][f][reg] - m);
                        acc[fr][cc][f][reg] = e;
                        s += e;
                    }
#pragma unroll
                for (int off = 1; off < 16; off <<= 1) s += __shfl_xor(s, off);
                if (ln == 0) redS[(fr * 16 + lg * 4 + reg) * 8 + w] = s;
            }
        __syncthreads();
        float invv[2][4];
#pragma unroll
        for (int fr = 0; fr < 2; ++fr)
#pragma unroll
            for (int reg = 0; reg < 4; ++reg) {
                int r = fr * 16 + lg * 4 + reg;
                float s = redS[r * 8] + redS[r * 8 + 1] + redS[r * 8 + 2] + redS[r * 8 + 3]
                        + redS[r * 8 + 4] + redS[r * 8 + 5] + redS[r * 8 + 6] + redS[r * 8 + 7];
                invv[fr][reg] = 1.f / s;
            }
        float* outT = (float*)smem4;    // [32][260] f32
        float* visp = vis + (((size_t)(b * 4 + h)) << 20);
#pragma unroll
        for (int cc = 0; cc < 4; ++cc) {
            __syncthreads();
#pragma unroll
            for (int fr = 0; fr < 2; ++fr)
#pragma unroll
                for (int reg = 0; reg < 4; ++reg) {
                    int r = fr * 16 + lg * 4 + reg;
#pragma unroll
                    for (int f = 0; f < 2; ++f)
                        outT[r * 260 + w * 32 + f * 16 + ln] = acc[fr][cc][f][reg] * invv[fr][reg];
                }
            __syncthreads();
#pragma unroll
            for (int u = 0; u < 4; ++u) {
                int unit = u * 512 + t;
                int r = unit >> 6, c4 = unit & 63;
                float4 v = *(const float4*)&outT[r * 260 + c4 * 4];
                *(float4*)&visp[(size_t)(l0 + r) * 1024 + cc * 256 + c4 * 4] = v;
            }
        }
        return;
    }
    // ---- msg path (64 blocks, 512 threads) ----
    float* kvl = (float*)smem4;             // [4][4112]
    float* ksl = (float*)smem4 + 4 * 4112;  // [4][65]
    const int bx2 = blockIdx.x - 1024;
    const int b = bx2 >> 3, l0 = (bx2 & 7) * 128;
    // stage KV (sum 4 chunks) via float4
#pragma unroll
    for (int m = 0; m < 8; ++m) {
        int unit = t + (m << 9);            // 4096 float4 units
        int hh = unit >> 10, dd = (unit >> 4) & 63, v4 = unit & 15;
        float4 s = make_float4(0.f, 0.f, 0.f, 0.f);
#pragma unroll
        for (int ch = 0; ch < 4; ++ch) {
            float4 u = *(const float4*)&KVp[((size_t)(ch * 32 + b * 4)) * 4096 + (size_t)unit * 4];
            s.x += u.x; s.y += u.y; s.z += u.z; s.w += u.w;
        }
        *(float4*)&kvl[hh * 4112 + dd * 64 + v4 * 4] = s;
    }
    if (t < 256) {
        float s = 0.f;
#pragma unroll
        for (int ch = 0; ch < 4; ++ch)
            s += Ksump[(size_t)(ch * 32 + b * 4) * 64 + t];
        ksl[(t >> 6) * 65 + (t & 63)] = s;
    }
    __syncthreads();
    const int h = t & 3, l = l0 + (t >> 2);
    const u16* qrow = qbt + ((size_t)(b * 4 + h) * 1024 + l) * 64;
    float qf[64];
#pragma unroll
    for (int j8 = 0; j8 < 8; ++j8) {
        int4 pk = *(const int4*)&qrow[j8 * 8];
        const u16* pku = (const u16*)&pk;
#pragma unroll
        for (int e = 0; e < 8; ++e) qf[j8 * 8 + e] = elu1(bf2f(pku[e]));
    }
    float zd = 1e-6f;
#pragma unroll
    for (int dd = 0; dd < 64; ++dd) zd += qf[dd] * ksl[h * 65 + dd];
    const float Z = 1.f / zd;
    float* op = msg + ((size_t)(b * 1024 + l)) * 256 + h * 64;
    for (int c0 = 0; c0 < 64; c0 += 16) {
        float4 a[4];
#pragma unroll
        for (int j = 0; j < 4; ++j) a[j] = make_float4(0.f, 0.f, 0.f, 0.f);
#pragma unroll
        for (int dd = 0; dd < 64; ++dd) {
            float qv = qf[dd];
            const float4* kp = (const float4*)(kvl + h * 4112 + dd * 64 + c0);
#pragma unroll
            for (int j = 0; j < 4; ++j) {
                float4 kk = kp[j];
                a[j].x += qv * kk.x; a[j].y += qv * kk.y;
                a[j].z += qv * kk.z; a[j].w += qv * kk.w;
            }
        }
#pragma unroll
        for (int j = 0; j < 4; ++j) {
            a[j].x *= Z; a[j].y *= Z; a[j].z *= Z; a[j].w *= Z;
            ((float4*)(op + c0))[j] = a[j];
        }
    }
}

// ===========================================================================
// Fused merge(Wm,LN1) + FF(W1,relu,W2,LN2) + residual (validated R12).
// ===========================================================================
__global__ __launch_bounds__(256) void ff_fused_kernel(
    const float* __restrict__ x, const float* __restrict__ msg,
    const u16* __restrict__ wmp,
    const u16* __restrict__ w1p, const u16* __restrict__ w2p,
    const float* __restrict__ g1, const float* __restrict__ b1,
    const float* __restrict__ g2, const float* __restrict__ b2,
    float* __restrict__ out)
{
    __shared__ u16 tile[16 * 520];
    __shared__ u16 mtile[16 * 264];
    __shared__ float redS[16 * 4];
    __shared__ float redQ[16 * 4];
    float* tf = (float*)tile;
    const int t = threadIdx.x;
    const int base = blockIdx.x * 16;   // 512 blocks
    const int b = base >> 10, l0 = base & 1023;
    const int w = t >> 6, l = t & 63, ln = l & 15, lg = l >> 4;

    {
        int rr = t & 15, cg = t >> 4;
        for (int cci = 0; cci < 16; ++cci) {
            int c = cci * 16 + cg;
            tile[rr * 520 + c] = f2bf(x[((size_t)b * 256 + c) * 1024 + l0 + rr]);
        }
        int r = t >> 4, cb = (t & 15) * 16;
#pragma unroll
        for (int i = 0; i < 4; ++i) {
            float4 v = *(const float4*)&msg[((size_t)(base + r)) * 256 + cb + i * 4];
            u32 p0 = (u32)f2bf(v.x) | ((u32)f2bf(v.y) << 16);
            u32 p1 = (u32)f2bf(v.z) | ((u32)f2bf(v.w) << 16);
            *(u32*)&mtile[r * 264 + cb + i * 4] = p0;
            *(u32*)&mtile[r * 264 + cb + i * 4 + 2] = p1;
        }
    }
    __syncthreads();

    f32x4 accm[4];
#pragma unroll
    for (int fc = 0; fc < 4; ++fc) accm[fc] = (f32x4){0.f, 0.f, 0.f, 0.f};
    for (int ks = 0; ks < 8; ++ks) {
        bf16x8 a0 = *(const bf16x8*)&mtile[ln * 264 + ks * 32 + lg * 8];
#pragma unroll
        for (int fc = 0; fc < 4; ++fc) {
            bf16x8 bb = *(const bf16x8*)&wmp[((size_t)(ks * 16 + w * 4 + fc) * 64 + l) * 8];
            accm[fc] = __builtin_amdgcn_mfma_f32_16x16x32_bf16(a0, bb, accm[fc], 0, 0, 0);
        }
    }
#pragma unroll
    for (int reg = 0; reg < 4; ++reg) {
        float s = 0.f, qsum = 0.f;
#pragma unroll
        for (int fc = 0; fc < 4; ++fc) {
            float v = accm[fc][reg];
            s += v; qsum += v * v;
        }
#pragma unroll
        for (int off = 1; off < 16; off <<= 1) {
            s += __shfl_xor(s, off);
            qsum += __shfl_xor(qsum, off);
        }
        if (ln == 0) {
            int r = lg * 4 + reg;
            redS[r * 4 + w] = s;
            redQ[r * 4 + w] = qsum;
        }
    }
    __syncthreads();
#pragma unroll
    for (int fc = 0; fc < 4; ++fc) {
        int c = w * 64 + fc * 16 + ln;
        float gg = g1[c], bb = b1[c];
#pragma unroll
        for (int reg = 0; reg < 4; ++reg) {
            int r = lg * 4 + reg;
            float s = redS[r * 4] + redS[r * 4 + 1] + redS[r * 4 + 2] + redS[r * 4 + 3];
            float qs = redQ[r * 4] + redQ[r * 4 + 1] + redQ[r * 4 + 2] + redQ[r * 4 + 3];
            float mean = s * (1.f / 256.f);
            float rstd = rsqrtf(qs * (1.f / 256.f) - mean * mean + 1e-5f);
            tile[r * 520 + 256 + c] = f2bf((accm[fc][reg] - mean) * rstd * gg + bb);
        }
    }
    __syncthreads();

    f32x4 acc1[8];
#pragma unroll
    for (int fc = 0; fc < 8; ++fc) acc1[fc] = (f32x4){0.f, 0.f, 0.f, 0.f};
    for (int ks = 0; ks < 16; ++ks) {
        bf16x8 a0 = *(const bf16x8*)&tile[ln * 520 + ks * 32 + lg * 8];
#pragma unroll
        for (int fc = 0; fc < 8; ++fc) {
            bf16x8 bb = *(const bf16x8*)&w1p[((size_t)(ks * 32 + w * 8 + fc) * 64 + l) * 8];
            acc1[fc] = __builtin_amdgcn_mfma_f32_16x16x32_bf16(a0, bb, acc1[fc], 0, 0, 0);
        }
    }
    __syncthreads();
#pragma unroll
    for (int fc = 0; fc < 8; ++fc)
#pragma unroll
        for (int reg = 0; reg < 4; ++reg) {
            int r = lg * 4 + reg;
            int c = w * 128 + fc * 16 + ln;
            tile[r * 520 + c] = f2bf(fmaxf(acc1[fc][reg], 0.f));
        }
    __syncthreads();

    f32x4 acc2[4];
#pragma unroll
    for (int fc = 0; fc < 4; ++fc) acc2[fc] = (f32x4){0.f, 0.f, 0.f, 0.f};
    for (int ks = 0; ks < 16; ++ks) {
        bf16x8 a0 = *(const bf16x8*)&tile[ln * 520 + ks * 32 + lg * 8];
#pragma unroll
        for (int fc = 0; fc < 4; ++fc) {
            bf16x8 bb = *(const bf16x8*)&w2p[((size_t)(ks * 16 + w * 4 + fc) * 64 + l) * 8];
            acc2[fc] = __builtin_amdgcn_mfma_f32_16x16x32_bf16(a0, bb, acc2[fc], 0, 0, 0);
        }
    }
#pragma unroll
    for (int reg = 0; reg < 4; ++reg) {
        float s = 0.f, qsum = 0.f;
#pragma unroll
        for (int fc = 0; fc < 4; ++fc) {
            float v = acc2[fc][reg];
            s += v; qsum += v * v;
        }
#pragma unroll
        for (int off = 1; off < 16; off <<= 1) {
            s += __shfl_xor(s, off);
            qsum += __shfl_xor(qsum, off);
        }
        if (ln == 0) {
            int r = lg * 4 + reg;
            redS[r * 4 + w] = s;
            redQ[r * 4 + w] = qsum;
        }
    }
    __syncthreads();
    float mean[4], rstd[4];
#pragma unroll
    for (int reg = 0; reg < 4; ++reg) {
        int r = lg * 4 + reg;
        float s = redS[r * 4] + redS[r * 4 + 1] + redS[r * 4 + 2] + redS[r * 4 + 3];
        float qs = redQ[r * 4] + redQ[r * 4 + 1] + redQ[r * 4 + 2] + redQ[r * 4 + 3];
        float m = s * (1.f / 256.f);
        mean[reg] = m;
        rstd[reg] = rsqrtf(qs * (1.f / 256.f) - m * m + 1e-5f);
    }
    __syncthreads();
#pragma unroll
    for (int fc = 0; fc < 4; ++fc) {
        int c = w * 64 + fc * 16 + ln;
        float gg = g2[c], bb = b2[c];
#pragma unroll
        for (int reg = 0; reg < 4; ++reg) {
            int r = lg * 4 + reg;
            tf[r * 260 + c] = (acc2[fc][reg] - mean[reg]) * rstd[reg] * gg + bb;
        }
    }
    __syncthreads();
    {
        const float* xp = x + ((size_t)b * 256 + t) * 1024 + l0;
        float* op = out + ((size_t)b * 256 + t) * 1024 + l0;
#pragma unroll
        for (int i = 0; i < 4; ++i) {
            float4 xv = *(const float4*)(xp + i * 4);
            float4 o;
            o.x = xv.x + tf[(i * 4 + 0) * 260 + t];
            o.y = xv.y + tf[(i * 4 + 1) * 260 + t];
            o.z = xv.z + tf[(i * 4 + 2) * 260 + t];
            o.w = xv.w + tf[(i * 4 + 3) * 260 + t];
            *(float4*)(op + i * 4) = o;
        }
    }
}

// ---------------------------------------------------------------------------
extern "C" void kernel_launch(void* const* d_in, const int* in_sizes, int n_in,
                              void* d_out, int out_size, void* d_ws, size_t ws_size,
                              hipStream_t stream)
{
    const float* x    = (const float*)d_in[0];
    const float* src  = (const float*)d_in[1];
    const float* Wq   = (const float*)d_in[2];
    const float* Wk1  = (const float*)d_in[3];
    const float* Wk3  = (const float*)d_in[4];
    const float* Wk5  = (const float*)d_in[5];
    const float* Wk7  = (const float*)d_in[6];
    const float* Wv1  = (const float*)d_in[7];
    const float* Wv3  = (const float*)d_in[8];
    const float* Wv5  = (const float*)d_in[9];
    const float* Wv7  = (const float*)d_in[10];
    const float* Wm   = (const float*)d_in[11];
    const float* g1   = (const float*)d_in[12];
    const float* b1   = (const float*)d_in[13];
    const float* g2   = (const float*)d_in[14];
    const float* b2   = (const float*)d_in[15];
    const float* W1   = (const float*)d_in[16];
    const float* W2   = (const float*)d_in[17];

    float* out = (float*)d_out;
    float* vis = out + 2097152;          // [b,h,l,s]

    // Conv partials in vis region (dead until qk_sm overwrites all of it).
    float* p5 = vis;                     // [2][4][8][64][1024]
    float* p7 = vis + 4194304;           // [2][8][8][64][1024]

    // ws extent+lifetime map (float offsets; re-audited R13):
    //  qb    [0,        2097152)  conv..qk_sm_msg(msg via qbt only; qb dead after prep3)
    //  kb    [2097152,  4194304)  conv..prep3
    //  vb    [4194304,  6291456)  conv..prep3
    //  wpack [6291456,  7962624)  prep1..conv
    //    then w1p [6291456, 6422528) prep2..ff_fused
    //         w2p [6422528, 6488064) prep2..ff_fused
    //         wmp [6488064, 6520832) prep2..ff_fused
    //         qbt [6520832, 7569408) prep3..qk_sm_msg
    //         kbt [7569408, 8617984) prep3..qk_sm_msg
    //  xbh   [7962624,  9011200)  prep1..conv
    //  sbh   [9011200, 10059776)  prep1..conv
    //  msg   [10059776, 12156928) qk_sm_msg..ff_fused (no overlap with kbt!)
    //  KVp   [12156928, 12681216), Ksump [12681216, 12689408) prep3..qk_sm_msg
    float* ws    = (float*)d_ws;
    float* qb    = ws;
    float* kb    = ws + 2097152;
    float* vb    = ws + 4194304;
    u16*   wpack = (u16*)(ws + 6291456);
    u16*   w1p   = (u16*)(ws + 6291456);
    u16*   w2p   = (u16*)(ws + 6422528);
    u16*   wmp   = (u16*)(ws + 6488064);
    u16*   qbt   = (u16*)(ws + 6520832);
    u16*   kbt   = (u16*)(ws + 7569408);
    u16*   xbh   = (u16*)(ws + 7962624);
    u16*   sbh   = (u16*)(ws + 9011200);
    float* msg   = ws + 10059776;
    float* KVp   = ws + 12156928;
    float* Ksump = ws + 12681216;

    prep1_kernel    <<<2656, 256, 0, stream>>>(Wq, Wk1, Wk3, Wk5, Wk7,
                                               Wv1, Wv3, Wv5, Wv7, wpack,
                                               x, src, xbh, sbh);
    conv_mfma_kernel<<<512,  512, 0, stream>>>(xbh, sbh, wpack, qb, kb, vb, p5, p7);
    prep2_kernel    <<<2272, 256, 0, stream>>>(p5, p7, kb, vb,
                                               W1, W2, Wm, w1p, w2p, wmp);
    prep3_kernel    <<<1152, 256, 0, stream>>>(qb, kb, vb, qbt, kbt, KVp, Ksump);
    qk_sm_msg_kernel<<<1088, 512, 0, stream>>>(qbt, kbt, vis, KVp, Ksump, msg);
    ff_fused_kernel <<<512,  256, 0, stream>>>(x, msg, wmp, w1p, w2p,
                                               g1, b1, g2, b2, out);
}

// Round 15
// 267.610 us; speedup vs baseline: 1.2189x; 1.0056x over previous
//
#include <hip/hip_runtime.h>

#define DEV __device__ __forceinline__

typedef unsigned short u16;
typedef unsigned int u32;
typedef __bf16 bf16x8 __attribute__((ext_vector_type(8)));
typedef float f32x4 __attribute__((ext_vector_type(4)));

DEV float elu1(float x) { return x > 0.f ? x + 1.f : __expf(x); }

DEV u16 f2bf(float f) {
    union { float f; unsigned u; } v; v.f = f;
    unsigned r = v.u + 0x7fffu + ((v.u >> 16) & 1u);
    return (u16)(r >> 16);
}

DEV float bf2f(u16 h) {
    union { u32 u; float f; } v; v.u = ((u32)h) << 16; return v.f;
}

// ===========================================================================
// prep1 = conv-weight repack (validated R2)  ||  cast_src (validated R5).
// ===========================================================================
__global__ __launch_bounds__(256) void prep1_kernel(
    const float* __restrict__ Wq,
    const float* __restrict__ Wk1, const float* __restrict__ Wk3,
    const float* __restrict__ Wk5, const float* __restrict__ Wk7,
    const float* __restrict__ Wv1, const float* __restrict__ Wv3,
    const float* __restrict__ Wv5, const float* __restrict__ Wv7,
    u16* __restrict__ wpack,
    const float* __restrict__ x, const float* __restrict__ src,
    u16* __restrict__ xbh, u16* __restrict__ sbh)
{
    __shared__ float lds[32 * 129];
    const int t = threadIdx.x;
    if (blockIdx.x < 1632) {
        int gid = blockIdx.x * 256 + t;
        int frag = gid >> 6, l = gid & 63;
        const float* W; int K, ocbase = 0, rel;
        if (frag < 1152) {
            W = Wq; K = 3; int slot = frag / 288; rel = frag % 288; ocbase = slot * 64;
        } else {
            int f = frag - 1152; int side = f / 2688; f %= 2688;
            if (f < 32)        { W = side ? Wv1 : Wk1; K = 1; rel = f; }
            else if (f < 320)  { W = side ? Wv3 : Wk3; K = 3; rel = f - 32; }
            else if (f < 1120) { W = side ? Wv5 : Wk5; K = 5; rel = f - 320; }
            else               { W = side ? Wv7 : Wk7; K = 7; rel = f - 1120; }
        }
        int og = rel & 3, cc = (rel >> 2) & 7, tap = rel >> 5;
        int dy = tap / K, dx = tap % K;
        int oc = ocbase + og * 16 + (l & 15);
        int c0 = cc * 32 + (l >> 4) * 8;
        u16 pk[8];
#pragma unroll
        for (int j = 0; j < 8; ++j)
            pk[j] = f2bf(W[((size_t)(oc * 256 + c0 + j) * K + dy) * K + dx]);
        *(int4*)&wpack[(size_t)frag * 512 + l * 8] = *(const int4*)pk;
        return;
    }
    const int i = blockIdx.x - 1632;    // 1024 cast_src blocks
    const int inp = i >> 9, rem = i & 511;
    const int b = rem >> 6, cc = (rem >> 3) & 7, pxb = rem & 7;
    const float* in = (inp ? src : x) + ((size_t)b * 256 + cc * 32) * 1024 + pxb * 128;
    u16* outp = (inp ? sbh : xbh) + (size_t)b * 262144 + (size_t)cc * 32768 + pxb * 128 * 32;
#pragma unroll
    for (int u = 0; u < 4; ++u) {
        int unit = t + u * 256;
        int r = unit >> 5, px4 = unit & 31;
        float4 v = *(const float4*)(in + (size_t)r * 1024 + px4 * 4);
        lds[r * 129 + px4 * 4 + 0] = v.x;
        lds[r * 129 + px4 * 4 + 1] = v.y;
        lds[r * 129 + px4 * 4 + 2] = v.z;
        lds[r * 129 + px4 * 4 + 3] = v.w;
    }
    __syncthreads();
#pragma unroll
    for (int u = 0; u < 2; ++u) {
        int unit = t + u * 256;
        int px = unit >> 2, cg = unit & 3;
        u16 pk[8];
#pragma unroll
        for (int j = 0; j < 8; ++j) pk[j] = f2bf(lds[(cg * 8 + j) * 129 + px]);
        *(int4*)&outp[px * 32 + cg * 8] = *(const int4*)pk;
    }
}

// ===========================================================================
// MFMA implicit-GEMM conv (R9 body, validated 88.7us). QOUT variant writes
// bf16 transposed [l][64] directly (q path) — bit-identical values to the
// old fp32->cast_qk path, 16x8B stores vs 64 scalar dwords.
// ===========================================================================
template<int K, bool QOUT>
DEV void conv_mfma_body(const u16* __restrict__ srcb,
                        const u16* __restrict__ wsec,
                        float* __restrict__ dst, u16* __restrict__ qdst,
                        u16* Bt, int y0, int cch0, int ncc, int t)
{
    constexpr int P = K / 2;
    const int w = t >> 6, l = t & 63;
    const int chi = l >> 4, ln = l & 15;
    const int rowbase = chi * 22 + w * 2 + 3 - P;
    const int colbase = ln + 3 - P;
    f32x4 acc[4][4];
#pragma unroll
    for (int m = 0; m < 4; ++m)
#pragma unroll
        for (int n = 0; n < 4; ++n) acc[m][n] = (f32x4){0.f, 0.f, 0.f, 0.f};

    for (int cc = 0; cc < ncc; ++cc) {
        const int ccg = cch0 + cc;
        __syncthreads();
#pragma unroll
        for (int u = 0; u < 7; ++u) {
            int unit = t + (u << 9);
            if (unit < 2816) {
                int xv = unit & 31, r = unit >> 5;
                int yy = r % 22, ch = r / 22;
                int ygl = y0 - 3 + yy;
                int4 pk;
                if ((unsigned)ygl < 32u)
                    pk = *(const int4*)&srcb[(size_t)ccg * 32768 + (ygl * 32 + xv) * 32 + ch * 8];
                else
                    pk = (int4){0, 0, 0, 0};
                *(int4*)&Bt[((ch * 22 + yy) * 40 + xv + 3) * 8] = pk;
            } else if (unit < 3520) {
                int hu = unit - 2816;
                int hx = hu & 7; int xi = hx < 3 ? hx : hx + 32;
                int r = hu >> 3; int yy = r % 22, ch = r / 22;
                int4 z = {0, 0, 0, 0};
                *(int4*)&Bt[((ch * 22 + yy) * 40 + xi) * 8] = z;
            }
        }
        __syncthreads();
#pragma unroll
        for (int dy = 0; dy < K; ++dy) {
#pragma unroll
            for (int dx = 0; dx < K; ++dx) {
                const int tap = dy * K + dx;
                const u16* wp = wsec + ((size_t)(tap * 8 + ccg) * 4) * 512 + l * 8;
                bf16x8 a0 = *(const bf16x8*)(wp);
                bf16x8 a1 = *(const bf16x8*)(wp + 512);
                bf16x8 a2 = *(const bf16x8*)(wp + 1024);
                bf16x8 a3 = *(const bf16x8*)(wp + 1536);
                bf16x8 bf[4];
#pragma unroll
                for (int n = 0; n < 4; ++n) {
                    int row = rowbase + dy + (n >> 1);
                    int col = colbase + dx + (n & 1) * 16;
                    bf[n] = *(const bf16x8*)&Bt[(row * 40 + col) * 8];
                }
#pragma unroll
                for (int n = 0; n < 4; ++n) {
                    acc[0][n] = __builtin_amdgcn_mfma_f32_16x16x32_bf16(a0, bf[n], acc[0][n], 0, 0, 0);
                    acc[1][n] = __builtin_amdgcn_mfma_f32_16x16x32_bf16(a1, bf[n], acc[1][n], 0, 0, 0);
                    acc[2][n] = __builtin_amdgcn_mfma_f32_16x16x32_bf16(a2, bf[n], acc[2][n], 0, 0, 0);
                    acc[3][n] = __builtin_amdgcn_mfma_f32_16x16x32_bf16(a3, bf[n], acc[3][n], 0, 0, 0);
                }
            }
        }
    }
#pragma unroll
    for (int m = 0; m < 4; ++m)
#pragma unroll
        for (int n = 0; n < 4; ++n) {
            int y = y0 + w * 2 + (n >> 1);
            int px = y * 32 + (n & 1) * 16 + ln;
            int ocb = m * 16 + chi * 4;
            if (!QOUT) {
#pragma unroll
                for (int r = 0; r < 4; ++r)
                    dst[(size_t)(ocb + r) * 1024 + px] = acc[m][n][r];
            } else {
                u16 pk[4];
#pragma unroll
                for (int r = 0; r < 4; ++r) pk[r] = f2bf(acc[m][n][r]);
                *(uint2*)&qdst[(size_t)px * 64 + ocb] = *(const uint2*)pk;
            }
        }
}

// Job decode (R9 XCD grouping): bx = m*256 + b*32 + g, grid 512. XCD = g%8.
__global__ __launch_bounds__(512) void conv_mfma_kernel(
    const u16* __restrict__ xbh, const u16* __restrict__ sbh,
    const u16* __restrict__ wpack,
    u16* __restrict__ qbt, float* __restrict__ kb, float* __restrict__ vb,
    float* __restrict__ p5, float* __restrict__ p7)
{
    __shared__ u16 Bt[4 * 22 * 40 * 8];
    const int bx = blockIdx.x, t = threadIdx.x;
    const int g = bx & 31, b = (bx >> 5) & 7, m = bx >> 8;
    if (g < 4) {
        conv_mfma_body<3, true>(xbh + (size_t)b * 262144,
                          wpack + (size_t)(g * 288) * 512,
                          nullptr, qbt + ((size_t)(b * 4 + g)) * 65536,
                          Bt, m * 16, 0, 8, t);
        return;
    }
    const int gs = g - 4;
    const int side = gs / 14, gg = gs % 14;
    const u16* sp = sbh + (size_t)b * 262144;
    float* fin = side ? vb : kb;
    const size_t wkb = 1152 + (size_t)side * 2688;
    if (gg == 0) {
        conv_mfma_body<1, false>(sp, wpack + (wkb + 0) * 512,
                          fin + ((size_t)b * 256) * 1024, nullptr, Bt, m * 16, 0, 8, t);
    } else if (gg == 1) {
        conv_mfma_body<3, false>(sp, wpack + (wkb + 32) * 512,
                          fin + ((size_t)b * 256 + 64) * 1024, nullptr, Bt, m * 16, 0, 8, t);
    } else if (gg < 6) {
        int cpart = gg - 2;
        conv_mfma_body<5, false>(sp, wpack + (wkb + 320) * 512,
                          p5 + (((size_t)side * 4 + cpart) * 8 + b) * 65536, nullptr,
                          Bt, m * 16, cpart * 2, 2, t);
    } else {
        int cpart = gg - 6;
        conv_mfma_body<7, false>(sp, wpack + (wkb + 1120) * 512,
                          p7 + (((size_t)side * 8 + cpart) * 8 + b) * 65536, nullptr,
                          Bt, m * 16, cpart, 1, t);
    }
}

// ===========================================================================
// prep2 = reduce (validated R6) || FF/Wm repack (validated R11/R12).
// ===========================================================================
__global__ __launch_bounds__(256) void prep2_kernel(
    const float* __restrict__ p5, const float* __restrict__ p7,
    float* __restrict__ kb, float* __restrict__ vb,
    const float* __restrict__ W1, const float* __restrict__ W2,
    const float* __restrict__ Wm,
    u16* __restrict__ w1p, u16* __restrict__ w2p, u16* __restrict__ wmp)
{
    const int t = threadIdx.x;
    if (blockIdx.x < 2048) {
        int gid = blockIdx.x * 256 + t;
        int px4 = gid & 255;
        int rr = gid >> 8;
        int oc = rr & 63, b = (rr >> 6) & 7, head = (rr >> 9) & 1, side = rr >> 10;
        float* outb = side ? vb : kb;
        float4 s = make_float4(0.f, 0.f, 0.f, 0.f);
        if (head == 0) {
#pragma unroll
            for (int p = 0; p < 4; ++p) {
                float4 u = *((const float4*)(p5 + (((size_t)side * 4 + p) * 8 + b) * 65536 + (size_t)oc * 1024) + px4);
                s.x += u.x; s.y += u.y; s.z += u.z; s.w += u.w;
            }
            *((float4*)(outb + ((size_t)b * 256 + 128 + oc) * 1024) + px4) = s;
        } else {
#pragma unroll
            for (int p = 0; p < 8; ++p) {
                float4 u = *((const float4*)(p7 + (((size_t)side * 8 + p) * 8 + b) * 65536 + (size_t)oc * 1024) + px4);
                s.x += u.x; s.y += u.y; s.z += u.z; s.w += u.w;
            }
            *((float4*)(outb + ((size_t)b * 256 + 192 + oc) * 1024) + px4) = s;
        }
        return;
    }
    int gid = (blockIdx.x - 2048) * 256 + t;    // 224 blocks, 896 frags
    int f = gid >> 6, l = gid & 63;
    if (f >= 896) return;
    u16 pk[8];
    if (f < 512) {
        int ks = f >> 5, nf = f & 31;
#pragma unroll
        for (int j = 0; j < 8; ++j)
            pk[j] = f2bf(W1[(size_t)(ks * 32 + (l >> 4) * 8 + j) * 512 + nf * 16 + (l & 15)]);
        *(int4*)&w1p[(size_t)f * 512 + l * 8] = *(const int4*)pk;
    } else if (f < 768) {
        int f2 = f - 512;
        int ks = f2 >> 4, nf = f2 & 15;
#pragma unroll
        for (int j = 0; j < 8; ++j)
            pk[j] = f2bf(W2[(size_t)(ks * 32 + (l >> 4) * 8 + j) * 256 + nf * 16 + (l & 15)]);
        *(int4*)&w2p[(size_t)f2 * 512 + l * 8] = *(const int4*)pk;
    } else {
        int f3 = f - 768;
        int ks = f3 >> 4, nf = f3 & 15;
#pragma unroll
        for (int j = 0; j < 8; ++j)
            pk[j] = f2bf(Wm[(size_t)(ks * 32 + (l >> 4) * 8 + j) * 256 + nf * 16 + (l & 15)]);
        *(int4*)&wmp[(size_t)f3 * 512 + l * 8] = *(const int4*)pk;
    }
}

// ===========================================================================
// prep3 = k-cast (512 blocks; q now produced by conv) || kv (128 blocks).
// ===========================================================================
__global__ __launch_bounds__(256) void prep3_kernel(
    const float* __restrict__ kb, const float* __restrict__ vb,
    u16* __restrict__ kbt,
    float* __restrict__ KVp, float* __restrict__ Ksump)
{
    __shared__ float4 smem4[2112];
    const int t = threadIdx.x;
    if (blockIdx.x < 512) {
        float* lds = (float*)smem4;     // [64][65]
        const int rem = blockIdx.x;
        const int b = rem >> 6, h = (rem >> 4) & 3, pxb = rem & 15;
        const float* in = kb + ((size_t)b * 256 + h * 64) * 1024 + pxb * 64;
        u16* outp = kbt + (((size_t)(b * 4 + h)) * 1024 + pxb * 64) * 64;
#pragma unroll
        for (int u = 0; u < 4; ++u) {
            int unit = t + u * 256;
            int r = unit >> 4, px4 = unit & 15;
            float4 v = *(const float4*)(in + (size_t)r * 1024 + px4 * 4);
            lds[r * 65 + px4 * 4 + 0] = v.x;
            lds[r * 65 + px4 * 4 + 1] = v.y;
            lds[r * 65 + px4 * 4 + 2] = v.z;
            lds[r * 65 + px4 * 4 + 3] = v.w;
        }
        __syncthreads();
#pragma unroll
        for (int u = 0; u < 2; ++u) {
            int unit = t + u * 256;
            int px = unit >> 3, cg = unit & 7;
            u16 pk[8];
#pragma unroll
            for (int j = 0; j < 8; ++j) pk[j] = f2bf(lds[(cg * 8 + j) * 65 + px]);
            *(int4*)&outp[px * 64 + cg * 8] = *(const int4*)pk;
        }
        return;
    }
    // ---- kv path ----
    float4* Kt4 = smem4;
    float4* Vt4 = smem4 + 64 * 17;
    float* Kt = (float*)Kt4;
    float* Vt = (float*)Vt4;
    const int bx = blockIdx.x - 512;    // 128 blocks
    const int b = bx >> 4, h = (bx >> 2) & 3, ch = bx & 3;
    const float* kp = kb + ((size_t)b * 256 + h * 64) * 1024 + ch * 256;
    const float* vp = vb + ((size_t)b * 256 + h * 64) * 1024 + ch * 256;
    const int d = t >> 2, v0 = (t & 3) * 16;
    float4 acc[4];
#pragma unroll
    for (int j = 0; j < 4; ++j) acc[j] = make_float4(0.f, 0.f, 0.f, 0.f);
    float ks = 0.f;
    for (int st = 0; st < 4; ++st) {
        __syncthreads();
        {
            int dd = t >> 2, r0 = (t & 3) * 16;
#pragma unroll
            for (int mm = 0; mm < 4; ++mm) {
                float4 kv = *(const float4*)(kp + dd * 1024 + st * 64 + r0 + mm * 4);
                Kt[(r0 + mm * 4 + 0) * 68 + dd] = elu1(kv.x);
                Kt[(r0 + mm * 4 + 1) * 68 + dd] = elu1(kv.y);
                Kt[(r0 + mm * 4 + 2) * 68 + dd] = elu1(kv.z);
                Kt[(r0 + mm * 4 + 3) * 68 + dd] = elu1(kv.w);
                float4 vv = *(const float4*)(vp + dd * 1024 + st * 64 + r0 + mm * 4);
                Vt[(r0 + mm * 4 + 0) * 64 + dd] = vv.x;
                Vt[(r0 + mm * 4 + 1) * 64 + dd] = vv.y;
                Vt[(r0 + mm * 4 + 2) * 64 + dd] = vv.z;
                Vt[(r0 + mm * 4 + 3) * 64 + dd] = vv.w;
            }
        }
        __syncthreads();
#pragma unroll 8
        for (int s = 0; s < 64; ++s) {
            float kf = Kt[s * 68 + d];
            const float4* vvp = (const float4*)(Vt + s * 64 + v0);
#pragma unroll
            for (int j = 0; j < 4; ++j) {
                float4 vv = vvp[j];
                acc[j].x += kf * vv.x; acc[j].y += kf * vv.y;
                acc[j].z += kf * vv.z; acc[j].w += kf * vv.w;
            }
        }
        if (t < 64) {
#pragma unroll 8
            for (int s = 0; s < 64; ++s) ks += Kt[s * 68 + t];
        }
    }
    float* op = KVp + ((size_t)((ch * 32 + b * 4 + h) * 64 + d)) * 64 + v0;
#pragma unroll
    for (int j = 0; j < 4; ++j) ((float4*)op)[j] = acc[j];
    if (t < 64) Ksump[(size_t)(ch * 32 + b * 4 + h) * 64 + t] = ks;
}

// ===========================================================================
// qk_sm (validated R12/R13; nontemporal vis stores via ext_vector f32x4)
// || msg (validated R13).
// ===========================================================================
__global__ __launch_bounds__(512) void qk_sm_msg_kernel(
    const u16* __restrict__ qbt, const u16* __restrict__ kbt,
    float* __restrict__ vis,
    const float* __restrict__ KVp, const float* __restrict__ Ksump,
    float* __restrict__ msg)
{
    __shared__ float4 smem4[4178];      // 66,848 B union
    const int t = threadIdx.x;
    if (blockIdx.x < 1024) {
        u16* kf = (u16*)smem4;
        u16* qf = (u16*)smem4 + 32 * 512;
        float* redM = (float*)((char*)smem4 + 36864);
        float* redS = redM + 256;
        const int bx = blockIdx.x;
        const int b = bx >> 7, h = (bx >> 5) & 3, l0 = (bx & 31) * 32;
        const u16* qtp = qbt + ((size_t)(b * 4 + h)) * 1024 * 64;
        const u16* ktp = kbt + ((size_t)(b * 4 + h)) * 1024 * 64;

        if (t < 256) {
            int r = t & 31, dblk = t >> 5;
            int4 pk = *(const int4*)&qtp[(size_t)(l0 + r) * 64 + dblk * 8];
            *(int4*)&qf[(((r >> 4) * 2 + (dblk >> 2)) * 64 + (dblk & 3) * 16 + (r & 15)) * 8] = pk;
        }
        __syncthreads();

        const int w = t >> 6, l = t & 63, ln = l & 15, lg = l >> 4;
        bf16x8 a[2][2];
#pragma unroll
        for (int fr = 0; fr < 2; ++fr)
#pragma unroll
            for (int ks = 0; ks < 2; ++ks)
                a[fr][ks] = *(const bf16x8*)&qf[((fr * 2 + ks) * 64 + l) * 8];

        f32x4 acc[2][4][2];
#pragma unroll
        for (int fr = 0; fr < 2; ++fr)
#pragma unroll
            for (int cc = 0; cc < 4; ++cc)
#pragma unroll
                for (int f = 0; f < 2; ++f) acc[fr][cc][f] = (f32x4){0.f, 0.f, 0.f, 0.f};

#pragma unroll
        for (int cc = 0; cc < 4; ++cc) {
            __syncthreads();
#pragma unroll
            for (int it = 0; it < 4; ++it) {
                int unit = it * 512 + t;
                int sl = unit & 255, dblk = unit >> 8;
                int4 pk = *(const int4*)&ktp[(size_t)(cc * 256 + sl) * 64 + dblk * 8];
                *(int4*)&kf[(((sl >> 4) * 2 + (dblk >> 2)) * 64 + (dblk & 3) * 16 + (sl & 15)) * 8] = pk;
            }
            __syncthreads();
#pragma unroll
            for (int f = 0; f < 2; ++f) {
                int fg = (w * 2 + f) * 2;
                bf16x8 b0 = *(const bf16x8*)&kf[((fg + 0) * 64 + l) * 8];
                bf16x8 b1 = *(const bf16x8*)&kf[((fg + 1) * 64 + l) * 8];
#pragma unroll
                for (int fr = 0; fr < 2; ++fr) {
                    acc[fr][cc][f] = __builtin_amdgcn_mfma_f32_16x16x32_bf16(a[fr][0], b0, acc[fr][cc][f], 0, 0, 0);
                    acc[fr][cc][f] = __builtin_amdgcn_mfma_f32_16x16x32_bf16(a[fr][1], b1, acc[fr][cc][f], 0, 0, 0);
                }
            }
        }

#pragma unroll
        for (int fr = 0; fr < 2; ++fr)
#pragma unroll
            for (int cc = 0; cc < 4; ++cc)
#pragma unroll
                for (int f = 0; f < 2; ++f)
#pragma unroll
                    for (int e = 0; e < 4; ++e) acc[fr][cc][f][e] *= 0.125f;

        float rmax[2][4];
#pragma unroll
        for (int fr = 0; fr < 2; ++fr)
#pragma unroll
            for (int reg = 0; reg < 4; ++reg) {
                float m = -1e30f;
#pragma unroll
                for (int cc = 0; cc < 4; ++cc)
#pragma unroll
                    for (int f = 0; f < 2; ++f) m = fmaxf(m, acc[fr][cc][f][reg]);
#pragma unroll
                for (int off = 1; off < 16; off <<= 1) m = fmaxf(m, __shfl_xor(m, off));
                if (ln == 0) redM[(fr * 16 + lg * 4 + reg) * 8 + w] = m;
                rmax[fr][reg] = m;
            }
        __syncthreads();
#pragma unroll
        for (int fr = 0; fr < 2; ++fr)
#pragma unroll
            for (int reg = 0; reg < 4; ++reg) {
                int r = fr * 16 + lg * 4 + reg;
                float m = redM[r * 8];
#pragma unroll
                for (int ww = 1; ww < 8; ++ww) m = fmaxf(m, redM[r * 8 + ww]);
                rmax[fr][reg] = m;
            }
#pragma unroll
        for (int fr = 0; fr < 2; ++fr)
#pragma unroll
            for (int reg = 0; reg < 4; ++reg) {
                float s = 0.f;
                float m = rmax[fr][reg];
#pragma unroll
                for (int cc = 0; cc < 4; ++cc)
#pragma unroll
                    for (int f = 0; f < 2; ++f) {
                        float e = __expf(acc[fr][cc][f][reg] - m);
                        acc[fr][cc][f][reg] = e;
                        s += e;
                    }
#pragma unroll
                for (int off = 1; off < 16; off <<= 1) s += __shfl_xor(s, off);
                if (ln == 0) redS[(fr * 16 + lg * 4 + reg) * 8 + w] = s;
            }
        __syncthreads();
        float invv[2][4];
#pragma unroll
        for (int fr = 0; fr < 2; ++fr)
#pragma unroll
            for (int reg = 0; reg < 4; ++reg) {
                int r = fr * 16 + lg * 4 + reg;
                float s = redS[r * 8] + redS[r * 8 + 1] + redS[r * 8 + 2] + redS[r * 8 + 3]
                        + redS[r * 8 + 4] + redS[r * 8 + 5] + redS[r * 8 + 6] + redS[r * 8 + 7];
                invv[fr][reg] = 1.f / s;
            }
        float* outT = (float*)smem4;    // [32][260] f32
        float* visp = vis + (((size_t)(b * 4 + h)) << 20);
#pragma unroll
        for (int cc = 0; cc < 4; ++cc) {
            __syncthreads();
#pragma unroll
            for (int fr = 0; fr < 2; ++fr)
#pragma unroll
                for (int reg = 0; reg < 4; ++reg) {
                    int r = fr * 16 + lg * 4 + reg;
#pragma unroll
                    for (int f = 0; f < 2; ++f)
                        outT[r * 260 + w * 32 + f * 16 + ln] = acc[fr][cc][f][reg] * invv[fr][reg];
                }
            __syncthreads();
#pragma unroll
            for (int u = 0; u < 4; ++u) {
                int unit = u * 512 + t;
                int r = unit >> 6, c4 = unit & 63;
                f32x4 v = *(const f32x4*)&outT[r * 260 + c4 * 4];
                __builtin_nontemporal_store(v,
                    (f32x4*)&visp[(size_t)(l0 + r) * 1024 + cc * 256 + c4 * 4]);
            }
        }
        return;
    }
    // ---- msg path (64 blocks, 512 threads) ----
    float* kvl = (float*)smem4;             // [4][4112]
    float* ksl = (float*)smem4 + 4 * 4112;  // [4][65]
    const int bx2 = blockIdx.x - 1024;
    const int b = bx2 >> 3, l0 = (bx2 & 7) * 128;
#pragma unroll
    for (int m = 0; m < 8; ++m) {
        int unit = t + (m << 9);            // 4096 float4 units
        int hh = unit >> 10, dd = (unit >> 4) & 63, v4 = unit & 15;
        float4 s = make_float4(0.f, 0.f, 0.f, 0.f);
#pragma unroll
        for (int ch = 0; ch < 4; ++ch) {
            float4 u = *(const float4*)&KVp[((size_t)(ch * 32 + b * 4)) * 4096 + (size_t)unit * 4];
            s.x += u.x; s.y += u.y; s.z += u.z; s.w += u.w;
        }
        *(float4*)&kvl[hh * 4112 + dd * 64 + v4 * 4] = s;
    }
    if (t < 256) {
        float s = 0.f;
#pragma unroll
        for (int ch = 0; ch < 4; ++ch)
            s += Ksump[(size_t)(ch * 32 + b * 4) * 64 + t];
        ksl[(t >> 6) * 65 + (t & 63)] = s;
    }
    __syncthreads();
    const int h = t & 3, l = l0 + (t >> 2);
    const u16* qrow = qbt + ((size_t)(b * 4 + h) * 1024 + l) * 64;
    float qf[64];
#pragma unroll
    for (int j8 = 0; j8 < 8; ++j8) {
        int4 pk = *(const int4*)&qrow[j8 * 8];
        const u16* pku = (const u16*)&pk;
#pragma unroll
        for (int e = 0; e < 8; ++e) qf[j8 * 8 + e] = elu1(bf2f(pku[e]));
    }
    float zd = 1e-6f;
#pragma unroll
    for (int dd = 0; dd < 64; ++dd) zd += qf[dd] * ksl[h * 65 + dd];
    const float Z = 1.f / zd;
    float* op = msg + ((size_t)(b * 1024 + l)) * 256 + h * 64;
    for (int c0 = 0; c0 < 64; c0 += 16) {
        float4 a[4];
#pragma unroll
        for (int j = 0; j < 4; ++j) a[j] = make_float4(0.f, 0.f, 0.f, 0.f);
#pragma unroll
        for (int dd = 0; dd < 64; ++dd) {
            float qv = qf[dd];
            const float4* kp = (const float4*)(kvl + h * 4112 + dd * 64 + c0);
#pragma unroll
            for (int j = 0; j < 4; ++j) {
                float4 kk = kp[j];
                a[j].x += qv * kk.x; a[j].y += qv * kk.y;
                a[j].z += qv * kk.z; a[j].w += qv * kk.w;
            }
        }
#pragma unroll
        for (int j = 0; j < 4; ++j) {
            a[j].x *= Z; a[j].y *= Z; a[j].z *= Z; a[j].w *= Z;
            ((float4*)(op + c0))[j] = a[j];
        }
    }
}

// ===========================================================================
// Fused merge(Wm,LN1) + FF(W1,relu,W2,LN2) + residual (validated R12).
// ===========================================================================
__global__ __launch_bounds__(256) void ff_fused_kernel(
    const float* __restrict__ x, const float* __restrict__ msg,
    const u16* __restrict__ wmp,
    const u16* __restrict__ w1p, const u16* __restrict__ w2p,
    const float* __restrict__ g1, const float* __restrict__ b1,
    const float* __restrict__ g2, const float* __restrict__ b2,
    float* __restrict__ out)
{
    __shared__ u16 tile[16 * 520];
    __shared__ u16 mtile[16 * 264];
    __shared__ float redS[16 * 4];
    __shared__ float redQ[16 * 4];
    float* tf = (float*)tile;
    const int t = threadIdx.x;
    const int base = blockIdx.x * 16;   // 512 blocks
    const int b = base >> 10, l0 = base & 1023;
    const int w = t >> 6, l = t & 63, ln = l & 15, lg = l >> 4;

    {
        int rr = t & 15, cg = t >> 4;
        for (int cci = 0; cci < 16; ++cci) {
            int c = cci * 16 + cg;
            tile[rr * 520 + c] = f2bf(x[((size_t)b * 256 + c) * 1024 + l0 + rr]);
        }
        int r = t >> 4, cb = (t & 15) * 16;
#pragma unroll
        for (int i = 0; i < 4; ++i) {
            float4 v = *(const float4*)&msg[((size_t)(base + r)) * 256 + cb + i * 4];
            u32 p0 = (u32)f2bf(v.x) | ((u32)f2bf(v.y) << 16);
            u32 p1 = (u32)f2bf(v.z) | ((u32)f2bf(v.w) << 16);
            *(u32*)&mtile[r * 264 + cb + i * 4] = p0;
            *(u32*)&mtile[r * 264 + cb + i * 4 + 2] = p1;
        }
    }
    __syncthreads();

    f32x4 accm[4];
#pragma unroll
    for (int fc = 0; fc < 4; ++fc) accm[fc] = (f32x4){0.f, 0.f, 0.f, 0.f};
    for (int ks = 0; ks < 8; ++ks) {
        bf16x8 a0 = *(const bf16x8*)&mtile[ln * 264 + ks * 32 + lg * 8];
#pragma unroll
        for (int fc = 0; fc < 4; ++fc) {
            bf16x8 bb = *(const bf16x8*)&wmp[((size_t)(ks * 16 + w * 4 + fc) * 64 + l) * 8];
            accm[fc] = __builtin_amdgcn_mfma_f32_16x16x32_bf16(a0, bb, accm[fc], 0, 0, 0);
        }
    }
#pragma unroll
    for (int reg = 0; reg < 4; ++reg) {
        float s = 0.f, qsum = 0.f;
#pragma unroll
        for (int fc = 0; fc < 4; ++fc) {
            float v = accm[fc][reg];
            s += v; qsum += v * v;
        }
#pragma unroll
        for (int off = 1; off < 16; off <<= 1) {
            s += __shfl_xor(s, off);
            qsum += __shfl_xor(qsum, off);
        }
        if (ln == 0) {
            int r = lg * 4 + reg;
            redS[r * 4 + w] = s;
            redQ[r * 4 + w] = qsum;
        }
    }
    __syncthreads();
#pragma unroll
    for (int fc = 0; fc < 4; ++fc) {
        int c = w * 64 + fc * 16 + ln;
        float gg = g1[c], bb = b1[c];
#pragma unroll
        for (int reg = 0; reg < 4; ++reg) {
            int r = lg * 4 + reg;
            float s = redS[r * 4] + redS[r * 4 + 1] + redS[r * 4 + 2] + redS[r * 4 + 3];
            float qs = redQ[r * 4] + redQ[r * 4 + 1] + redQ[r * 4 + 2] + redQ[r * 4 + 3];
            float mean = s * (1.f / 256.f);
            float rstd = rsqrtf(qs * (1.f / 256.f) - mean * mean + 1e-5f);
            tile[r * 520 + 256 + c] = f2bf((accm[fc][reg] - mean) * rstd * gg + bb);
        }
    }
    __syncthreads();

    f32x4 acc1[8];
#pragma unroll
    for (int fc = 0; fc < 8; ++fc) acc1[fc] = (f32x4){0.f, 0.f, 0.f, 0.f};
    for (int ks = 0; ks < 16; ++ks) {
        bf16x8 a0 = *(const bf16x8*)&tile[ln * 520 + ks * 32 + lg * 8];
#pragma unroll
        for (int fc = 0; fc < 8; ++fc) {
            bf16x8 bb = *(const bf16x8*)&w1p[((size_t)(ks * 32 + w * 8 + fc) * 64 + l) * 8];
            acc1[fc] = __builtin_amdgcn_mfma_f32_16x16x32_bf16(a0, bb, acc1[fc], 0, 0, 0);
        }
    }
    __syncthreads();
#pragma unroll
    for (int fc = 0; fc < 8; ++fc)
#pragma unroll
        for (int reg = 0; reg < 4; ++reg) {
            int r = lg * 4 + reg;
            int c = w * 128 + fc * 16 + ln;
            tile[r * 520 + c] = f2bf(fmaxf(acc1[fc][reg], 0.f));
        }
    __syncthreads();

    f32x4 acc2[4];
#pragma unroll
    for (int fc = 0; fc < 4; ++fc) acc2[fc] = (f32x4){0.f, 0.f, 0.f, 0.f};
    for (int ks = 0; ks < 16; ++ks) {
        bf16x8 a0 = *(const bf16x8*)&tile[ln * 520 + ks * 32 + lg * 8];
#pragma unroll
        for (int fc = 0; fc < 4; ++fc) {
            bf16x8 bb = *(const bf16x8*)&w2p[((size_t)(ks * 16 + w * 4 + fc) * 64 + l) * 8];
            acc2[fc] = __builtin_amdgcn_mfma_f32_16x16x32_bf16(a0, bb, acc2[fc], 0, 0, 0);
        }
    }
#pragma unroll
    for (int reg = 0; reg < 4; ++reg) {
        float s = 0.f, qsum = 0.f;
#pragma unroll
        for (int fc = 0; fc < 4; ++fc) {
            float v = acc2[fc][reg];
            s += v; qsum += v * v;
        }
#pragma unroll
        for (int off = 1; off < 16; off <<= 1) {
            s += __shfl_xor(s, off);
            qsum += __shfl_xor(qsum, off);
        }
        if (ln == 0) {
            int r = lg * 4 + reg;
            redS[r * 4 + w] = s;
            redQ[r * 4 + w] = qsum;
        }
    }
    __syncthreads();
    float mean[4], rstd[4];
#pragma unroll
    for (int reg = 0; reg < 4; ++reg) {
        int r = lg * 4 + reg;
        float s = redS[r * 4] + redS[r * 4 + 1] + redS[r * 4 + 2] + redS[r * 4 + 3];
        float qs = redQ[r * 4] + redQ[r * 4 + 1] + redQ[r * 4 + 2] + redQ[r * 4 + 3];
        float m = s * (1.f / 256.f);
        mean[reg] = m;
        rstd[reg] = rsqrtf(qs * (1.f / 256.f) - m * m + 1e-5f);
    }
    __syncthreads();
#pragma unroll
    for (int fc = 0; fc < 4; ++fc) {
        int c = w * 64 + fc * 16 + ln;
        float gg = g2[c], bb = b2[c];
#pragma unroll
        for (int reg = 0; reg < 4; ++reg) {
            int r = lg * 4 + reg;
            tf[r * 260 + c] = (acc2[fc][reg] - mean[reg]) * rstd[reg] * gg + bb;
        }
    }
    __syncthreads();
    {
        const float* xp = x + ((size_t)b * 256 + t) * 1024 + l0;
        float* op = out + ((size_t)b * 256 + t) * 1024 + l0;
#pragma unroll
        for (int i = 0; i < 4; ++i) {
            float4 xv = *(const float4*)(xp + i * 4);
            float4 o;
            o.x = xv.x + tf[(i * 4 + 0) * 260 + t];
            o.y = xv.y + tf[(i * 4 + 1) * 260 + t];
            o.z = xv.z + tf[(i * 4 + 2) * 260 + t];
            o.w = xv.w + tf[(i * 4 + 3) * 260 + t];
            *(float4*)(op + i * 4) = o;
        }
    }
}

// ---------------------------------------------------------------------------
extern "C" void kernel_launch(void* const* d_in, const int* in_sizes, int n_in,
                              void* d_out, int out_size, void* d_ws, size_t ws_size,
                              hipStream_t stream)
{
    const float* x    = (const float*)d_in[0];
    const float* src  = (const float*)d_in[1];
    const float* Wq   = (const float*)d_in[2];
    const float* Wk1  = (const float*)d_in[3];
    const float* Wk3  = (const float*)d_in[4];
    const float* Wk5  = (const float*)d_in[5];
    const float* Wk7  = (const float*)d_in[6];
    const float* Wv1  = (const float*)d_in[7];
    const float* Wv3  = (const float*)d_in[8];
    const float* Wv5  = (const float*)d_in[9];
    const float* Wv7  = (const float*)d_in[10];
    const float* Wm   = (const float*)d_in[11];
    const float* g1   = (const float*)d_in[12];
    const float* b1   = (const float*)d_in[13];
    const float* g2   = (const float*)d_in[14];
    const float* b2   = (const float*)d_in[15];
    const float* W1   = (const float*)d_in[16];
    const float* W2   = (const float*)d_in[17];

    float* out = (float*)d_out;
    float* vis = out + 2097152;          // [b,h,l,s]

    // Conv partials in vis region (dead until qk_sm overwrites all of it).
    float* p5 = vis;                     // [2][4][8][64][1024]
    float* p7 = vis + 4194304;           // [2][8][8][64][1024]

    // ws extent+lifetime map (float offsets; audited R14):
    //  qbt   [0,        1048576)  conv..qk_sm_msg (bf16, written by conv)
    //  kb    [2097152,  4194304)  conv..prep3
    //  vb    [4194304,  6291456)  conv..prep3
    //  wpack [6291456,  7962624)  prep1..conv
    //    then w1p [6291456, 6422528) prep2..ff_fused
    //         w2p [6422528, 6488064) prep2..ff_fused
    //         wmp [6488064, 6520832) prep2..ff_fused
    //         kbt [7569408, 8617984) prep3..qk_sm_msg (overlaps dead xbh only)
    //  xbh   [7962624,  9011200)  prep1..conv
    //  sbh   [9011200, 10059776)  prep1..conv
    //  msg   [10059776, 12156928) qk_sm_msg..ff_fused
    //  KVp   [12156928, 12681216), Ksump [12681216, 12689408) prep3..qk_sm_msg
    float* ws    = (float*)d_ws;
    u16*   qbt   = (u16*)ws;
    float* kb    = ws + 2097152;
    float* vb    = ws + 4194304;
    u16*   wpack = (u16*)(ws + 6291456);
    u16*   w1p   = (u16*)(ws + 6291456);
    u16*   w2p   = (u16*)(ws + 6422528);
    u16*   wmp   = (u16*)(ws + 6488064);
    u16*   kbt   = (u16*)(ws + 7569408);
    u16*   xbh   = (u16*)(ws + 7962624);
    u16*   sbh   = (u16*)(ws + 9011200);
    float* msg   = ws + 10059776;
    float* KVp   = ws + 12156928;
    float* Ksump = ws + 12681216;

    prep1_kernel    <<<2656, 256, 0, stream>>>(Wq, Wk1, Wk3, Wk5, Wk7,
                                               Wv1, Wv3, Wv5, Wv7, wpack,
                                               x, src, xbh, sbh);
    conv_mfma_kernel<<<512,  512, 0, stream>>>(xbh, sbh, wpack, qbt, kb, vb, p5, p7);
    prep2_kernel    <<<2272, 256, 0, stream>>>(p5, p7, kb, vb,
                                               W1, W2, Wm, w1p, w2p, wmp);
    prep3_kernel    <<<640,  256, 0, stream>>>(kb, vb, kbt, KVp, Ksump);
    qk_sm_msg_kernel<<<1088, 512, 0, stream>>>(qbt, kbt, vis, KVp, Ksump, msg);
    ff_fused_kernel <<<512,  256, 0, stream>>>(x, msg, wmp, w1p, w2p,
                                               g1, b1, g2, b2, out);
}

// Round 16
// 260.670 us; speedup vs baseline: 1.2514x; 1.0266x over previous
//
#include <hip/hip_runtime.h>

#define DEV __device__ __forceinline__

typedef unsigned short u16;
typedef unsigned int u32;
typedef __bf16 bf16x8 __attribute__((ext_vector_type(8)));
typedef float f32x4 __attribute__((ext_vector_type(4)));

DEV float elu1(float x) { return x > 0.f ? x + 1.f : __expf(x); }

DEV u16 f2bf(float f) {
    union { float f; unsigned u; } v; v.f = f;
    unsigned r = v.u + 0x7fffu + ((v.u >> 16) & 1u);
    return (u16)(r >> 16);
}

DEV float bf2f(u16 h) {
    union { u32 u; float f; } v; v.u = ((u32)h) << 16; return v.f;
}

// ===========================================================================
// prep1 = conv-weight repack (validated R2)  ||  cast_src (validated R5).
// ===========================================================================
__global__ __launch_bounds__(256) void prep1_kernel(
    const float* __restrict__ Wq,
    const float* __restrict__ Wk1, const float* __restrict__ Wk3,
    const float* __restrict__ Wk5, const float* __restrict__ Wk7,
    const float* __restrict__ Wv1, const float* __restrict__ Wv3,
    const float* __restrict__ Wv5, const float* __restrict__ Wv7,
    u16* __restrict__ wpack,
    const float* __restrict__ x, const float* __restrict__ src,
    u16* __restrict__ xbh, u16* __restrict__ sbh)
{
    __shared__ float lds[32 * 129];
    const int t = threadIdx.x;
    if (blockIdx.x < 1632) {
        int gid = blockIdx.x * 256 + t;
        int frag = gid >> 6, l = gid & 63;
        const float* W; int K, ocbase = 0, rel;
        if (frag < 1152) {
            W = Wq; K = 3; int slot = frag / 288; rel = frag % 288; ocbase = slot * 64;
        } else {
            int f = frag - 1152; int side = f / 2688; f %= 2688;
            if (f < 32)        { W = side ? Wv1 : Wk1; K = 1; rel = f; }
            else if (f < 320)  { W = side ? Wv3 : Wk3; K = 3; rel = f - 32; }
            else if (f < 1120) { W = side ? Wv5 : Wk5; K = 5; rel = f - 320; }
            else               { W = side ? Wv7 : Wk7; K = 7; rel = f - 1120; }
        }
        int og = rel & 3, cc = (rel >> 2) & 7, tap = rel >> 5;
        int dy = tap / K, dx = tap % K;
        int oc = ocbase + og * 16 + (l & 15);
        int c0 = cc * 32 + (l >> 4) * 8;
        u16 pk[8];
#pragma unroll
        for (int j = 0; j < 8; ++j)
            pk[j] = f2bf(W[((size_t)(oc * 256 + c0 + j) * K + dy) * K + dx]);
        *(int4*)&wpack[(size_t)frag * 512 + l * 8] = *(const int4*)pk;
        return;
    }
    const int i = blockIdx.x - 1632;    // 1024 cast_src blocks
    const int inp = i >> 9, rem = i & 511;
    const int b = rem >> 6, cc = (rem >> 3) & 7, pxb = rem & 7;
    const float* in = (inp ? src : x) + ((size_t)b * 256 + cc * 32) * 1024 + pxb * 128;
    u16* outp = (inp ? sbh : xbh) + (size_t)b * 262144 + (size_t)cc * 32768 + pxb * 128 * 32;
#pragma unroll
    for (int u = 0; u < 4; ++u) {
        int unit = t + u * 256;
        int r = unit >> 5, px4 = unit & 31;
        float4 v = *(const float4*)(in + (size_t)r * 1024 + px4 * 4);
        lds[r * 129 + px4 * 4 + 0] = v.x;
        lds[r * 129 + px4 * 4 + 1] = v.y;
        lds[r * 129 + px4 * 4 + 2] = v.z;
        lds[r * 129 + px4 * 4 + 3] = v.w;
    }
    __syncthreads();
#pragma unroll
    for (int u = 0; u < 2; ++u) {
        int unit = t + u * 256;
        int px = unit >> 2, cg = unit & 3;
        u16 pk[8];
#pragma unroll
        for (int j = 0; j < 8; ++j) pk[j] = f2bf(lds[(cg * 8 + j) * 129 + px]);
        *(int4*)&outp[px * 32 + cg * 8] = *(const int4*)pk;
    }
}

// ===========================================================================
// MFMA implicit-GEMM conv (R9 body MFMA math, validated). R16: ALL outputs
// via the transposed bf16 epilogue [px][64] (validated R15 for q) — q/k1/k3
// heads direct, K5/K7 c-split partials as bf16.
// ===========================================================================
template<int K>
DEV void conv_mfma_body(const u16* __restrict__ srcb,
                        const u16* __restrict__ wsec,
                        u16* __restrict__ dst,
                        u16* Bt, int y0, int cch0, int ncc, int t)
{
    constexpr int P = K / 2;
    const int w = t >> 6, l = t & 63;
    const int chi = l >> 4, ln = l & 15;
    const int rowbase = chi * 22 + w * 2 + 3 - P;
    const int colbase = ln + 3 - P;
    f32x4 acc[4][4];
#pragma unroll
    for (int m = 0; m < 4; ++m)
#pragma unroll
        for (int n = 0; n < 4; ++n) acc[m][n] = (f32x4){0.f, 0.f, 0.f, 0.f};

    for (int cc = 0; cc < ncc; ++cc) {
        const int ccg = cch0 + cc;
        __syncthreads();
#pragma unroll
        for (int u = 0; u < 7; ++u) {
            int unit = t + (u << 9);
            if (unit < 2816) {
                int xv = unit & 31, r = unit >> 5;
                int yy = r % 22, ch = r / 22;
                int ygl = y0 - 3 + yy;
                int4 pk;
                if ((unsigned)ygl < 32u)
                    pk = *(const int4*)&srcb[(size_t)ccg * 32768 + (ygl * 32 + xv) * 32 + ch * 8];
                else
                    pk = (int4){0, 0, 0, 0};
                *(int4*)&Bt[((ch * 22 + yy) * 40 + xv + 3) * 8] = pk;
            } else if (unit < 3520) {
                int hu = unit - 2816;
                int hx = hu & 7; int xi = hx < 3 ? hx : hx + 32;
                int r = hu >> 3; int yy = r % 22, ch = r / 22;
                int4 z = {0, 0, 0, 0};
                *(int4*)&Bt[((ch * 22 + yy) * 40 + xi) * 8] = z;
            }
        }
        __syncthreads();
#pragma unroll
        for (int dy = 0; dy < K; ++dy) {
#pragma unroll
            for (int dx = 0; dx < K; ++dx) {
                const int tap = dy * K + dx;
                const u16* wp = wsec + ((size_t)(tap * 8 + ccg) * 4) * 512 + l * 8;
                bf16x8 a0 = *(const bf16x8*)(wp);
                bf16x8 a1 = *(const bf16x8*)(wp + 512);
                bf16x8 a2 = *(const bf16x8*)(wp + 1024);
                bf16x8 a3 = *(const bf16x8*)(wp + 1536);
                bf16x8 bf[4];
#pragma unroll
                for (int n = 0; n < 4; ++n) {
                    int row = rowbase + dy + (n >> 1);
                    int col = colbase + dx + (n & 1) * 16;
                    bf[n] = *(const bf16x8*)&Bt[(row * 40 + col) * 8];
                }
#pragma unroll
                for (int n = 0; n < 4; ++n) {
                    acc[0][n] = __builtin_amdgcn_mfma_f32_16x16x32_bf16(a0, bf[n], acc[0][n], 0, 0, 0);
                    acc[1][n] = __builtin_amdgcn_mfma_f32_16x16x32_bf16(a1, bf[n], acc[1][n], 0, 0, 0);
                    acc[2][n] = __builtin_amdgcn_mfma_f32_16x16x32_bf16(a2, bf[n], acc[2][n], 0, 0, 0);
                    acc[3][n] = __builtin_amdgcn_mfma_f32_16x16x32_bf16(a3, bf[n], acc[3][n], 0, 0, 0);
                }
            }
        }
    }
#pragma unroll
    for (int m = 0; m < 4; ++m)
#pragma unroll
        for (int n = 0; n < 4; ++n) {
            int y = y0 + w * 2 + (n >> 1);
            int px = y * 32 + (n & 1) * 16 + ln;
            int ocb = m * 16 + chi * 4;
            u16 pk[4];
#pragma unroll
            for (int r = 0; r < 4; ++r) pk[r] = f2bf(acc[m][n][r]);
            *(uint2*)&dst[(size_t)px * 64 + ocb] = *(const uint2*)pk;
        }
}

// Job decode (R9 XCD grouping): bx = m*256 + b*32 + g, grid 512. XCD = g%8.
// All outputs bf16 [slot][px][64]: q slots = qbt[b*4+g]; k1/k3 = kbt heads
// 0/1; v1/v3 = vbt heads 0/1; K5/K7 partials into p5u/p7u.
__global__ __launch_bounds__(512) void conv_mfma_kernel(
    const u16* __restrict__ xbh, const u16* __restrict__ sbh,
    const u16* __restrict__ wpack,
    u16* __restrict__ qbt, u16* __restrict__ kbt, u16* __restrict__ vbt,
    u16* __restrict__ p5u, u16* __restrict__ p7u)
{
    __shared__ u16 Bt[4 * 22 * 40 * 8];
    const int bx = blockIdx.x, t = threadIdx.x;
    const int g = bx & 31, b = (bx >> 5) & 7, m = bx >> 8;
    if (g < 4) {
        conv_mfma_body<3>(xbh + (size_t)b * 262144,
                          wpack + (size_t)(g * 288) * 512,
                          qbt + ((size_t)(b * 4 + g)) * 65536,
                          Bt, m * 16, 0, 8, t);
        return;
    }
    const int gs = g - 4;
    const int side = gs / 14, gg = gs % 14;
    const u16* sp = sbh + (size_t)b * 262144;
    u16* fin = side ? vbt : kbt;
    const size_t wkb = 1152 + (size_t)side * 2688;
    if (gg == 0) {
        conv_mfma_body<1>(sp, wpack + (wkb + 0) * 512,
                          fin + ((size_t)(b * 4 + 0)) * 65536, Bt, m * 16, 0, 8, t);
    } else if (gg == 1) {
        conv_mfma_body<3>(sp, wpack + (wkb + 32) * 512,
                          fin + ((size_t)(b * 4 + 1)) * 65536, Bt, m * 16, 0, 8, t);
    } else if (gg < 6) {
        int cpart = gg - 2;
        conv_mfma_body<5>(sp, wpack + (wkb + 320) * 512,
                          p5u + (((size_t)side * 4 + cpart) * 8 + b) * 65536,
                          Bt, m * 16, cpart * 2, 2, t);
    } else {
        int cpart = gg - 6;
        conv_mfma_body<7>(sp, wpack + (wkb + 1120) * 512,
                          p7u + (((size_t)side * 8 + cpart) * 8 + b) * 65536,
                          Bt, m * 16, cpart, 1, t);
    }
}

// ===========================================================================
// prep2 = bf16-partial reduce -> kbt/vbt heads 2,3  ||  FF/Wm repack.
// reduce: 1024 blocks x 256 thr = 262144 uint4 units (8 bf16 each).
// gid = ((side*2 + headk)*8 + b)*8192 + u8.
// ===========================================================================
__global__ __launch_bounds__(256) void prep2_kernel(
    const u16* __restrict__ p5u, const u16* __restrict__ p7u,
    u16* __restrict__ kbt, u16* __restrict__ vbt,
    const float* __restrict__ W1, const float* __restrict__ W2,
    const float* __restrict__ Wm,
    u16* __restrict__ w1p, u16* __restrict__ w2p, u16* __restrict__ wmp)
{
    const int t = threadIdx.x;
    if (blockIdx.x < 1024) {
        int gid = blockIdx.x * 256 + t;
        int u8 = gid & 8191;
        int b = (gid >> 13) & 7;
        int headk = (gid >> 16) & 1;
        int side = gid >> 17;
        float sacc[8];
#pragma unroll
        for (int e = 0; e < 8; ++e) sacc[e] = 0.f;
        if (headk == 0) {
#pragma unroll
            for (int p = 0; p < 4; ++p) {
                int4 u = *(const int4*)&p5u[(((size_t)side * 4 + p) * 8 + b) * 65536 + (size_t)u8 * 8];
                const u16* uu = (const u16*)&u;
#pragma unroll
                for (int e = 0; e < 8; ++e) sacc[e] += bf2f(uu[e]);
            }
        } else {
#pragma unroll
            for (int p = 0; p < 8; ++p) {
                int4 u = *(const int4*)&p7u[(((size_t)side * 8 + p) * 8 + b) * 65536 + (size_t)u8 * 8];
                const u16* uu = (const u16*)&u;
#pragma unroll
                for (int e = 0; e < 8; ++e) sacc[e] += bf2f(uu[e]);
            }
        }
        u16 pk[8];
#pragma unroll
        for (int e = 0; e < 8; ++e) pk[e] = f2bf(sacc[e]);
        u16* outb = side ? vbt : kbt;
        *(int4*)&outb[((size_t)(b * 4 + 2 + headk)) * 65536 + (size_t)u8 * 8] = *(const int4*)pk;
        return;
    }
    int gid = (blockIdx.x - 1024) * 256 + t;    // 224 blocks, 896 frags
    int f = gid >> 6, l = gid & 63;
    if (f >= 896) return;
    u16 pk[8];
    if (f < 512) {
        int ks = f >> 5, nf = f & 31;
#pragma unroll
        for (int j = 0; j < 8; ++j)
            pk[j] = f2bf(W1[(size_t)(ks * 32 + (l >> 4) * 8 + j) * 512 + nf * 16 + (l & 15)]);
        *(int4*)&w1p[(size_t)f * 512 + l * 8] = *(const int4*)pk;
    } else if (f < 768) {
        int f2 = f - 512;
        int ks = f2 >> 4, nf = f2 & 15;
#pragma unroll
        for (int j = 0; j < 8; ++j)
            pk[j] = f2bf(W2[(size_t)(ks * 32 + (l >> 4) * 8 + j) * 256 + nf * 16 + (l & 15)]);
        *(int4*)&w2p[(size_t)f2 * 512 + l * 8] = *(const int4*)pk;
    } else {
        int f3 = f - 768;
        int ks = f3 >> 4, nf = f3 & 15;
#pragma unroll
        for (int j = 0; j < 8; ++j)
            pk[j] = f2bf(Wm[(size_t)(ks * 32 + (l >> 4) * 8 + j) * 256 + nf * 16 + (l & 15)]);
        *(int4*)&wmp[(size_t)f3 * 512 + l * 8] = *(const int4*)pk;
    }
}

// ===========================================================================
// prep3 = linear-attention KV/Ksum (kv math validated R2; staging now from
// bf16 row-major kbt/vbt — fully coalesced). 128 blocks.
// ===========================================================================
__global__ __launch_bounds__(256) void prep3_kernel(
    const u16* __restrict__ kbt, const u16* __restrict__ vbt,
    float* __restrict__ KVp, float* __restrict__ Ksump)
{
    __shared__ float4 smem4[2112];
    float* Kt = (float*)smem4;              // [64][68]
    float* Vt = (float*)(smem4 + 64 * 17);  // [64][64]
    const int t = threadIdx.x;
    const int bx = blockIdx.x;              // 128
    const int b = bx >> 4, h = (bx >> 2) & 3, ch = bx & 3;
    const u16* kbase = kbt + ((size_t)(b * 4 + h) * 1024 + ch * 256) * 64;
    const u16* vbase = vbt + ((size_t)(b * 4 + h) * 1024 + ch * 256) * 64;
    const int d = t >> 2, v0 = (t & 3) * 16;
    float4 acc[4];
#pragma unroll
    for (int j = 0; j < 4; ++j) acc[j] = make_float4(0.f, 0.f, 0.f, 0.f);
    float ks = 0.f;
    for (int st = 0; st < 4; ++st) {
        __syncthreads();
        {
            int s = t >> 2, d0 = (t & 3) * 16;
            const u16* krow = kbase + (size_t)(st * 64 + s) * 64;
            const u16* vrow = vbase + (size_t)(st * 64 + s) * 64;
#pragma unroll
            for (int oo = 0; oo < 2; ++oo) {
                int4 k8 = *(const int4*)&krow[d0 + oo * 8];
                int4 v8 = *(const int4*)&vrow[d0 + oo * 8];
                const u16* ku = (const u16*)&k8;
                const u16* vu = (const u16*)&v8;
#pragma unroll
                for (int e = 0; e < 8; ++e) {
                    Kt[s * 68 + d0 + oo * 8 + e] = elu1(bf2f(ku[e]));
                    Vt[s * 64 + d0 + oo * 8 + e] = bf2f(vu[e]);
                }
            }
        }
        __syncthreads();
#pragma unroll 8
        for (int s = 0; s < 64; ++s) {
            float kf = Kt[s * 68 + d];
            const float4* vvp = (const float4*)(Vt + s * 64 + v0);
#pragma unroll
            for (int j = 0; j < 4; ++j) {
                float4 vv = vvp[j];
                acc[j].x += kf * vv.x; acc[j].y += kf * vv.y;
                acc[j].z += kf * vv.z; acc[j].w += kf * vv.w;
            }
        }
        if (t < 64) {
#pragma unroll 8
            for (int s = 0; s < 64; ++s) ks += Kt[s * 68 + t];
        }
    }
    float* op = KVp + ((size_t)((ch * 32 + b * 4 + h) * 64 + d)) * 64 + v0;
#pragma unroll
    for (int j = 0; j < 4; ++j) ((float4*)op)[j] = acc[j];
    if (t < 64) Ksump[(size_t)(ch * 32 + b * 4 + h) * 64 + t] = ks;
}

// ===========================================================================
// qk_sm (validated R12/R15; nontemporal vis stores) || msg (validated R13).
// ===========================================================================
__global__ __launch_bounds__(512) void qk_sm_msg_kernel(
    const u16* __restrict__ qbt, const u16* __restrict__ kbt,
    float* __restrict__ vis,
    const float* __restrict__ KVp, const float* __restrict__ Ksump,
    float* __restrict__ msg)
{
    __shared__ float4 smem4[4178];      // 66,848 B union
    const int t = threadIdx.x;
    if (blockIdx.x < 1024) {
        u16* kf = (u16*)smem4;
        u16* qf = (u16*)smem4 + 32 * 512;
        float* redM = (float*)((char*)smem4 + 36864);
        float* redS = redM + 256;
        const int bx = blockIdx.x;
        const int b = bx >> 7, h = (bx >> 5) & 3, l0 = (bx & 31) * 32;
        const u16* qtp = qbt + ((size_t)(b * 4 + h)) * 1024 * 64;
        const u16* ktp = kbt + ((size_t)(b * 4 + h)) * 1024 * 64;

        if (t < 256) {
            int r = t & 31, dblk = t >> 5;
            int4 pk = *(const int4*)&qtp[(size_t)(l0 + r) * 64 + dblk * 8];
            *(int4*)&qf[(((r >> 4) * 2 + (dblk >> 2)) * 64 + (dblk & 3) * 16 + (r & 15)) * 8] = pk;
        }
        __syncthreads();

        const int w = t >> 6, l = t & 63, ln = l & 15, lg = l >> 4;
        bf16x8 a[2][2];
#pragma unroll
        for (int fr = 0; fr < 2; ++fr)
#pragma unroll
            for (int ks = 0; ks < 2; ++ks)
                a[fr][ks] = *(const bf16x8*)&qf[((fr * 2 + ks) * 64 + l) * 8];

        f32x4 acc[2][4][2];
#pragma unroll
        for (int fr = 0; fr < 2; ++fr)
#pragma unroll
            for (int cc = 0; cc < 4; ++cc)
#pragma unroll
                for (int f = 0; f < 2; ++f) acc[fr][cc][f] = (f32x4){0.f, 0.f, 0.f, 0.f};

#pragma unroll
        for (int cc = 0; cc < 4; ++cc) {
            __syncthreads();
#pragma unroll
            for (int it = 0; it < 4; ++it) {
                int unit = it * 512 + t;
                int sl = unit & 255, dblk = unit >> 8;
                int4 pk = *(const int4*)&ktp[(size_t)(cc * 256 + sl) * 64 + dblk * 8];
                *(int4*)&kf[(((sl >> 4) * 2 + (dblk >> 2)) * 64 + (dblk & 3) * 16 + (sl & 15)) * 8] = pk;
            }
            __syncthreads();
#pragma unroll
            for (int f = 0; f < 2; ++f) {
                int fg = (w * 2 + f) * 2;
                bf16x8 b0 = *(const bf16x8*)&kf[((fg + 0) * 64 + l) * 8];
                bf16x8 b1 = *(const bf16x8*)&kf[((fg + 1) * 64 + l) * 8];
#pragma unroll
                for (int fr = 0; fr < 2; ++fr) {
                    acc[fr][cc][f] = __builtin_amdgcn_mfma_f32_16x16x32_bf16(a[fr][0], b0, acc[fr][cc][f], 0, 0, 0);
                    acc[fr][cc][f] = __builtin_amdgcn_mfma_f32_16x16x32_bf16(a[fr][1], b1, acc[fr][cc][f], 0, 0, 0);
                }
            }
        }

#pragma unroll
        for (int fr = 0; fr < 2; ++fr)
#pragma unroll
            for (int cc = 0; cc < 4; ++cc)
#pragma unroll
                for (int f = 0; f < 2; ++f)
#pragma unroll
                    for (int e = 0; e < 4; ++e) acc[fr][cc][f][e] *= 0.125f;

        float rmax[2][4];
#pragma unroll
        for (int fr = 0; fr < 2; ++fr)
#pragma unroll
            for (int reg = 0; reg < 4; ++reg) {
                float m = -1e30f;
#pragma unroll
                for (int cc = 0; cc < 4; ++cc)
#pragma unroll
                    for (int f = 0; f < 2; ++f) m = fmaxf(m, acc[fr][cc][f][reg]);
#pragma unroll
                for (int off = 1; off < 16; off <<= 1) m = fmaxf(m, __shfl_xor(m, off));
                if (ln == 0) redM[(fr * 16 + lg * 4 + reg) * 8 + w] = m;
                rmax[fr][reg] = m;
            }
        __syncthreads();
#pragma unroll
        for (int fr = 0; fr < 2; ++fr)
#pragma unroll
            for (int reg = 0; reg < 4; ++reg) {
                int r = fr * 16 + lg * 4 + reg;
                float m = redM[r * 8];
#pragma unroll
                for (int ww = 1; ww < 8; ++ww) m = fmaxf(m, redM[r * 8 + ww]);
                rmax[fr][reg] = m;
            }
#pragma unroll
        for (int fr = 0; fr < 2; ++fr)
#pragma unroll
            for (int reg = 0; reg < 4; ++reg) {
                float s = 0.f;
                float m = rmax[fr][reg];
#pragma unroll
                for (int cc = 0; cc < 4; ++cc)
#pragma unroll
                    for (int f = 0; f < 2; ++f) {
                        float e = __expf(acc[fr][cc][f][reg] - m);
                        acc[fr][cc][f][reg] = e;
                        s += e;
                    }
#pragma unroll
                for (int off = 1; off < 16; off <<= 1) s += __shfl_xor(s, off);
                if (ln == 0) redS[(fr * 16 + lg * 4 + reg) * 8 + w] = s;
            }
        __syncthreads();
        float invv[2][4];
#pragma unroll
        for (int fr = 0; fr < 2; ++fr)
#pragma unroll
            for (int reg = 0; reg < 4; ++reg) {
                int r = fr * 16 + lg * 4 + reg;
                float s = redS[r * 8] + redS[r * 8 + 1] + redS[r * 8 + 2] + redS[r * 8 + 3]
                        + redS[r * 8 + 4] + redS[r * 8 + 5] + redS[r * 8 + 6] + redS[r * 8 + 7];
                invv[fr][reg] = 1.f / s;
            }
        float* outT = (float*)smem4;    // [32][260] f32
        float* visp = vis + (((size_t)(b * 4 + h)) << 20);
#pragma unroll
        for (int cc = 0; cc < 4; ++cc) {
            __syncthreads();
#pragma unroll
            for (int fr = 0; fr < 2; ++fr)
#pragma unroll
                for (int reg = 0; reg < 4; ++reg) {
                    int r = fr * 16 + lg * 4 + reg;
#pragma unroll
                    for (int f = 0; f < 2; ++f)
                        outT[r * 260 + w * 32 + f * 16 + ln] = acc[fr][cc][f][reg] * invv[fr][reg];
                }
            __syncthreads();
#pragma unroll
            for (int u = 0; u < 4; ++u) {
                int unit = u * 512 + t;
                int r = unit >> 6, c4 = unit & 63;
                f32x4 v = *(const f32x4*)&outT[r * 260 + c4 * 4];
                __builtin_nontemporal_store(v,
                    (f32x4*)&visp[(size_t)(l0 + r) * 1024 + cc * 256 + c4 * 4]);
            }
        }
        return;
    }
    // ---- msg path (64 blocks, 512 threads) ----
    float* kvl = (float*)smem4;             // [4][4112]
    float* ksl = (float*)smem4 + 4 * 4112;  // [4][65]
    const int bx2 = blockIdx.x - 1024;
    const int b = bx2 >> 3, l0 = (bx2 & 7) * 128;
#pragma unroll
    for (int m = 0; m < 8; ++m) {
        int unit = t + (m << 9);            // 4096 float4 units
        int hh = unit >> 10, dd = (unit >> 4) & 63, v4 = unit & 15;
        float4 s = make_float4(0.f, 0.f, 0.f, 0.f);
#pragma unroll
        for (int ch = 0; ch < 4; ++ch) {
            float4 u = *(const float4*)&KVp[((size_t)(ch * 32 + b * 4)) * 4096 + (size_t)unit * 4];
            s.x += u.x; s.y += u.y; s.z += u.z; s.w += u.w;
        }
        *(float4*)&kvl[hh * 4112 + dd * 64 + v4 * 4] = s;
    }
    if (t < 256) {
        float s = 0.f;
#pragma unroll
        for (int ch = 0; ch < 4; ++ch)
            s += Ksump[(size_t)(ch * 32 + b * 4) * 64 + t];
        ksl[(t >> 6) * 65 + (t & 63)] = s;
    }
    __syncthreads();
    const int h = t & 3, l = l0 + (t >> 2);
    const u16* qrow = qbt + ((size_t)(b * 4 + h) * 1024 + l) * 64;
    float qf[64];
#pragma unroll
    for (int j8 = 0; j8 < 8; ++j8) {
        int4 pk = *(const int4*)&qrow[j8 * 8];
        const u16* pku = (const u16*)&pk;
#pragma unroll
        for (int e = 0; e < 8; ++e) qf[j8 * 8 + e] = elu1(bf2f(pku[e]));
    }
    float zd = 1e-6f;
#pragma unroll
    for (int dd = 0; dd < 64; ++dd) zd += qf[dd] * ksl[h * 65 + dd];
    const float Z = 1.f / zd;
    float* op = msg + ((size_t)(b * 1024 + l)) * 256 + h * 64;
    for (int c0 = 0; c0 < 64; c0 += 16) {
        float4 a[4];
#pragma unroll
        for (int j = 0; j < 4; ++j) a[j] = make_float4(0.f, 0.f, 0.f, 0.f);
#pragma unroll
        for (int dd = 0; dd < 64; ++dd) {
            float qv = qf[dd];
            const float4* kp = (const float4*)(kvl + h * 4112 + dd * 64 + c0);
#pragma unroll
            for (int j = 0; j < 4; ++j) {
                float4 kk = kp[j];
                a[j].x += qv * kk.x; a[j].y += qv * kk.y;
                a[j].z += qv * kk.z; a[j].w += qv * kk.w;
            }
        }
#pragma unroll
        for (int j = 0; j < 4; ++j) {
            a[j].x *= Z; a[j].y *= Z; a[j].z *= Z; a[j].w *= Z;
            ((float4*)(op + c0))[j] = a[j];
        }
    }
}

// ===========================================================================
// Fused merge(Wm,LN1) + FF(W1,relu,W2,LN2) + residual (validated R12).
// ===========================================================================
__global__ __launch_bounds__(256) void ff_fused_kernel(
    const float* __restrict__ x, const float* __restrict__ msg,
    const u16* __restrict__ wmp,
    const u16* __restrict__ w1p, const u16* __restrict__ w2p,
    const float* __restrict__ g1, const float* __restrict__ b1,
    const float* __restrict__ g2, const float* __restrict__ b2,
    float* __restrict__ out)
{
    __shared__ u16 tile[16 * 520];
    __shared__ u16 mtile[16 * 264];
    __shared__ float redS[16 * 4];
    __shared__ float redQ[16 * 4];
    float* tf = (float*)tile;
    const int t = threadIdx.x;
    const int base = blockIdx.x * 16;   // 512 blocks
    const int b = base >> 10, l0 = base & 1023;
    const int w = t >> 6, l = t & 63, ln = l & 15, lg = l >> 4;

    {
        int rr = t & 15, cg = t >> 4;
        for (int cci = 0; cci < 16; ++cci) {
            int c = cci * 16 + cg;
            tile[rr * 520 + c] = f2bf(x[((size_t)b * 256 + c) * 1024 + l0 + rr]);
        }
        int r = t >> 4, cb = (t & 15) * 16;
#pragma unroll
        for (int i = 0; i < 4; ++i) {
            float4 v = *(const float4*)&msg[((size_t)(base + r)) * 256 + cb + i * 4];
            u32 p0 = (u32)f2bf(v.x) | ((u32)f2bf(v.y) << 16);
            u32 p1 = (u32)f2bf(v.z) | ((u32)f2bf(v.w) << 16);
            *(u32*)&mtile[r * 264 + cb + i * 4] = p0;
            *(u32*)&mtile[r * 264 + cb + i * 4 + 2] = p1;
        }
    }
    __syncthreads();

    f32x4 accm[4];
#pragma unroll
    for (int fc = 0; fc < 4; ++fc) accm[fc] = (f32x4){0.f, 0.f, 0.f, 0.f};
    for (int ks = 0; ks < 8; ++ks) {
        bf16x8 a0 = *(const bf16x8*)&mtile[ln * 264 + ks * 32 + lg * 8];
#pragma unroll
        for (int fc = 0; fc < 4; ++fc) {
            bf16x8 bb = *(const bf16x8*)&wmp[((size_t)(ks * 16 + w * 4 + fc) * 64 + l) * 8];
            accm[fc] = __builtin_amdgcn_mfma_f32_16x16x32_bf16(a0, bb, accm[fc], 0, 0, 0);
        }
    }
#pragma unroll
    for (int reg = 0; reg < 4; ++reg) {
        float s = 0.f, qsum = 0.f;
#pragma unroll
        for (int fc = 0; fc < 4; ++fc) {
            float v = accm[fc][reg];
            s += v; qsum += v * v;
        }
#pragma unroll
        for (int off = 1; off < 16; off <<= 1) {
            s += __shfl_xor(s, off);
            qsum += __shfl_xor(qsum, off);
        }
        if (ln == 0) {
            int r = lg * 4 + reg;
            redS[r * 4 + w] = s;
            redQ[r * 4 + w] = qsum;
        }
    }
    __syncthreads();
#pragma unroll
    for (int fc = 0; fc < 4; ++fc) {
        int c = w * 64 + fc * 16 + ln;
        float gg = g1[c], bb = b1[c];
#pragma unroll
        for (int reg = 0; reg < 4; ++reg) {
            int r = lg * 4 + reg;
            float s = redS[r * 4] + redS[r * 4 + 1] + redS[r * 4 + 2] + redS[r * 4 + 3];
            float qs = redQ[r * 4] + redQ[r * 4 + 1] + redQ[r * 4 + 2] + redQ[r * 4 + 3];
            float mean = s * (1.f / 256.f);
            float rstd = rsqrtf(qs * (1.f / 256.f) - mean * mean + 1e-5f);
            tile[r * 520 + 256 + c] = f2bf((accm[fc][reg] - mean) * rstd * gg + bb);
        }
    }
    __syncthreads();

    f32x4 acc1[8];
#pragma unroll
    for (int fc = 0; fc < 8; ++fc) acc1[fc] = (f32x4){0.f, 0.f, 0.f, 0.f};
    for (int ks = 0; ks < 16; ++ks) {
        bf16x8 a0 = *(const bf16x8*)&tile[ln * 520 + ks * 32 + lg * 8];
#pragma unroll
        for (int fc = 0; fc < 8; ++fc) {
            bf16x8 bb = *(const bf16x8*)&w1p[((size_t)(ks * 32 + w * 8 + fc) * 64 + l) * 8];
            acc1[fc] = __builtin_amdgcn_mfma_f32_16x16x32_bf16(a0, bb, acc1[fc], 0, 0, 0);
        }
    }
    __syncthreads();
#pragma unroll
    for (int fc = 0; fc < 8; ++fc)
#pragma unroll
        for (int reg = 0; reg < 4; ++reg) {
            int r = lg * 4 + reg;
            int c = w * 128 + fc * 16 + ln;
            tile[r * 520 + c] = f2bf(fmaxf(acc1[fc][reg], 0.f));
        }
    __syncthreads();

    f32x4 acc2[4];
#pragma unroll
    for (int fc = 0; fc < 4; ++fc) acc2[fc] = (f32x4){0.f, 0.f, 0.f, 0.f};
    for (int ks = 0; ks < 16; ++ks) {
        bf16x8 a0 = *(const bf16x8*)&tile[ln * 520 + ks * 32 + lg * 8];
#pragma unroll
        for (int fc = 0; fc < 4; ++fc) {
            bf16x8 bb = *(const bf16x8*)&w2p[((size_t)(ks * 16 + w * 4 + fc) * 64 + l) * 8];
            acc2[fc] = __builtin_amdgcn_mfma_f32_16x16x32_bf16(a0, bb, acc2[fc], 0, 0, 0);
        }
    }
#pragma unroll
    for (int reg = 0; reg < 4; ++reg) {
        float s = 0.f, qsum = 0.f;
#pragma unroll
        for (int fc = 0; fc < 4; ++fc) {
            float v = acc2[fc][reg];
            s += v; qsum += v * v;
        }
#pragma unroll
        for (int off = 1; off < 16; off <<= 1) {
            s += __shfl_xor(s, off);
            qsum += __shfl_xor(qsum, off);
        }
        if (ln == 0) {
            int r = lg * 4 + reg;
            redS[r * 4 + w] = s;
            redQ[r * 4 + w] = qsum;
        }
    }
    __syncthreads();
    float mean[4], rstd[4];
#pragma unroll
    for (int reg = 0; reg < 4; ++reg) {
        int r = lg * 4 + reg;
        float s = redS[r * 4] + redS[r * 4 + 1] + redS[r * 4 + 2] + redS[r * 4 + 3];
        float qs = redQ[r * 4] + redQ[r * 4 + 1] + redQ[r * 4 + 2] + redQ[r * 4 + 3];
        float m = s * (1.f / 256.f);
        mean[reg] = m;
        rstd[reg] = rsqrtf(qs * (1.f / 256.f) - m * m + 1e-5f);
    }
    __syncthreads();
#pragma unroll
    for (int fc = 0; fc < 4; ++fc) {
        int c = w * 64 + fc * 16 + ln;
        float gg = g2[c], bb = b2[c];
#pragma unroll
        for (int reg = 0; reg < 4; ++reg) {
            int r = lg * 4 + reg;
            tf[r * 260 + c] = (acc2[fc][reg] - mean[reg]) * rstd[reg] * gg + bb;
        }
    }
    __syncthreads();
    {
        const float* xp = x + ((size_t)b * 256 + t) * 1024 + l0;
        float* op = out + ((size_t)b * 256 + t) * 1024 + l0;
#pragma unroll
        for (int i = 0; i < 4; ++i) {
            float4 xv = *(const float4*)(xp + i * 4);
            float4 o;
            o.x = xv.x + tf[(i * 4 + 0) * 260 + t];
            o.y = xv.y + tf[(i * 4 + 1) * 260 + t];
            o.z = xv.z + tf[(i * 4 + 2) * 260 + t];
            o.w = xv.w + tf[(i * 4 + 3) * 260 + t];
            *(float4*)(op + i * 4) = o;
        }
    }
}

// ---------------------------------------------------------------------------
extern "C" void kernel_launch(void* const* d_in, const int* in_sizes, int n_in,
                              void* d_out, int out_size, void* d_ws, size_t ws_size,
                              hipStream_t stream)
{
    const float* x    = (const float*)d_in[0];
    const float* src  = (const float*)d_in[1];
    const float* Wq   = (const float*)d_in[2];
    const float* Wk1  = (const float*)d_in[3];
    const float* Wk3  = (const float*)d_in[4];
    const float* Wk5  = (const float*)d_in[5];
    const float* Wk7  = (const float*)d_in[6];
    const float* Wv1  = (const float*)d_in[7];
    const float* Wv3  = (const float*)d_in[8];
    const float* Wv5  = (const float*)d_in[9];
    const float* Wv7  = (const float*)d_in[10];
    const float* Wm   = (const float*)d_in[11];
    const float* g1   = (const float*)d_in[12];
    const float* b1   = (const float*)d_in[13];
    const float* g2   = (const float*)d_in[14];
    const float* b2   = (const float*)d_in[15];
    const float* W1   = (const float*)d_in[16];
    const float* W2   = (const float*)d_in[17];

    float* out = (float*)d_out;
    float* vis = out + 2097152;          // [b,h,l,s]

    // bf16 conv partials in vis region (dead until qk_sm overwrites it):
    //  p5u [2 side][4 part][8 b][65536] bf16 = 2,097,152 float-equiv
    //  p7u [2 side][8 part][8 b][65536] bf16 = 4,194,304 float-equiv
    u16* p5u = (u16*)vis;
    u16* p7u = (u16*)(vis + 2097152);

    // ws extent+lifetime map (float offsets; re-audited R16 — kb/vb fp32
    // buffers ELIMINATED; all q/k/v flow bf16 [bh][l][64]):
    //  qbt   [0,        1048576)  conv..qk_sm_msg
    //  kbt   [1048576,  2097152)  conv+prep2..qk_sm_msg/prep3
    //  vbt   [2097152,  3145728)  conv+prep2..prep3
    //  wpack [6291456,  7962624)  prep1..conv
    //    then w1p [6291456, 6422528) prep2..ff_fused
    //         w2p [6422528, 6488064) prep2..ff_fused
    //         wmp [6488064, 6520832) prep2..ff_fused
    //  xbh   [7962624,  9011200)  prep1..conv
    //  sbh   [9011200, 10059776)  prep1..conv
    //  msg   [10059776, 12156928) qk_sm_msg..ff_fused
    //  KVp   [12156928, 12681216), Ksump [12681216, 12689408) prep3..qk_sm_msg
    float* ws    = (float*)d_ws;
    u16*   qbt   = (u16*)ws;
    u16*   kbt   = (u16*)(ws + 1048576);
    u16*   vbt   = (u16*)(ws + 2097152);
    u16*   wpack = (u16*)(ws + 6291456);
    u16*   w1p   = (u16*)(ws + 6291456);
    u16*   w2p   = (u16*)(ws + 6422528);
    u16*   wmp   = (u16*)(ws + 6488064);
    u16*   xbh   = (u16*)(ws + 7962624);
    u16*   sbh   = (u16*)(ws + 9011200);
    float* msg   = ws + 10059776;
    float* KVp   = ws + 12156928;
    float* Ksump = ws + 12681216;

    prep1_kernel    <<<2656, 256, 0, stream>>>(Wq, Wk1, Wk3, Wk5, Wk7,
                                               Wv1, Wv3, Wv5, Wv7, wpack,
                                               x, src, xbh, sbh);
    conv_mfma_kernel<<<512,  512, 0, stream>>>(xbh, sbh, wpack, qbt, kbt, vbt,
                                               p5u, p7u);
    prep2_kernel    <<<1248, 256, 0, stream>>>(p5u, p7u, kbt, vbt,
                                               W1, W2, Wm, w1p, w2p, wmp);
    prep3_kernel    <<<128,  256, 0, stream>>>(kbt, vbt, KVp, Ksump);
    qk_sm_msg_kernel<<<1088, 512, 0, stream>>>(qbt, kbt, vis, KVp, Ksump, msg);
    ff_fused_kernel <<<512,  256, 0, stream>>>(x, msg, wmp, w1p, w2p,
                                               g1, b1, g2, b2, out);
}

// Round 17
// 255.031 us; speedup vs baseline: 1.2790x; 1.0221x over previous
//
#include <hip/hip_runtime.h>

#define DEV __device__ __forceinline__

typedef unsigned short u16;
typedef unsigned int u32;
typedef __bf16 bf16x8 __attribute__((ext_vector_type(8)));
typedef float f32x4 __attribute__((ext_vector_type(4)));

DEV float elu1(float x) { return x > 0.f ? x + 1.f : __expf(x); }

DEV u16 f2bf(float f) {
    union { float f; unsigned u; } v; v.f = f;
    unsigned r = v.u + 0x7fffu + ((v.u >> 16) & 1u);
    return (u16)(r >> 16);
}

DEV float bf2f(u16 h) {
    union { u32 u; float f; } v; v.u = ((u32)h) << 16; return v.f;
}

// ===========================================================================
// prep1 = conv-weight repack (validated R2)  ||  cast_src (validated R5).
// ===========================================================================
__global__ __launch_bounds__(256) void prep1_kernel(
    const float* __restrict__ Wq,
    const float* __restrict__ Wk1, const float* __restrict__ Wk3,
    const float* __restrict__ Wk5, const float* __restrict__ Wk7,
    const float* __restrict__ Wv1, const float* __restrict__ Wv3,
    const float* __restrict__ Wv5, const float* __restrict__ Wv7,
    u16* __restrict__ wpack,
    const float* __restrict__ x, const float* __restrict__ src,
    u16* __restrict__ xbh, u16* __restrict__ sbh)
{
    __shared__ float lds[32 * 129];
    const int t = threadIdx.x;
    if (blockIdx.x < 1632) {
        int gid = blockIdx.x * 256 + t;
        int frag = gid >> 6, l = gid & 63;
        const float* W; int K, ocbase = 0, rel;
        if (frag < 1152) {
            W = Wq; K = 3; int slot = frag / 288; rel = frag % 288; ocbase = slot * 64;
        } else {
            int f = frag - 1152; int side = f / 2688; f %= 2688;
            if (f < 32)        { W = side ? Wv1 : Wk1; K = 1; rel = f; }
            else if (f < 320)  { W = side ? Wv3 : Wk3; K = 3; rel = f - 32; }
            else if (f < 1120) { W = side ? Wv5 : Wk5; K = 5; rel = f - 320; }
            else               { W = side ? Wv7 : Wk7; K = 7; rel = f - 1120; }
        }
        int og = rel & 3, cc = (rel >> 2) & 7, tap = rel >> 5;
        int dy = tap / K, dx = tap % K;
        int oc = ocbase + og * 16 + (l & 15);
        int c0 = cc * 32 + (l >> 4) * 8;
        u16 pk[8];
#pragma unroll
        for (int j = 0; j < 8; ++j)
            pk[j] = f2bf(W[((size_t)(oc * 256 + c0 + j) * K + dy) * K + dx]);
        *(int4*)&wpack[(size_t)frag * 512 + l * 8] = *(const int4*)pk;
        return;
    }
    const int i = blockIdx.x - 1632;    // 1024 cast_src blocks
    const int inp = i >> 9, rem = i & 511;
    const int b = rem >> 6, cc = (rem >> 3) & 7, pxb = rem & 7;
    const float* in = (inp ? src : x) + ((size_t)b * 256 + cc * 32) * 1024 + pxb * 128;
    u16* outp = (inp ? sbh : xbh) + (size_t)b * 262144 + (size_t)cc * 32768 + pxb * 128 * 32;
#pragma unroll
    for (int u = 0; u < 4; ++u) {
        int unit = t + u * 256;
        int r = unit >> 5, px4 = unit & 31;
        float4 v = *(const float4*)(in + (size_t)r * 1024 + px4 * 4);
        lds[r * 129 + px4 * 4 + 0] = v.x;
        lds[r * 129 + px4 * 4 + 1] = v.y;
        lds[r * 129 + px4 * 4 + 2] = v.z;
        lds[r * 129 + px4 * 4 + 3] = v.w;
    }
    __syncthreads();
#pragma unroll
    for (int u = 0; u < 2; ++u) {
        int unit = t + u * 256;
        int px = unit >> 2, cg = unit & 3;
        u16 pk[8];
#pragma unroll
        for (int j = 0; j < 8; ++j) pk[j] = f2bf(lds[(cg * 8 + j) * 129 + px]);
        *(int4*)&outp[px * 32 + cg * 8] = *(const int4*)pk;
    }
}

// ===========================================================================
// MFMA implicit-GEMM conv body (R9 MFMA math + R16 bf16 epilogue, validated).
// ===========================================================================
template<int K>
DEV void conv_mfma_body(const u16* __restrict__ srcb,
                        const u16* __restrict__ wsec,
                        u16* __restrict__ dst,
                        u16* Bt, int y0, int cch0, int ncc, int t)
{
    constexpr int P = K / 2;
    const int w = t >> 6, l = t & 63;
    const int chi = l >> 4, ln = l & 15;
    const int rowbase = chi * 22 + w * 2 + 3 - P;
    const int colbase = ln + 3 - P;
    f32x4 acc[4][4];
#pragma unroll
    for (int m = 0; m < 4; ++m)
#pragma unroll
        for (int n = 0; n < 4; ++n) acc[m][n] = (f32x4){0.f, 0.f, 0.f, 0.f};

    for (int cc = 0; cc < ncc; ++cc) {
        const int ccg = cch0 + cc;
        __syncthreads();
#pragma unroll
        for (int u = 0; u < 7; ++u) {
            int unit = t + (u << 9);
            if (unit < 2816) {
                int xv = unit & 31, r = unit >> 5;
                int yy = r % 22, ch = r / 22;
                int ygl = y0 - 3 + yy;
                int4 pk;
                if ((unsigned)ygl < 32u)
                    pk = *(const int4*)&srcb[(size_t)ccg * 32768 + (ygl * 32 + xv) * 32 + ch * 8];
                else
                    pk = (int4){0, 0, 0, 0};
                *(int4*)&Bt[((ch * 22 + yy) * 40 + xv + 3) * 8] = pk;
            } else if (unit < 3520) {
                int hu = unit - 2816;
                int hx = hu & 7; int xi = hx < 3 ? hx : hx + 32;
                int r = hu >> 3; int yy = r % 22, ch = r / 22;
                int4 z = {0, 0, 0, 0};
                *(int4*)&Bt[((ch * 22 + yy) * 40 + xi) * 8] = z;
            }
        }
        __syncthreads();
#pragma unroll
        for (int dy = 0; dy < K; ++dy) {
#pragma unroll
            for (int dx = 0; dx < K; ++dx) {
                const int tap = dy * K + dx;
                const u16* wp = wsec + ((size_t)(tap * 8 + ccg) * 4) * 512 + l * 8;
                bf16x8 a0 = *(const bf16x8*)(wp);
                bf16x8 a1 = *(const bf16x8*)(wp + 512);
                bf16x8 a2 = *(const bf16x8*)(wp + 1024);
                bf16x8 a3 = *(const bf16x8*)(wp + 1536);
                bf16x8 bf[4];
#pragma unroll
                for (int n = 0; n < 4; ++n) {
                    int row = rowbase + dy + (n >> 1);
                    int col = colbase + dx + (n & 1) * 16;
                    bf[n] = *(const bf16x8*)&Bt[(row * 40 + col) * 8];
                }
#pragma unroll
                for (int n = 0; n < 4; ++n) {
                    acc[0][n] = __builtin_amdgcn_mfma_f32_16x16x32_bf16(a0, bf[n], acc[0][n], 0, 0, 0);
                    acc[1][n] = __builtin_amdgcn_mfma_f32_16x16x32_bf16(a1, bf[n], acc[1][n], 0, 0, 0);
                    acc[2][n] = __builtin_amdgcn_mfma_f32_16x16x32_bf16(a2, bf[n], acc[2][n], 0, 0, 0);
                    acc[3][n] = __builtin_amdgcn_mfma_f32_16x16x32_bf16(a3, bf[n], acc[3][n], 0, 0, 0);
                }
            }
        }
    }
#pragma unroll
    for (int m = 0; m < 4; ++m)
#pragma unroll
        for (int n = 0; n < 4; ++n) {
            int y = y0 + w * 2 + (n >> 1);
            int px = y * 32 + (n & 1) * 16 + ln;
            int ocb = m * 16 + chi * 4;
            u16 pk[4];
#pragma unroll
            for (int r = 0; r < 4; ++r) pk[r] = f2bf(acc[m][n][r]);
            *(uint2*)&dst[(size_t)px * 64 + ocb] = *(const uint2*)pk;
        }
}

// Job decode (R17 load-balanced): bx = b*76 + job; job = j*2 + m, j<38.
//  j<8: q slot=j>>1, cpart=j&1 (ncc4, cost 36) -> pq partials
//  else s2=j-8, side=s2/15, jj=s2%15:
//   jj=0: K1 head0 direct (cost 8); jj 1-2: K3 cpart (ncc4, 36) -> p3;
//   jj 3-6: K5 cpart (ncc2, 50) -> p5; jj 7-14: K7 cpart (ncc1, 49) -> p7.
// Max job cost 50 (was 72).
__global__ __launch_bounds__(512) void conv_mfma_kernel(
    const u16* __restrict__ xbh, const u16* __restrict__ sbh,
    const u16* __restrict__ wpack,
    u16* __restrict__ kbt, u16* __restrict__ vbt,
    u16* __restrict__ pq, u16* __restrict__ p3,
    u16* __restrict__ p5, u16* __restrict__ p7)
{
    __shared__ u16 Bt[4 * 22 * 40 * 8];
    const int bx = blockIdx.x, t = threadIdx.x;
    const int b = bx / 76, job = bx % 76;
    const int m = job & 1, j = job >> 1;
    if (j < 8) {
        int slot = j >> 1, cp = j & 1;
        conv_mfma_body<3>(xbh + (size_t)b * 262144,
                          wpack + (size_t)(slot * 288) * 512,
                          pq + ((size_t)((slot * 2 + cp) * 8 + b)) * 65536,
                          Bt, m * 16, cp * 4, 4, t);
        return;
    }
    const int s2 = j - 8;
    const int side = s2 / 15, jj = s2 % 15;
    const u16* sp = sbh + (size_t)b * 262144;
    u16* fin = side ? vbt : kbt;
    const size_t wkb = 1152 + (size_t)side * 2688;
    if (jj == 0) {
        conv_mfma_body<1>(sp, wpack + (wkb + 0) * 512,
                          fin + ((size_t)(b * 4 + 0)) * 65536, Bt, m * 16, 0, 8, t);
    } else if (jj < 3) {
        int cp = jj - 1;
        conv_mfma_body<3>(sp, wpack + (wkb + 32) * 512,
                          p3 + ((size_t)((side * 2 + cp) * 8 + b)) * 65536,
                          Bt, m * 16, cp * 4, 4, t);
    } else if (jj < 7) {
        int cp = jj - 3;
        conv_mfma_body<5>(sp, wpack + (wkb + 320) * 512,
                          p5 + ((size_t)((side * 4 + cp) * 8 + b)) * 65536,
                          Bt, m * 16, cp * 2, 2, t);
    } else {
        int cp = jj - 7;
        conv_mfma_body<7>(sp, wpack + (wkb + 1120) * 512,
                          p7 + ((size_t)((side * 8 + cp) * 8 + b)) * 65536,
                          Bt, m * 16, cp, 1, t);
    }
}

// ===========================================================================
// prep2 = bf16-partial reduce (80 images: q x32, h1 x16, h2 x16, h3 x16)
// || FF/Wm repack. 2560 + 224 = 2784 blocks.
// ===========================================================================
__global__ __launch_bounds__(256) void prep2_kernel(
    const u16* __restrict__ pq, const u16* __restrict__ p3,
    const u16* __restrict__ p5, const u16* __restrict__ p7,
    u16* __restrict__ qbt, u16* __restrict__ kbt, u16* __restrict__ vbt,
    const float* __restrict__ W1, const float* __restrict__ W2,
    const float* __restrict__ Wm,
    u16* __restrict__ w1p, u16* __restrict__ w2p, u16* __restrict__ wmp)
{
    const int t = threadIdx.x;
    if (blockIdx.x < 2560) {
        int gid = blockIdx.x * 256 + t;     // 655360 units of 8 bf16
        int u8 = gid & 8191;
        int img = gid >> 13;                // 0..79
        const u16* srcb; u16* outb; int parts;
        if (img < 32) {
            int sub = img >> 3, b_ = img & 7;
            parts = 2;
            srcb = pq + ((size_t)(sub * 2) * 8 + b_) * 65536;
            outb = qbt + ((size_t)(b_ * 4 + sub)) * 65536;
        } else if (img < 48) {
            int i2 = img - 32; int sub = i2 >> 3, b_ = i2 & 7;
            parts = 2;
            srcb = p3 + ((size_t)(sub * 2) * 8 + b_) * 65536;
            outb = (sub ? vbt : kbt) + ((size_t)(b_ * 4 + 1)) * 65536;
        } else if (img < 64) {
            int i2 = img - 48; int sub = i2 >> 3, b_ = i2 & 7;
            parts = 4;
            srcb = p5 + ((size_t)(sub * 4) * 8 + b_) * 65536;
            outb = (sub ? vbt : kbt) + ((size_t)(b_ * 4 + 2)) * 65536;
        } else {
            int i2 = img - 64; int sub = i2 >> 3, b_ = i2 & 7;
            parts = 8;
            srcb = p7 + ((size_t)(sub * 8) * 8 + b_) * 65536;
            outb = (sub ? vbt : kbt) + ((size_t)(b_ * 4 + 3)) * 65536;
        }
        float sacc[8];
#pragma unroll
        for (int e = 0; e < 8; ++e) sacc[e] = 0.f;
        for (int p = 0; p < parts; ++p) {
            int4 u = *(const int4*)&srcb[(size_t)p * 524288 + (size_t)u8 * 8];
            const u16* uu = (const u16*)&u;
#pragma unroll
            for (int e = 0; e < 8; ++e) sacc[e] += bf2f(uu[e]);
        }
        u16 pk[8];
#pragma unroll
        for (int e = 0; e < 8; ++e) pk[e] = f2bf(sacc[e]);
        *(int4*)&outb[(size_t)u8 * 8] = *(const int4*)pk;
        return;
    }
    int gid = (blockIdx.x - 2560) * 256 + t;    // 224 blocks, 896 frags
    int f = gid >> 6, l = gid & 63;
    if (f >= 896) return;
    u16 pk[8];
    if (f < 512) {
        int ks = f >> 5, nf = f & 31;
#pragma unroll
        for (int j = 0; j < 8; ++j)
            pk[j] = f2bf(W1[(size_t)(ks * 32 + (l >> 4) * 8 + j) * 512 + nf * 16 + (l & 15)]);
        *(int4*)&w1p[(size_t)f * 512 + l * 8] = *(const int4*)pk;
    } else if (f < 768) {
        int f2 = f - 512;
        int ks = f2 >> 4, nf = f2 & 15;
#pragma unroll
        for (int j = 0; j < 8; ++j)
            pk[j] = f2bf(W2[(size_t)(ks * 32 + (l >> 4) * 8 + j) * 256 + nf * 16 + (l & 15)]);
        *(int4*)&w2p[(size_t)f2 * 512 + l * 8] = *(const int4*)pk;
    } else {
        int f3 = f - 768;
        int ks = f3 >> 4, nf = f3 & 15;
#pragma unroll
        for (int j = 0; j < 8; ++j)
            pk[j] = f2bf(Wm[(size_t)(ks * 32 + (l >> 4) * 8 + j) * 256 + nf * 16 + (l & 15)]);
        *(int4*)&wmp[(size_t)f3 * 512 + l * 8] = *(const int4*)pk;
    }
}

// ===========================================================================
// prep3 = linear-attention KV/Ksum (validated R16). 128 blocks.
// ===========================================================================
__global__ __launch_bounds__(256) void prep3_kernel(
    const u16* __restrict__ kbt, const u16* __restrict__ vbt,
    float* __restrict__ KVp, float* __restrict__ Ksump)
{
    __shared__ float4 smem4[2112];
    float* Kt = (float*)smem4;              // [64][68]
    float* Vt = (float*)(smem4 + 64 * 17);  // [64][64]
    const int t = threadIdx.x;
    const int bx = blockIdx.x;              // 128
    const int b = bx >> 4, h = (bx >> 2) & 3, ch = bx & 3;
    const u16* kbase = kbt + ((size_t)(b * 4 + h) * 1024 + ch * 256) * 64;
    const u16* vbase = vbt + ((size_t)(b * 4 + h) * 1024 + ch * 256) * 64;
    const int d = t >> 2, v0 = (t & 3) * 16;
    float4 acc[4];
#pragma unroll
    for (int j = 0; j < 4; ++j) acc[j] = make_float4(0.f, 0.f, 0.f, 0.f);
    float ks = 0.f;
    for (int st = 0; st < 4; ++st) {
        __syncthreads();
        {
            int s = t >> 2, d0 = (t & 3) * 16;
            const u16* krow = kbase + (size_t)(st * 64 + s) * 64;
            const u16* vrow = vbase + (size_t)(st * 64 + s) * 64;
#pragma unroll
            for (int oo = 0; oo < 2; ++oo) {
                int4 k8 = *(const int4*)&krow[d0 + oo * 8];
                int4 v8 = *(const int4*)&vrow[d0 + oo * 8];
                const u16* ku = (const u16*)&k8;
                const u16* vu = (const u16*)&v8;
#pragma unroll
                for (int e = 0; e < 8; ++e) {
                    Kt[s * 68 + d0 + oo * 8 + e] = elu1(bf2f(ku[e]));
                    Vt[s * 64 + d0 + oo * 8 + e] = bf2f(vu[e]);
                }
            }
        }
        __syncthreads();
#pragma unroll 8
        for (int s = 0; s < 64; ++s) {
            float kf = Kt[s * 68 + d];
            const float4* vvp = (const float4*)(Vt + s * 64 + v0);
#pragma unroll
            for (int j = 0; j < 4; ++j) {
                float4 vv = vvp[j];
                acc[j].x += kf * vv.x; acc[j].y += kf * vv.y;
                acc[j].z += kf * vv.z; acc[j].w += kf * vv.w;
            }
        }
        if (t < 64) {
#pragma unroll 8
            for (int s = 0; s < 64; ++s) ks += Kt[s * 68 + t];
        }
    }
    float* op = KVp + ((size_t)((ch * 32 + b * 4 + h) * 64 + d)) * 64 + v0;
#pragma unroll
    for (int j = 0; j < 4; ++j) ((float4*)op)[j] = acc[j];
    if (t < 64) Ksump[(size_t)(ch * 32 + b * 4 + h) * 64 + t] = ks;
}

// ===========================================================================
// qk_sm (validated R12/R15; nontemporal vis stores) || msg (validated R13).
// ===========================================================================
__global__ __launch_bounds__(512) void qk_sm_msg_kernel(
    const u16* __restrict__ qbt, const u16* __restrict__ kbt,
    float* __restrict__ vis,
    const float* __restrict__ KVp, const float* __restrict__ Ksump,
    float* __restrict__ msg)
{
    __shared__ float4 smem4[4178];      // 66,848 B union
    const int t = threadIdx.x;
    if (blockIdx.x < 1024) {
        u16* kf = (u16*)smem4;
        u16* qf = (u16*)smem4 + 32 * 512;
        float* redM = (float*)((char*)smem4 + 36864);
        float* redS = redM + 256;
        const int bx = blockIdx.x;
        const int b = bx >> 7, h = (bx >> 5) & 3, l0 = (bx & 31) * 32;
        const u16* qtp = qbt + ((size_t)(b * 4 + h)) * 1024 * 64;
        const u16* ktp = kbt + ((size_t)(b * 4 + h)) * 1024 * 64;

        if (t < 256) {
            int r = t & 31, dblk = t >> 5;
            int4 pk = *(const int4*)&qtp[(size_t)(l0 + r) * 64 + dblk * 8];
            *(int4*)&qf[(((r >> 4) * 2 + (dblk >> 2)) * 64 + (dblk & 3) * 16 + (r & 15)) * 8] = pk;
        }
        __syncthreads();

        const int w = t >> 6, l = t & 63, ln = l & 15, lg = l >> 4;
        bf16x8 a[2][2];
#pragma unroll
        for (int fr = 0; fr < 2; ++fr)
#pragma unroll
            for (int ks = 0; ks < 2; ++ks)
                a[fr][ks] = *(const bf16x8*)&qf[((fr * 2 + ks) * 64 + l) * 8];

        f32x4 acc[2][4][2];
#pragma unroll
        for (int fr = 0; fr < 2; ++fr)
#pragma unroll
            for (int cc = 0; cc < 4; ++cc)
#pragma unroll
                for (int f = 0; f < 2; ++f) acc[fr][cc][f] = (f32x4){0.f, 0.f, 0.f, 0.f};

#pragma unroll
        for (int cc = 0; cc < 4; ++cc) {
            __syncthreads();
#pragma unroll
            for (int it = 0; it < 4; ++it) {
                int unit = it * 512 + t;
                int sl = unit & 255, dblk = unit >> 8;
                int4 pk = *(const int4*)&ktp[(size_t)(cc * 256 + sl) * 64 + dblk * 8];
                *(int4*)&kf[(((sl >> 4) * 2 + (dblk >> 2)) * 64 + (dblk & 3) * 16 + (sl & 15)) * 8] = pk;
            }
            __syncthreads();
#pragma unroll
            for (int f = 0; f < 2; ++f) {
                int fg = (w * 2 + f) * 2;
                bf16x8 b0 = *(const bf16x8*)&kf[((fg + 0) * 64 + l) * 8];
                bf16x8 b1 = *(const bf16x8*)&kf[((fg + 1) * 64 + l) * 8];
#pragma unroll
                for (int fr = 0; fr < 2; ++fr) {
                    acc[fr][cc][f] = __builtin_amdgcn_mfma_f32_16x16x32_bf16(a[fr][0], b0, acc[fr][cc][f], 0, 0, 0);
                    acc[fr][cc][f] = __builtin_amdgcn_mfma_f32_16x16x32_bf16(a[fr][1], b1, acc[fr][cc][f], 0, 0, 0);
                }
            }
        }

#pragma unroll
        for (int fr = 0; fr < 2; ++fr)
#pragma unroll
            for (int cc = 0; cc < 4; ++cc)
#pragma unroll
                for (int f = 0; f < 2; ++f)
#pragma unroll
                    for (int e = 0; e < 4; ++e) acc[fr][cc][f][e] *= 0.125f;

        float rmax[2][4];
#pragma unroll
        for (int fr = 0; fr < 2; ++fr)
#pragma unroll
            for (int reg = 0; reg < 4; ++reg) {
                float m = -1e30f;
#pragma unroll
                for (int cc = 0; cc < 4; ++cc)
#pragma unroll
                    for (int f = 0; f < 2; ++f) m = fmaxf(m, acc[fr][cc][f][reg]);
#pragma unroll
                for (int off = 1; off < 16; off <<= 1) m = fmaxf(m, __shfl_xor(m, off));
                if (ln == 0) redM[(fr * 16 + lg * 4 + reg) * 8 + w] = m;
                rmax[fr][reg] = m;
            }
        __syncthreads();
#pragma unroll
        for (int fr = 0; fr < 2; ++fr)
#pragma unroll
            for (int reg = 0; reg < 4; ++reg) {
                int r = fr * 16 + lg * 4 + reg;
                float m = redM[r * 8];
#pragma unroll
                for (int ww = 1; ww < 8; ++ww) m = fmaxf(m, redM[r * 8 + ww]);
                rmax[fr][reg] = m;
            }
#pragma unroll
        for (int fr = 0; fr < 2; ++fr)
#pragma unroll
            for (int reg = 0; reg < 4; ++reg) {
                float s = 0.f;
                float m = rmax[fr][reg];
#pragma unroll
                for (int cc = 0; cc < 4; ++cc)
#pragma unroll
                    for (int f = 0; f < 2; ++f) {
                        float e = __expf(acc[fr][cc][f][reg] - m);
                        acc[fr][cc][f][reg] = e;
                        s += e;
                    }
#pragma unroll
                for (int off = 1; off < 16; off <<= 1) s += __shfl_xor(s, off);
                if (ln == 0) redS[(fr * 16 + lg * 4 + reg) * 8 + w] = s;
            }
        __syncthreads();
        float invv[2][4];
#pragma unroll
        for (int fr = 0; fr < 2; ++fr)
#pragma unroll
            for (int reg = 0; reg < 4; ++reg) {
                int r = fr * 16 + lg * 4 + reg;
                float s = redS[r * 8] + redS[r * 8 + 1] + redS[r * 8 + 2] + redS[r * 8 + 3]
                        + redS[r * 8 + 4] + redS[r * 8 + 5] + redS[r * 8 + 6] + redS[r * 8 + 7];
                invv[fr][reg] = 1.f / s;
            }
        float* outT = (float*)smem4;    // [32][260] f32
        float* visp = vis + (((size_t)(b * 4 + h)) << 20);
#pragma unroll
        for (int cc = 0; cc < 4; ++cc) {
            __syncthreads();
#pragma unroll
            for (int fr = 0; fr < 2; ++fr)
#pragma unroll
                for (int reg = 0; reg < 4; ++reg) {
                    int r = fr * 16 + lg * 4 + reg;
#pragma unroll
                    for (int f = 0; f < 2; ++f)
                        outT[r * 260 + w * 32 + f * 16 + ln] = acc[fr][cc][f][reg] * invv[fr][reg];
                }
            __syncthreads();
#pragma unroll
            for (int u = 0; u < 4; ++u) {
                int unit = u * 512 + t;
                int r = unit >> 6, c4 = unit & 63;
                f32x4 v = *(const f32x4*)&outT[r * 260 + c4 * 4];
                __builtin_nontemporal_store(v,
                    (f32x4*)&visp[(size_t)(l0 + r) * 1024 + cc * 256 + c4 * 4]);
            }
        }
        return;
    }
    // ---- msg path (64 blocks, 512 threads) ----
    float* kvl = (float*)smem4;             // [4][4112]
    float* ksl = (float*)smem4 + 4 * 4112;  // [4][65]
    const int bx2 = blockIdx.x - 1024;
    const int b = bx2 >> 3, l0 = (bx2 & 7) * 128;
#pragma unroll
    for (int m = 0; m < 8; ++m) {
        int unit = t + (m << 9);            // 4096 float4 units
        int hh = unit >> 10, dd = (unit >> 4) & 63, v4 = unit & 15;
        float4 s = make_float4(0.f, 0.f, 0.f, 0.f);
#pragma unroll
        for (int ch = 0; ch < 4; ++ch) {
            float4 u = *(const float4*)&KVp[((size_t)(ch * 32 + b * 4)) * 4096 + (size_t)unit * 4];
            s.x += u.x; s.y += u.y; s.z += u.z; s.w += u.w;
        }
        *(float4*)&kvl[hh * 4112 + dd * 64 + v4 * 4] = s;
    }
    if (t < 256) {
        float s = 0.f;
#pragma unroll
        for (int ch = 0; ch < 4; ++ch)
            s += Ksump[(size_t)(ch * 32 + b * 4) * 64 + t];
        ksl[(t >> 6) * 65 + (t & 63)] = s;
    }
    __syncthreads();
    const int h = t & 3, l = l0 + (t >> 2);
    const u16* qrow = qbt + ((size_t)(b * 4 + h) * 1024 + l) * 64;
    float qf[64];
#pragma unroll
    for (int j8 = 0; j8 < 8; ++j8) {
        int4 pk = *(const int4*)&qrow[j8 * 8];
        const u16* pku = (const u16*)&pk;
#pragma unroll
        for (int e = 0; e < 8; ++e) qf[j8 * 8 + e] = elu1(bf2f(pku[e]));
    }
    float zd = 1e-6f;
#pragma unroll
    for (int dd = 0; dd < 64; ++dd) zd += qf[dd] * ksl[h * 65 + dd];
    const float Z = 1.f / zd;
    float* op = msg + ((size_t)(b * 1024 + l)) * 256 + h * 64;
    for (int c0 = 0; c0 < 64; c0 += 16) {
        float4 a[4];
#pragma unroll
        for (int j = 0; j < 4; ++j) a[j] = make_float4(0.f, 0.f, 0.f, 0.f);
#pragma unroll
        for (int dd = 0; dd < 64; ++dd) {
            float qv = qf[dd];
            const float4* kp = (const float4*)(kvl + h * 4112 + dd * 64 + c0);
#pragma unroll
            for (int j = 0; j < 4; ++j) {
                float4 kk = kp[j];
                a[j].x += qv * kk.x; a[j].y += qv * kk.y;
                a[j].z += qv * kk.z; a[j].w += qv * kk.w;
            }
        }
#pragma unroll
        for (int j = 0; j < 4; ++j) {
            a[j].x *= Z; a[j].y *= Z; a[j].z *= Z; a[j].w *= Z;
            ((float4*)(op + c0))[j] = a[j];
        }
    }
}

// ===========================================================================
// Fused merge(Wm,LN1) + FF(W1,relu,W2,LN2) + residual (validated R12).
// ===========================================================================
__global__ __launch_bounds__(256) void ff_fused_kernel(
    const float* __restrict__ x, const float* __restrict__ msg,
    const u16* __restrict__ wmp,
    const u16* __restrict__ w1p, const u16* __restrict__ w2p,
    const float* __restrict__ g1, const float* __restrict__ b1,
    const float* __restrict__ g2, const float* __restrict__ b2,
    float* __restrict__ out)
{
    __shared__ u16 tile[16 * 520];
    __shared__ u16 mtile[16 * 264];
    __shared__ float redS[16 * 4];
    __shared__ float redQ[16 * 4];
    float* tf = (float*)tile;
    const int t = threadIdx.x;
    const int base = blockIdx.x * 16;   // 512 blocks
    const int b = base >> 10, l0 = base & 1023;
    const int w = t >> 6, l = t & 63, ln = l & 15, lg = l >> 4;

    {
        int rr = t & 15, cg = t >> 4;
        for (int cci = 0; cci < 16; ++cci) {
            int c = cci * 16 + cg;
            tile[rr * 520 + c] = f2bf(x[((size_t)b * 256 + c) * 1024 + l0 + rr]);
        }
        int r = t >> 4, cb = (t & 15) * 16;
#pragma unroll
        for (int i = 0; i < 4; ++i) {
            float4 v = *(const float4*)&msg[((size_t)(base + r)) * 256 + cb + i * 4];
            u32 p0 = (u32)f2bf(v.x) | ((u32)f2bf(v.y) << 16);
            u32 p1 = (u32)f2bf(v.z) | ((u32)f2bf(v.w) << 16);
            *(u32*)&mtile[r * 264 + cb + i * 4] = p0;
            *(u32*)&mtile[r * 264 + cb + i * 4 + 2] = p1;
        }
    }
    __syncthreads();

    f32x4 accm[4];
#pragma unroll
    for (int fc = 0; fc < 4; ++fc) accm[fc] = (f32x4){0.f, 0.f, 0.f, 0.f};
    for (int ks = 0; ks < 8; ++ks) {
        bf16x8 a0 = *(const bf16x8*)&mtile[ln * 264 + ks * 32 + lg * 8];
#pragma unroll
        for (int fc = 0; fc < 4; ++fc) {
            bf16x8 bb = *(const bf16x8*)&wmp[((size_t)(ks * 16 + w * 4 + fc) * 64 + l) * 8];
            accm[fc] = __builtin_amdgcn_mfma_f32_16x16x32_bf16(a0, bb, accm[fc], 0, 0, 0);
        }
    }
#pragma unroll
    for (int reg = 0; reg < 4; ++reg) {
        float s = 0.f, qsum = 0.f;
#pragma unroll
        for (int fc = 0; fc < 4; ++fc) {
            float v = accm[fc][reg];
            s += v; qsum += v * v;
        }
#pragma unroll
        for (int off = 1; off < 16; off <<= 1) {
            s += __shfl_xor(s, off);
            qsum += __shfl_xor(qsum, off);
        }
        if (ln == 0) {
            int r = lg * 4 + reg;
            redS[r * 4 + w] = s;
            redQ[r * 4 + w] = qsum;
        }
    }
    __syncthreads();
#pragma unroll
    for (int fc = 0; fc < 4; ++fc) {
        int c = w * 64 + fc * 16 + ln;
        float gg = g1[c], bb = b1[c];
#pragma unroll
        for (int reg = 0; reg < 4; ++reg) {
            int r = lg * 4 + reg;
            float s = redS[r * 4] + redS[r * 4 + 1] + redS[r * 4 + 2] + redS[r * 4 + 3];
            float qs = redQ[r * 4] + redQ[r * 4 + 1] + redQ[r * 4 + 2] + redQ[r * 4 + 3];
            float mean = s * (1.f / 256.f);
            float rstd = rsqrtf(qs * (1.f / 256.f) - mean * mean + 1e-5f);
            tile[r * 520 + 256 + c] = f2bf((accm[fc][reg] - mean) * rstd * gg + bb);
        }
    }
    __syncthreads();

    f32x4 acc1[8];
#pragma unroll
    for (int fc = 0; fc < 8; ++fc) acc1[fc] = (f32x4){0.f, 0.f, 0.f, 0.f};
    for (int ks = 0; ks < 16; ++ks) {
        bf16x8 a0 = *(const bf16x8*)&tile[ln * 520 + ks * 32 + lg * 8];
#pragma unroll
        for (int fc = 0; fc < 8; ++fc) {
            bf16x8 bb = *(const bf16x8*)&w1p[((size_t)(ks * 32 + w * 8 + fc) * 64 + l) * 8];
            acc1[fc] = __builtin_amdgcn_mfma_f32_16x16x32_bf16(a0, bb, acc1[fc], 0, 0, 0);
        }
    }
    __syncthreads();
#pragma unroll
    for (int fc = 0; fc < 8; ++fc)
#pragma unroll
        for (int reg = 0; reg < 4; ++reg) {
            int r = lg * 4 + reg;
            int c = w * 128 + fc * 16 + ln;
            tile[r * 520 + c] = f2bf(fmaxf(acc1[fc][reg], 0.f));
        }
    __syncthreads();

    f32x4 acc2[4];
#pragma unroll
    for (int fc = 0; fc < 4; ++fc) acc2[fc] = (f32x4){0.f, 0.f, 0.f, 0.f};
    for (int ks = 0; ks < 16; ++ks) {
        bf16x8 a0 = *(const bf16x8*)&tile[ln * 520 + ks * 32 + lg * 8];
#pragma unroll
        for (int fc = 0; fc < 4; ++fc) {
            bf16x8 bb = *(const bf16x8*)&w2p[((size_t)(ks * 16 + w * 4 + fc) * 64 + l) * 8];
            acc2[fc] = __builtin_amdgcn_mfma_f32_16x16x32_bf16(a0, bb, acc2[fc], 0, 0, 0);
        }
    }
#pragma unroll
    for (int reg = 0; reg < 4; ++reg) {
        float s = 0.f, qsum = 0.f;
#pragma unroll
        for (int fc = 0; fc < 4; ++fc) {
            float v = acc2[fc][reg];
            s += v; qsum += v * v;
        }
#pragma unroll
        for (int off = 1; off < 16; off <<= 1) {
            s += __shfl_xor(s, off);
            qsum += __shfl_xor(qsum, off);
        }
        if (ln == 0) {
            int r = lg * 4 + reg;
            redS[r * 4 + w] = s;
            redQ[r * 4 + w] = qsum;
        }
    }
    __syncthreads();
    float mean[4], rstd[4];
#pragma unroll
    for (int reg = 0; reg < 4; ++reg) {
        int r = lg * 4 + reg;
        float s = redS[r * 4] + redS[r * 4 + 1] + redS[r * 4 + 2] + redS[r * 4 + 3];
        float qs = redQ[r * 4] + redQ[r * 4 + 1] + redQ[r * 4 + 2] + redQ[r * 4 + 3];
        float m = s * (1.f / 256.f);
        mean[reg] = m;
        rstd[reg] = rsqrtf(qs * (1.f / 256.f) - m * m + 1e-5f);
    }
    __syncthreads();
#pragma unroll
    for (int fc = 0; fc < 4; ++fc) {
        int c = w * 64 + fc * 16 + ln;
        float gg = g2[c], bb = b2[c];
#pragma unroll
        for (int reg = 0; reg < 4; ++reg) {
            int r = lg * 4 + reg;
            tf[r * 260 + c] = (acc2[fc][reg] - mean[reg]) * rstd[reg] * gg + bb;
        }
    }
    __syncthreads();
    {
        const float* xp = x + ((size_t)b * 256 + t) * 1024 + l0;
        float* op = out + ((size_t)b * 256 + t) * 1024 + l0;
#pragma unroll
        for (int i = 0; i < 4; ++i) {
            float4 xv = *(const float4*)(xp + i * 4);
            float4 o;
            o.x = xv.x + tf[(i * 4 + 0) * 260 + t];
            o.y = xv.y + tf[(i * 4 + 1) * 260 + t];
            o.z = xv.z + tf[(i * 4 + 2) * 260 + t];
            o.w = xv.w + tf[(i * 4 + 3) * 260 + t];
            *(float4*)(op + i * 4) = o;
        }
    }
}

// ---------------------------------------------------------------------------
extern "C" void kernel_launch(void* const* d_in, const int* in_sizes, int n_in,
                              void* d_out, int out_size, void* d_ws, size_t ws_size,
                              hipStream_t stream)
{
    const float* x    = (const float*)d_in[0];
    const float* src  = (const float*)d_in[1];
    const float* Wq   = (const float*)d_in[2];
    const float* Wk1  = (const float*)d_in[3];
    const float* Wk3  = (const float*)d_in[4];
    const float* Wk5  = (const float*)d_in[5];
    const float* Wk7  = (const float*)d_in[6];
    const float* Wv1  = (const float*)d_in[7];
    const float* Wv3  = (const float*)d_in[8];
    const float* Wv5  = (const float*)d_in[9];
    const float* Wv7  = (const float*)d_in[10];
    const float* Wm   = (const float*)d_in[11];
    const float* g1   = (const float*)d_in[12];
    const float* b1   = (const float*)d_in[13];
    const float* g2   = (const float*)d_in[14];
    const float* b2   = (const float*)d_in[15];
    const float* W1   = (const float*)d_in[16];
    const float* W2   = (const float*)d_in[17];

    float* out = (float*)d_out;
    float* vis = out + 2097152;          // [b,h,l,s]

    // bf16 conv partials in vis region (dead until qk_sm overwrites it):
    //  pq [4 slot][2 part][8 b][65536] = 4,194,304 u16
    //  p3 [2 side][2 part][8 b][65536] = 2,097,152 u16
    //  p5 [2 side][4 part][8 b][65536] = 4,194,304 u16
    //  p7 [2 side][8 part][8 b][65536] = 8,388,608 u16
    //  total 18.9M u16 = 9.44M floats < 33.5M vis floats ✓
    u16* pq = (u16*)vis;
    u16* p3 = pq + 4194304;
    u16* p5 = p3 + 2097152;
    u16* p7 = p5 + 4194304;

    // ws extent+lifetime map (float offsets; unchanged from R16):
    //  qbt   [0,        1048576)  prep2..qk_sm_msg (bf16, from reduce)
    //  kbt   [1048576,  2097152)  conv+prep2..qk_sm_msg/prep3
    //  vbt   [2097152,  3145728)  conv+prep2..prep3
    //  wpack [6291456,  7962624)  prep1..conv
    //    then w1p/w2p/wmp [6291456, 6520832) prep2..ff_fused
    //  xbh   [7962624,  9011200)  prep1..conv
    //  sbh   [9011200, 10059776)  prep1..conv
    //  msg   [10059776, 12156928) qk_sm_msg..ff_fused
    //  KVp   [12156928, 12681216), Ksump [12681216, 12689408) prep3..qk_sm_msg
    float* ws    = (float*)d_ws;
    u16*   qbt   = (u16*)ws;
    u16*   kbt   = (u16*)(ws + 1048576);
    u16*   vbt   = (u16*)(ws + 2097152);
    u16*   wpack = (u16*)(ws + 6291456);
    u16*   w1p   = (u16*)(ws + 6291456);
    u16*   w2p   = (u16*)(ws + 6422528);
    u16*   wmp   = (u16*)(ws + 6488064);
    u16*   xbh   = (u16*)(ws + 7962624);
    u16*   sbh   = (u16*)(ws + 9011200);
    float* msg   = ws + 10059776;
    float* KVp   = ws + 12156928;
    float* Ksump = ws + 12681216;

    prep1_kernel    <<<2656, 256, 0, stream>>>(Wq, Wk1, Wk3, Wk5, Wk7,
                                               Wv1, Wv3, Wv5, Wv7, wpack,
                                               x, src, xbh, sbh);
    conv_mfma_kernel<<<608,  512, 0, stream>>>(xbh, sbh, wpack, kbt, vbt,
                                               pq, p3, p5, p7);
    prep2_kernel    <<<2784, 256, 0, stream>>>(pq, p3, p5, p7, qbt, kbt, vbt,
                                               W1, W2, Wm, w1p, w2p, wmp);
    prep3_kernel    <<<128,  256, 0, stream>>>(kbt, vbt, KVp, Ksump);
    qk_sm_msg_kernel<<<1088, 512, 0, stream>>>(qbt, kbt, vis, KVp, Ksump, msg);
    ff_fused_kernel <<<512,  256, 0, stream>>>(x, msg, wmp, w1p, w2p,
                                               g1, b1, g2, b2, out);
}